// Round 4
// baseline (2104.174 us; speedup 1.0000x reference)
//
#include <hip/hip_runtime.h>
#include <hip/hip_bf16.h>

// MPNN on MI355X — fused tile kernel.
// msg[e,o] = sum_k t[e,k]*Q[src,k,o] + q0[src,o],  Q[n] = h[n] @ W2ext
// W2ext[i][k*32+o] = en_W2[k][i*32+o]; cols 1024..1055 hold b2 (bias term q0).
// Edges bucketed once by 32-node src tile (src>>5); per tile, one block computes
// Q for its 32 nodes in LDS (bf16, 67.6KB) and immediately consumes it for that
// tile's edges. Q never touches global memory.

#define NN 100000
#define NE 320000
#define DD 32
#define QC 1056        // 33*32 (32 k-blocks + 1 bias block)
#define NTILES 3125    // NN/32 exact
#define HB 128         // histogram blocks
#define EPB ((NE + HB - 1) / HB)   // 2500
#define SEG 13         // ceil(NTILES/256)

__device__ __forceinline__ float bf2f(unsigned short u) {
    return __uint_as_float(((unsigned int)u) << 16);
}
__device__ __forceinline__ unsigned short f2bf(float f) {
    unsigned int x = __float_as_uint(f);
    unsigned int r = (x + 0x7fffu + ((x >> 16) & 1u)) >> 16;
    return (unsigned short)r;
}

// ---- build W2ext [32][1056]
__global__ __launch_bounds__(256) void k_w2ext(const float* __restrict__ W2,
                                               const float* __restrict__ b2,
                                               float* __restrict__ W2ext) {
    int idx = blockIdx.x * 256 + threadIdx.x;
    if (idx >= 32 * QC) return;
    int i = idx / QC, c = idx % QC;
    float v;
    if (c < 1024) { int k = c >> 5, o = c & 31; v = W2[k * 1024 + i * 32 + o]; }
    else          { v = b2[i * 32 + (c - 1024)]; }
    W2ext[idx] = v;
}

// ---- node encoder + projection
__global__ __launch_bounds__(256) void k_node_enc(
    const int* __restrict__ nfeats, const float* __restrict__ emb,
    const float* __restrict__ encW, const float* __restrict__ encB,
    const float* __restrict__ projW, const float* __restrict__ projB,
    float* __restrict__ h) {
    __shared__ float sEncW[1024], sProjW[1024], sEncB[32], sProjB[32];
    __shared__ float sEmb[8][33], sNh[8][33];
    int tid = threadIdx.x;
    for (int i = tid; i < 1024; i += 256) { sEncW[i] = encW[i]; sProjW[i] = projW[i]; }
    if (tid < 32) { sEncB[tid] = encB[tid]; sProjB[tid] = projB[tid]; }
    int ln = tid >> 5, o = tid & 31;
    int node = blockIdx.x * 8 + ln;
    int nt = nfeats[node];
    sEmb[ln][o] = fmaxf(emb[nt * DD + o], 0.f);
    __syncthreads();
    float acc = sEncB[o];
    #pragma unroll
    for (int i = 0; i < 32; ++i) acc += sEmb[ln][i] * sEncW[i * 32 + o];
    sNh[ln][o] = fmaxf(acc, 0.f);
    __syncthreads();
    float acc2 = sProjB[o];
    #pragma unroll
    for (int i = 0; i < 32; ++i) acc2 += sNh[ln][i] * sProjW[i * 32 + o];
    h[node * DD + o] = fmaxf(acc2, 0.f);
}

// ---- edge encoder
__global__ __launch_bounds__(256) void k_edge_t(
    const float* __restrict__ efeats,
    const float* __restrict__ eencW, const float* __restrict__ eencB,
    const float* __restrict__ enW1, const float* __restrict__ enB1,
    float* __restrict__ t) {
    __shared__ float sEW[512], sW1[1024], sEB[32], sB1[32];
    __shared__ float sEf[8][17], sEh[8][33];
    int tid = threadIdx.x;
    for (int i = tid; i < 512; i += 256) sEW[i] = eencW[i];
    for (int i = tid; i < 1024; i += 256) sW1[i] = enW1[i];
    if (tid < 32) { sEB[tid] = eencB[tid]; sB1[tid] = enB1[tid]; }
    int ln = tid >> 5, o = tid & 31;
    int e = blockIdx.x * 8 + ln;
    if (o < 16) sEf[ln][o] = efeats[e * 16 + o];
    __syncthreads();
    float acc = sEB[o];
    #pragma unroll
    for (int i = 0; i < 16; ++i) acc += sEf[ln][i] * sEW[i * 32 + o];
    sEh[ln][o] = acc;
    __syncthreads();
    float acc2 = sB1[o];
    #pragma unroll
    for (int i = 0; i < 32; ++i) acc2 += sEh[ln][i] * sW1[i * 32 + o];
    t[e * 32 + o] = fmaxf(acc2, 0.f);
}

// ---- bucketing pass A: per-block LDS histogram over tiles
__global__ __launch_bounds__(256) void k_hist2(const int* __restrict__ src,
                                               int* __restrict__ blockCounts) {
    __shared__ int sHist[NTILES];
    int tid = threadIdx.x, b = blockIdx.x;
    for (int c = tid; c < NTILES; c += 256) sHist[c] = 0;
    __syncthreads();
    int beg = b * EPB, end = min(beg + EPB, NE);
    for (int e = beg + tid; e < end; e += 256)
        atomicAdd(&sHist[src[e] >> 5], 1);
    __syncthreads();
    for (int c = tid; c < NTILES; c += 256) blockCounts[b * NTILES + c] = sHist[c];
}

// ---- bucketing pass B: two-level scan -> offs + per-block absolute starts
__global__ __launch_bounds__(256) void k_scan2(const int* __restrict__ blockCounts,
                                               int* __restrict__ blockStart,
                                               int* __restrict__ offs) {
    __shared__ int sTot[NTILES];
    __shared__ int sPart[257];
    int tid = threadIdx.x;
    for (int c = tid; c < NTILES; c += 256) {
        int running = 0;
        for (int b = 0; b < HB; ++b) {
            blockStart[b * NTILES + c] = running;
            running += blockCounts[b * NTILES + c];
        }
        sTot[c] = running;
    }
    __syncthreads();
    // exclusive scan of sTot (contiguous SEG-sized segments per thread)
    int base = tid * SEG;
    int loc = 0;
    #pragma unroll
    for (int j = 0; j < SEG; ++j) {
        int c = base + j;
        if (c < NTILES) { int v = sTot[c]; sTot[c] = loc; loc += v; }
    }
    sPart[tid] = loc;
    __syncthreads();
    if (tid == 0) {
        int s = 0;
        for (int i = 0; i < 256; ++i) { int v = sPart[i]; sPart[i] = s; s += v; }
        sPart[256] = s;
    }
    __syncthreads();
    int add = sPart[tid];
    #pragma unroll
    for (int j = 0; j < SEG; ++j) {
        int c = base + j;
        if (c < NTILES) sTot[c] += add;
    }
    __syncthreads();
    for (int c = tid; c < NTILES; c += 256) offs[c] = sTot[c];
    if (tid == 0) offs[NTILES] = sPart[256];
    for (int b = 0; b < HB; ++b)
        for (int c = tid; c < NTILES; c += 256)
            blockStart[b * NTILES + c] += sTot[c];
}

// ---- bucketing pass C: scatter via LDS cursors
__global__ __launch_bounds__(256) void k_scatter2(const int* __restrict__ src,
                                                  const int* __restrict__ blockStart,
                                                  int* __restrict__ eperm) {
    __shared__ int sCur[NTILES];
    int tid = threadIdx.x, b = blockIdx.x;
    for (int c = tid; c < NTILES; c += 256) sCur[c] = blockStart[b * NTILES + c];
    __syncthreads();
    int beg = b * EPB, end = min(beg + EPB, NE);
    for (int e = beg + tid; e < end; e += 256) {
        int pos = atomicAdd(&sCur[src[e] >> 5], 1);
        eperm[pos] = e;
    }
}

// ---- fused: per 32-node tile, Q in LDS then consume tile's edges
__global__ __launch_bounds__(256) void k_msgF(
    const float* __restrict__ h, const float* __restrict__ W2ext,
    const float* __restrict__ t, const int* __restrict__ src, const int* __restrict__ dst,
    const int* __restrict__ eperm, const int* __restrict__ offs,
    float* __restrict__ agg) {
    __shared__ unsigned short sQ[32 * 1056];   // 67584 B; stride 1056 shorts (S%64==32)
    __shared__ float sW[1024];                 // W2ext 32-col slice
    __shared__ float sT[32 * 33];              // h rows (Q phase) then t rows (edge phase)
    __shared__ int sRow[32], sDst[32], sEdge[32];
    int tid = threadIdx.x;
    int tile = blockIdx.x;
    int beg = offs[tile], end = offs[tile + 1];
    if (beg >= end) return;                    // no outgoing edges: Q unused
    int nodeBase = tile * 32;
    int m = tid >> 3, l8 = tid & 7;

    // stage h tile (coalesced) then copy own row to regs
    for (int idx = tid; idx < 1024; idx += 256)
        sT[(idx >> 5) * 33 + (idx & 31)] = h[(size_t)nodeBase * 32 + idx];
    __syncthreads();
    float hr[32];
    {
        const float* hp = sT + m * 33;
        #pragma unroll
        for (int i = 0; i < 32; ++i) hr[i] = hp[i];
    }
    // Q phase: 33 column groups of 32
    for (int cg = 0; cg < 33; ++cg) {
        __syncthreads();
        for (int idx = tid; idx < 1024; idx += 256)
            sW[idx] = W2ext[(idx >> 5) * QC + cg * 32 + (idx & 31)];
        __syncthreads();
        float a0 = 0.f, a1 = 0.f, a2 = 0.f, a3 = 0.f;
        const float* wp = sW + l8 * 4;
        #pragma unroll 8
        for (int i = 0; i < 32; ++i) {
            float4 w = *(const float4*)(wp + i * 32);   // broadcast across m-groups
            float x = hr[i];
            a0 += x * w.x; a1 += x * w.y; a2 += x * w.z; a3 += x * w.w;
        }
        ushort4 qv;
        qv.x = f2bf(a0); qv.y = f2bf(a1); qv.z = f2bf(a2); qv.w = f2bf(a3);
        *(ushort4*)(sQ + m * 1056 + cg * 32 + l8 * 4) = qv;
    }
    __syncthreads();

    // edge phase: 32 edges per iteration
    for (int s0 = beg; s0 < end; s0 += 32) {
        int nact = min(32, end - s0);
        if (tid < nact) {
            int e = eperm[s0 + tid];
            sEdge[tid] = e;
            sRow[tid] = src[e] - nodeBase;
            sDst[tid] = dst[e];
        }
        __syncthreads();
        for (int idx = tid; idx < (nact << 5); idx += 256) {
            int el = idx >> 5, k = idx & 31;
            sT[el * 33 + k] = t[(size_t)sEdge[el] * 32 + k];
        }
        __syncthreads();
        int el = tid >> 3;
        if (el < nact) {
            const unsigned short* qp = sQ + sRow[el] * 1056 + l8 * 4;
            const float* tp = sT + el * 33;
            float a0 = 0.f, a1 = 0.f, a2 = 0.f, a3 = 0.f;
            #pragma unroll 8
            for (int k = 0; k < 32; ++k) {
                float tk = tp[k];
                ushort4 q = *(const ushort4*)(qp + k * 32);
                a0 += tk * bf2f(q.x); a1 += tk * bf2f(q.y);
                a2 += tk * bf2f(q.z); a3 += tk * bf2f(q.w);
            }
            ushort4 qb = *(const ushort4*)(qp + 1024);
            a0 += bf2f(qb.x); a1 += bf2f(qb.y); a2 += bf2f(qb.z); a3 += bf2f(qb.w);
            float* ap = agg + (size_t)sDst[el] * 32 + l8 * 4;
            atomicAdd(ap + 0, a0); atomicAdd(ap + 1, a1);
            atomicAdd(ap + 2, a2); atomicAdd(ap + 3, a3);
        }
        __syncthreads();
    }
}

// ---- fallback msg (tiny ws): recompute We per edge
__global__ __launch_bounds__(256) void k_msgC(
    const float* __restrict__ t, const int* __restrict__ src, const int* __restrict__ dst,
    const float* __restrict__ h, const float* __restrict__ W2ext, float* __restrict__ agg) {
    __shared__ float sT[32][33], sH[32][33];
    __shared__ int sSrc[32], sDst[32];
    int tid = threadIdx.x;
    int e0 = blockIdx.x * 32;
    if (tid < 32) sSrc[tid] = src[e0 + tid];
    else if (tid < 64) sDst[tid - 32] = dst[e0 + tid - 32];
    __syncthreads();
    for (int idx = tid; idx < 1024; idx += 256) {
        int el = idx >> 5, k = idx & 31;
        sT[el][k] = t[(e0 + el) * 32 + k];
        sH[el][k] = h[(size_t)sSrc[el] * 32 + k];
    }
    __syncthreads();
    int el = tid >> 3, l8 = tid & 7;
    int c0 = l8 * 4;
    float m0 = 0.f, m1 = 0.f, m2 = 0.f, m3 = 0.f;
    for (int i = 0; i < 32; ++i) {
        const float* wrow = W2ext + i * QC;
        float4 wb = *(const float4*)(wrow + 1024 + c0);
        float w0 = wb.x, w1 = wb.y, w2 = wb.z, w3 = wb.w;
        #pragma unroll 8
        for (int k = 0; k < 32; ++k) {
            float tk = sT[el][k];
            float4 w = *(const float4*)(wrow + k * 32 + c0);
            w0 += tk * w.x; w1 += tk * w.y; w2 += tk * w.z; w3 += tk * w.w;
        }
        float hi = sH[el][i];
        m0 += hi * w0; m1 += hi * w1; m2 += hi * w2; m3 += hi * w3;
    }
    float* ap = agg + (size_t)sDst[el] * 32 + c0;
    atomicAdd(ap + 0, m0); atomicAdd(ap + 1, m1);
    atomicAdd(ap + 2, m2); atomicAdd(ap + 3, m3);
}

// ---- GRU step, 32 nodes/block
__global__ __launch_bounds__(256) void k_gru(
    const float* __restrict__ agg, const float* __restrict__ convB,
    const float* __restrict__ Wi, const float* __restrict__ Wh,
    const float* __restrict__ bi, const float* __restrict__ bh,
    float* __restrict__ h) {
    __shared__ float sWi[3072], sWh[3072], sBi[96], sBh[96], sCb[32];
    __shared__ float sX[8][33], sH[8][33];
    int tid = threadIdx.x;
    for (int i = tid; i < 3072; i += 256) { sWi[i] = Wi[i]; sWh[i] = Wh[i]; }
    if (tid < 96) { sBi[tid] = bi[tid]; sBh[tid] = bh[tid]; }
    if (tid < 32) sCb[tid] = convB[tid];
    int ln = tid >> 5, o = tid & 31;
    for (int g = 0; g < 4; ++g) {
        int node = blockIdx.x * 32 + g * 8 + ln;
        float hv = h[node * 32 + o];
        float av = agg[node * 32 + o];
        __syncthreads();
        sX[ln][o] = fmaxf(av + sCb[o], 0.f);
        sH[ln][o] = hv;
        __syncthreads();
        float air = sBi[o], aiz = sBi[o + 32], ain = sBi[o + 64];
        float ahr = sBh[o], ahz = sBh[o + 32], ahn = sBh[o + 64];
        #pragma unroll 8
        for (int i = 0; i < 32; ++i) {
            float x = sX[ln][i], hh = sH[ln][i];
            air += x * sWi[i * 96 + o];      ahr += hh * sWh[i * 96 + o];
            aiz += x * sWi[i * 96 + o + 32]; ahz += hh * sWh[i * 96 + o + 32];
            ain += x * sWi[i * 96 + o + 64]; ahn += hh * sWh[i * 96 + o + 64];
        }
        float r = 1.f / (1.f + __expf(-(air + ahr)));
        float z = 1.f / (1.f + __expf(-(aiz + ahz)));
        float ng = tanhf(ain + r * ahn);
        h[node * 32 + o] = (1.f - z) * ng + z * hv;
    }
}

// ---- decoder
__global__ __launch_bounds__(256) void k_dec(
    const float* __restrict__ h,
    const float* __restrict__ W1, const float* __restrict__ b1, const float* __restrict__ a1,
    const float* __restrict__ W2, const float* __restrict__ b2, const float* __restrict__ a2,
    const float* __restrict__ W3, const float* __restrict__ b3, const float* __restrict__ a3,
    const float* __restrict__ W4, const float* __restrict__ b4,
    float* __restrict__ out) {
    __shared__ float sW1[1024], sW2[1024], sW3[1024], sW4[96];
    __shared__ float sB1[32], sB2[32], sB3[32], sB4[3];
    __shared__ float sYa[8][33], sYb[8][33];
    int tid = threadIdx.x;
    for (int i = tid; i < 1024; i += 256) { sW1[i] = W1[i]; sW2[i] = W2[i]; sW3[i] = W3[i]; }
    if (tid < 96) sW4[tid] = W4[tid];
    if (tid < 32) { sB1[tid] = b1[tid]; sB2[tid] = b2[tid]; sB3[tid] = b3[tid]; }
    if (tid < 3) sB4[tid] = b4[tid];
    float A1 = a1[0], A2 = a2[0], A3 = a3[0];
    int ln = tid >> 5, o = tid & 31;
    int node = blockIdx.x * 8 + ln;
    sYa[ln][o] = h[node * 32 + o];
    __syncthreads();
    float acc = sB1[o];
    #pragma unroll
    for (int i = 0; i < 32; ++i) acc += sYa[ln][i] * sW1[i * 32 + o];
    acc = acc >= 0.f ? acc : A1 * acc;
    sYb[ln][o] = acc;
    __syncthreads();
    acc = sB2[o];
    #pragma unroll
    for (int i = 0; i < 32; ++i) acc += sYb[ln][i] * sW2[i * 32 + o];
    acc = acc >= 0.f ? acc : A2 * acc;
    __syncthreads();
    sYa[ln][o] = acc;
    __syncthreads();
    acc = sB3[o];
    #pragma unroll
    for (int i = 0; i < 32; ++i) acc += sYa[ln][i] * sW3[i * 32 + o];
    acc = acc >= 0.f ? acc : A3 * acc;
    __syncthreads();
    sYb[ln][o] = acc;
    __syncthreads();
    if (o < 3) {
        float r = sB4[o];
        #pragma unroll
        for (int i = 0; i < 32; ++i) r += sYb[ln][i] * sW4[i * 3 + o];
        out[node * 3 + o] = r;
    }
}

extern "C" void kernel_launch(void* const* d_in, const int* in_sizes, int n_in,
                              void* d_out, int out_size, void* d_ws, size_t ws_size,
                              hipStream_t stream) {
    const int*   nfeats = (const int*)d_in[0];
    const float* efeats = (const float*)d_in[1];
    const int*   src    = (const int*)d_in[2];
    const int*   dst    = (const int*)d_in[3];
    const float* emb    = (const float*)d_in[4];
    const float* encW   = (const float*)d_in[5];
    const float* encB   = (const float*)d_in[6];
    const float* eencW  = (const float*)d_in[7];
    const float* eencB  = (const float*)d_in[8];
    const float* projW  = (const float*)d_in[9];
    const float* projB  = (const float*)d_in[10];
    const float* enW1   = (const float*)d_in[11];
    const float* enB1   = (const float*)d_in[12];
    const float* enW2   = (const float*)d_in[13];
    const float* enB2   = (const float*)d_in[14];
    const float* convB  = (const float*)d_in[15];
    const float* gruWi  = (const float*)d_in[16];
    const float* gruWh  = (const float*)d_in[17];
    const float* gruBi  = (const float*)d_in[18];
    const float* gruBh  = (const float*)d_in[19];
    const float* dW1 = (const float*)d_in[20]; const float* db1 = (const float*)d_in[21]; const float* da1 = (const float*)d_in[22];
    const float* dW2 = (const float*)d_in[23]; const float* db2 = (const float*)d_in[24]; const float* da2 = (const float*)d_in[25];
    const float* dW3 = (const float*)d_in[26]; const float* db3 = (const float*)d_in[27]; const float* da3 = (const float*)d_in[28];
    const float* dW4 = (const float*)d_in[29]; const float* db4 = (const float*)d_in[30];
    float* out = (float*)d_out;

    float* h     = (float*)d_ws;                       // NN*32
    float* t     = h + (size_t)NN * 32;                // NE*32
    float* agg   = t + (size_t)NE * 32;                // NN*32
    float* W2ext = agg + (size_t)NN * 32;              // 32*QC
    int* eperm       = (int*)(W2ext + 32 * QC);        // NE
    int* blockCounts = eperm + NE;                     // HB*NTILES
    int* blockStart  = blockCounts + (size_t)HB * NTILES;  // HB*NTILES
    int* offs        = blockStart + (size_t)HB * NTILES;   // NTILES+1
    size_t need = ((char*)(offs + NTILES + 1) - (char*)d_ws);
    bool useF = (ws_size >= need);

    k_w2ext<<<(32 * QC + 255) / 256, 256, 0, stream>>>(enW2, enB2, W2ext);
    k_node_enc<<<NN / 8, 256, 0, stream>>>(nfeats, emb, encW, encB, projW, projB, h);
    k_edge_t<<<NE / 8, 256, 0, stream>>>(efeats, eencW, eencB, enW1, enB1, t);

    if (useF) {
        k_hist2<<<HB, 256, 0, stream>>>(src, blockCounts);
        k_scan2<<<1, 256, 0, stream>>>(blockCounts, blockStart, offs);
        k_scatter2<<<HB, 256, 0, stream>>>(src, blockStart, eperm);
    }

    for (int s = 0; s < 3; ++s) {
        hipMemsetAsync(agg, 0, (size_t)NN * 32 * 4, stream);
        if (useF) {
            k_msgF<<<NTILES, 256, 0, stream>>>(h, W2ext, t, src, dst, eperm, offs, agg);
        } else {
            k_msgC<<<NE / 32, 256, 0, stream>>>(t, src, dst, h, W2ext, agg);
        }
        k_gru<<<NN / 32, 256, 0, stream>>>(agg, convB, gruWi, gruWh, gruBi, gruBh, h);
    }
    k_dec<<<NN / 8, 256, 0, stream>>>(h, dW1, db1, da1, dW2, db2, da2, dW3, db3, da3, dW4, db4, out);
}

// Round 5
// 1541.754 us; speedup vs baseline: 1.3648x; 1.3648x over previous
//
#include <hip/hip_runtime.h>
#include <hip/hip_bf16.h>

// MPNN on MI355X — fused tile kernel.
// msg[e,o] = sum_k t[e,k]*Q[src,k,o] + q0[src,o],  Q[n] = h[n] @ W2ext
// W2ext[i][k*32+o] = en_W2[k][i*32+o]; cols 1024..1055 hold b2 (bias term q0).
// Edges bucketed once by 32-node src tile (src>>5); per tile, one block computes
// Q for its 32 nodes in LDS (bf16, 67.6KB) and immediately consumes it for that
// tile's edges. Q never touches global memory.
// Bucketing scan is fully parallel: colsum (13 blocks) -> LDS scan (1 block).

#define NN 100000
#define NE 320000
#define DD 32
#define QC 1056        // 33*32 (32 k-blocks + 1 bias block)
#define NTILES 3125    // NN/32 exact
#define HB 128         // histogram blocks
#define EPB ((NE + HB - 1) / HB)   // 2500
#define SEG 13         // ceil(NTILES/256)

__device__ __forceinline__ float bf2f(unsigned short u) {
    return __uint_as_float(((unsigned int)u) << 16);
}
__device__ __forceinline__ unsigned short f2bf(float f) {
    unsigned int x = __float_as_uint(f);
    unsigned int r = (x + 0x7fffu + ((x >> 16) & 1u)) >> 16;
    return (unsigned short)r;
}

// ---- build W2ext [32][1056]
__global__ __launch_bounds__(256) void k_w2ext(const float* __restrict__ W2,
                                               const float* __restrict__ b2,
                                               float* __restrict__ W2ext) {
    int idx = blockIdx.x * 256 + threadIdx.x;
    if (idx >= 32 * QC) return;
    int i = idx / QC, c = idx % QC;
    float v;
    if (c < 1024) { int k = c >> 5, o = c & 31; v = W2[k * 1024 + i * 32 + o]; }
    else          { v = b2[i * 32 + (c - 1024)]; }
    W2ext[idx] = v;
}

// ---- node encoder + projection
__global__ __launch_bounds__(256) void k_node_enc(
    const int* __restrict__ nfeats, const float* __restrict__ emb,
    const float* __restrict__ encW, const float* __restrict__ encB,
    const float* __restrict__ projW, const float* __restrict__ projB,
    float* __restrict__ h) {
    __shared__ float sEncW[1024], sProjW[1024], sEncB[32], sProjB[32];
    __shared__ float sEmb[8][33], sNh[8][33];
    int tid = threadIdx.x;
    for (int i = tid; i < 1024; i += 256) { sEncW[i] = encW[i]; sProjW[i] = projW[i]; }
    if (tid < 32) { sEncB[tid] = encB[tid]; sProjB[tid] = projB[tid]; }
    int ln = tid >> 5, o = tid & 31;
    int node = blockIdx.x * 8 + ln;
    int nt = nfeats[node];
    sEmb[ln][o] = fmaxf(emb[nt * DD + o], 0.f);
    __syncthreads();
    float acc = sEncB[o];
    #pragma unroll
    for (int i = 0; i < 32; ++i) acc += sEmb[ln][i] * sEncW[i * 32 + o];
    sNh[ln][o] = fmaxf(acc, 0.f);
    __syncthreads();
    float acc2 = sProjB[o];
    #pragma unroll
    for (int i = 0; i < 32; ++i) acc2 += sNh[ln][i] * sProjW[i * 32 + o];
    h[node * DD + o] = fmaxf(acc2, 0.f);
}

// ---- edge encoder
__global__ __launch_bounds__(256) void k_edge_t(
    const float* __restrict__ efeats,
    const float* __restrict__ eencW, const float* __restrict__ eencB,
    const float* __restrict__ enW1, const float* __restrict__ enB1,
    float* __restrict__ t) {
    __shared__ float sEW[512], sW1[1024], sEB[32], sB1[32];
    __shared__ float sEf[8][17], sEh[8][33];
    int tid = threadIdx.x;
    for (int i = tid; i < 512; i += 256) sEW[i] = eencW[i];
    for (int i = tid; i < 1024; i += 256) sW1[i] = enW1[i];
    if (tid < 32) { sEB[tid] = eencB[tid]; sB1[tid] = enB1[tid]; }
    int ln = tid >> 5, o = tid & 31;
    int e = blockIdx.x * 8 + ln;
    if (o < 16) sEf[ln][o] = efeats[e * 16 + o];
    __syncthreads();
    float acc = sEB[o];
    #pragma unroll
    for (int i = 0; i < 16; ++i) acc += sEf[ln][i] * sEW[i * 32 + o];
    sEh[ln][o] = acc;
    __syncthreads();
    float acc2 = sB1[o];
    #pragma unroll
    for (int i = 0; i < 32; ++i) acc2 += sEh[ln][i] * sW1[i * 32 + o];
    t[e * 32 + o] = fmaxf(acc2, 0.f);
}

// ---- bucketing pass A: per-block LDS histogram over tiles
__global__ __launch_bounds__(256) void k_hist2(const int* __restrict__ src,
                                               int* __restrict__ blockCounts) {
    __shared__ int sHist[NTILES];
    int tid = threadIdx.x, b = blockIdx.x;
    for (int c = tid; c < NTILES; c += 256) sHist[c] = 0;
    __syncthreads();
    int beg = b * EPB, end = min(beg + EPB, NE);
    for (int e = beg + tid; e < end; e += 256)
        atomicAdd(&sHist[src[e] >> 5], 1);
    __syncthreads();
    for (int c = tid; c < NTILES; c += 256) blockCounts[b * NTILES + c] = sHist[c];
}

// ---- pass B1: per-tile column sums + per-block relative starts (coalesced)
__global__ __launch_bounds__(256) void k_colsum(const int* __restrict__ blockCounts,
                                                int* __restrict__ blockStart,
                                                int* __restrict__ tileTot) {
    int c = blockIdx.x * 256 + threadIdx.x;
    if (c >= NTILES) return;
    int running = 0;
    #pragma unroll 8
    for (int b = 0; b < HB; ++b) {
        blockStart[b * NTILES + c] = running;
        running += blockCounts[b * NTILES + c];
    }
    tileTot[c] = running;
}

// ---- pass B2: exclusive scan of tile totals (pure LDS, single block)
__global__ __launch_bounds__(256) void k_scan1(const int* __restrict__ tileTot,
                                               int* __restrict__ offs) {
    __shared__ int sTot[NTILES];
    __shared__ int sPart[257];
    int tid = threadIdx.x;
    for (int c = tid; c < NTILES; c += 256) sTot[c] = tileTot[c];
    __syncthreads();
    int base = tid * SEG;
    int loc = 0;
    #pragma unroll
    for (int j = 0; j < SEG; ++j) {
        int c = base + j;
        if (c < NTILES) { int v = sTot[c]; sTot[c] = loc; loc += v; }
    }
    sPart[tid] = loc;
    __syncthreads();
    if (tid == 0) {
        int s = 0;
        for (int i = 0; i < 256; ++i) { int v = sPart[i]; sPart[i] = s; s += v; }
        sPart[256] = s;
    }
    __syncthreads();
    int add = sPart[tid];
    #pragma unroll
    for (int j = 0; j < SEG; ++j) {
        int c = base + j;
        if (c < NTILES) sTot[c] += add;
    }
    __syncthreads();
    for (int c = tid; c < NTILES; c += 256) offs[c] = sTot[c];
    if (tid == 0) offs[NTILES] = sPart[256];
}

// ---- bucketing pass C: scatter via LDS cursors (absolute = offs + relative)
__global__ __launch_bounds__(256) void k_scatter2(const int* __restrict__ src,
                                                  const int* __restrict__ blockStart,
                                                  const int* __restrict__ offs,
                                                  int* __restrict__ eperm) {
    __shared__ int sCur[NTILES];
    int tid = threadIdx.x, b = blockIdx.x;
    for (int c = tid; c < NTILES; c += 256)
        sCur[c] = offs[c] + blockStart[b * NTILES + c];
    __syncthreads();
    int beg = b * EPB, end = min(beg + EPB, NE);
    for (int e = beg + tid; e < end; e += 256) {
        int pos = atomicAdd(&sCur[src[e] >> 5], 1);
        eperm[pos] = e;
    }
}

// ---- fused: per 32-node tile, Q in LDS then consume tile's edges
__global__ __launch_bounds__(256) void k_msgF(
    const float* __restrict__ h, const float* __restrict__ W2ext,
    const float* __restrict__ t, const int* __restrict__ src, const int* __restrict__ dst,
    const int* __restrict__ eperm, const int* __restrict__ offs,
    float* __restrict__ agg) {
    __shared__ unsigned short sQ[32 * 1056];   // 67584 B; stride 1056 shorts (S%64==32)
    __shared__ float sW[1024];                 // W2ext 32-col slice
    __shared__ float sT[32 * 33];              // h rows (Q phase) then t rows (edge phase)
    __shared__ int sRow[32], sDst[32], sEdge[32];
    int tid = threadIdx.x;
    int tile = blockIdx.x;
    int beg = offs[tile], end = offs[tile + 1];
    if (beg >= end) return;                    // no outgoing edges: Q unused
    int nodeBase = tile * 32;
    int m = tid >> 3, l8 = tid & 7;

    // stage h tile (coalesced) then copy own row to regs
    for (int idx = tid; idx < 1024; idx += 256)
        sT[(idx >> 5) * 33 + (idx & 31)] = h[(size_t)nodeBase * 32 + idx];
    __syncthreads();
    float hr[32];
    {
        const float* hp = sT + m * 33;
        #pragma unroll
        for (int i = 0; i < 32; ++i) hr[i] = hp[i];
    }
    // Q phase: 33 column groups of 32
    for (int cg = 0; cg < 33; ++cg) {
        __syncthreads();
        for (int idx = tid; idx < 1024; idx += 256)
            sW[idx] = W2ext[(idx >> 5) * QC + cg * 32 + (idx & 31)];
        __syncthreads();
        float a0 = 0.f, a1 = 0.f, a2 = 0.f, a3 = 0.f;
        const float* wp = sW + l8 * 4;
        #pragma unroll 8
        for (int i = 0; i < 32; ++i) {
            float4 w = *(const float4*)(wp + i * 32);   // broadcast across m-groups
            float x = hr[i];
            a0 += x * w.x; a1 += x * w.y; a2 += x * w.z; a3 += x * w.w;
        }
        ushort4 qv;
        qv.x = f2bf(a0); qv.y = f2bf(a1); qv.z = f2bf(a2); qv.w = f2bf(a3);
        *(ushort4*)(sQ + m * 1056 + cg * 32 + l8 * 4) = qv;
    }
    __syncthreads();

    // edge phase: 32 edges per iteration
    for (int s0 = beg; s0 < end; s0 += 32) {
        int nact = min(32, end - s0);
        if (tid < nact) {
            int e = eperm[s0 + tid];
            sEdge[tid] = e;
            sRow[tid] = src[e] - nodeBase;
            sDst[tid] = dst[e];
        }
        __syncthreads();
        for (int idx = tid; idx < (nact << 5); idx += 256) {
            int el = idx >> 5, k = idx & 31;
            sT[el * 33 + k] = t[(size_t)sEdge[el] * 32 + k];
        }
        __syncthreads();
        int el = tid >> 3;
        if (el < nact) {
            const unsigned short* qp = sQ + sRow[el] * 1056 + l8 * 4;
            const float* tp = sT + el * 33;
            float a0 = 0.f, a1 = 0.f, a2 = 0.f, a3 = 0.f;
            #pragma unroll 8
            for (int k = 0; k < 32; ++k) {
                float tk = tp[k];
                ushort4 q = *(const ushort4*)(qp + k * 32);
                a0 += tk * bf2f(q.x); a1 += tk * bf2f(q.y);
                a2 += tk * bf2f(q.z); a3 += tk * bf2f(q.w);
            }
            ushort4 qb = *(const ushort4*)(qp + 1024);
            a0 += bf2f(qb.x); a1 += bf2f(qb.y); a2 += bf2f(qb.z); a3 += bf2f(qb.w);
            float* ap = agg + (size_t)sDst[el] * 32 + l8 * 4;
            atomicAdd(ap + 0, a0); atomicAdd(ap + 1, a1);
            atomicAdd(ap + 2, a2); atomicAdd(ap + 3, a3);
        }
        __syncthreads();
    }
}

// ---- fallback msg (tiny ws): recompute We per edge
__global__ __launch_bounds__(256) void k_msgC(
    const float* __restrict__ t, const int* __restrict__ src, const int* __restrict__ dst,
    const float* __restrict__ h, const float* __restrict__ W2ext, float* __restrict__ agg) {
    __shared__ float sT[32][33], sH[32][33];
    __shared__ int sSrc[32], sDst[32];
    int tid = threadIdx.x;
    int e0 = blockIdx.x * 32;
    if (tid < 32) sSrc[tid] = src[e0 + tid];
    else if (tid < 64) sDst[tid - 32] = dst[e0 + tid - 32];
    __syncthreads();
    for (int idx = tid; idx < 1024; idx += 256) {
        int el = idx >> 5, k = idx & 31;
        sT[el][k] = t[(e0 + el) * 32 + k];
        sH[el][k] = h[(size_t)sSrc[el] * 32 + k];
    }
    __syncthreads();
    int el = tid >> 3, l8 = tid & 7;
    int c0 = l8 * 4;
    float m0 = 0.f, m1 = 0.f, m2 = 0.f, m3 = 0.f;
    for (int i = 0; i < 32; ++i) {
        const float* wrow = W2ext + i * QC;
        float4 wb = *(const float4*)(wrow + 1024 + c0);
        float w0 = wb.x, w1 = wb.y, w2 = wb.z, w3 = wb.w;
        #pragma unroll 8
        for (int k = 0; k < 32; ++k) {
            float tk = sT[el][k];
            float4 w = *(const float4*)(wrow + k * 32 + c0);
            w0 += tk * w.x; w1 += tk * w.y; w2 += tk * w.z; w3 += tk * w.w;
        }
        float hi = sH[el][i];
        m0 += hi * w0; m1 += hi * w1; m2 += hi * w2; m3 += hi * w3;
    }
    float* ap = agg + (size_t)sDst[el] * 32 + c0;
    atomicAdd(ap + 0, m0); atomicAdd(ap + 1, m1);
    atomicAdd(ap + 2, m2); atomicAdd(ap + 3, m3);
}

// ---- GRU step, 32 nodes/block
__global__ __launch_bounds__(256) void k_gru(
    const float* __restrict__ agg, const float* __restrict__ convB,
    const float* __restrict__ Wi, const float* __restrict__ Wh,
    const float* __restrict__ bi, const float* __restrict__ bh,
    float* __restrict__ h) {
    __shared__ float sWi[3072], sWh[3072], sBi[96], sBh[96], sCb[32];
    __shared__ float sX[8][33], sH[8][33];
    int tid = threadIdx.x;
    for (int i = tid; i < 3072; i += 256) { sWi[i] = Wi[i]; sWh[i] = Wh[i]; }
    if (tid < 96) { sBi[tid] = bi[tid]; sBh[tid] = bh[tid]; }
    if (tid < 32) sCb[tid] = convB[tid];
    int ln = tid >> 5, o = tid & 31;
    for (int g = 0; g < 4; ++g) {
        int node = blockIdx.x * 32 + g * 8 + ln;
        float hv = h[node * 32 + o];
        float av = agg[node * 32 + o];
        __syncthreads();
        sX[ln][o] = fmaxf(av + sCb[o], 0.f);
        sH[ln][o] = hv;
        __syncthreads();
        float air = sBi[o], aiz = sBi[o + 32], ain = sBi[o + 64];
        float ahr = sBh[o], ahz = sBh[o + 32], ahn = sBh[o + 64];
        #pragma unroll 8
        for (int i = 0; i < 32; ++i) {
            float x = sX[ln][i], hh = sH[ln][i];
            air += x * sWi[i * 96 + o];      ahr += hh * sWh[i * 96 + o];
            aiz += x * sWi[i * 96 + o + 32]; ahz += hh * sWh[i * 96 + o + 32];
            ain += x * sWi[i * 96 + o + 64]; ahn += hh * sWh[i * 96 + o + 64];
        }
        float r = 1.f / (1.f + __expf(-(air + ahr)));
        float z = 1.f / (1.f + __expf(-(aiz + ahz)));
        float ng = tanhf(ain + r * ahn);
        h[node * 32 + o] = (1.f - z) * ng + z * hv;
    }
}

// ---- decoder
__global__ __launch_bounds__(256) void k_dec(
    const float* __restrict__ h,
    const float* __restrict__ W1, const float* __restrict__ b1, const float* __restrict__ a1,
    const float* __restrict__ W2, const float* __restrict__ b2, const float* __restrict__ a2,
    const float* __restrict__ W3, const float* __restrict__ b3, const float* __restrict__ a3,
    const float* __restrict__ W4, const float* __restrict__ b4,
    float* __restrict__ out) {
    __shared__ float sW1[1024], sW2[1024], sW3[1024], sW4[96];
    __shared__ float sB1[32], sB2[32], sB3[32], sB4[3];
    __shared__ float sYa[8][33], sYb[8][33];
    int tid = threadIdx.x;
    for (int i = tid; i < 1024; i += 256) { sW1[i] = W1[i]; sW2[i] = W2[i]; sW3[i] = W3[i]; }
    if (tid < 96) sW4[tid] = W4[tid];
    if (tid < 32) { sB1[tid] = b1[tid]; sB2[tid] = b2[tid]; sB3[tid] = b3[tid]; }
    if (tid < 3) sB4[tid] = b4[tid];
    float A1 = a1[0], A2 = a2[0], A3 = a3[0];
    int ln = tid >> 5, o = tid & 31;
    int node = blockIdx.x * 8 + ln;
    sYa[ln][o] = h[node * 32 + o];
    __syncthreads();
    float acc = sB1[o];
    #pragma unroll
    for (int i = 0; i < 32; ++i) acc += sYa[ln][i] * sW1[i * 32 + o];
    acc = acc >= 0.f ? acc : A1 * acc;
    sYb[ln][o] = acc;
    __syncthreads();
    acc = sB2[o];
    #pragma unroll
    for (int i = 0; i < 32; ++i) acc += sYb[ln][i] * sW2[i * 32 + o];
    acc = acc >= 0.f ? acc : A2 * acc;
    __syncthreads();
    sYa[ln][o] = acc;
    __syncthreads();
    acc = sB3[o];
    #pragma unroll
    for (int i = 0; i < 32; ++i) acc += sYa[ln][i] * sW3[i * 32 + o];
    acc = acc >= 0.f ? acc : A3 * acc;
    __syncthreads();
    sYb[ln][o] = acc;
    __syncthreads();
    if (o < 3) {
        float r = sB4[o];
        #pragma unroll
        for (int i = 0; i < 32; ++i) r += sYb[ln][i] * sW4[i * 3 + o];
        out[node * 3 + o] = r;
    }
}

extern "C" void kernel_launch(void* const* d_in, const int* in_sizes, int n_in,
                              void* d_out, int out_size, void* d_ws, size_t ws_size,
                              hipStream_t stream) {
    const int*   nfeats = (const int*)d_in[0];
    const float* efeats = (const float*)d_in[1];
    const int*   src    = (const int*)d_in[2];
    const int*   dst    = (const int*)d_in[3];
    const float* emb    = (const float*)d_in[4];
    const float* encW   = (const float*)d_in[5];
    const float* encB   = (const float*)d_in[6];
    const float* eencW  = (const float*)d_in[7];
    const float* eencB  = (const float*)d_in[8];
    const float* projW  = (const float*)d_in[9];
    const float* projB  = (const float*)d_in[10];
    const float* enW1   = (const float*)d_in[11];
    const float* enB1   = (const float*)d_in[12];
    const float* enW2   = (const float*)d_in[13];
    const float* enB2   = (const float*)d_in[14];
    const float* convB  = (const float*)d_in[15];
    const float* gruWi  = (const float*)d_in[16];
    const float* gruWh  = (const float*)d_in[17];
    const float* gruBi  = (const float*)d_in[18];
    const float* gruBh  = (const float*)d_in[19];
    const float* dW1 = (const float*)d_in[20]; const float* db1 = (const float*)d_in[21]; const float* da1 = (const float*)d_in[22];
    const float* dW2 = (const float*)d_in[23]; const float* db2 = (const float*)d_in[24]; const float* da2 = (const float*)d_in[25];
    const float* dW3 = (const float*)d_in[26]; const float* db3 = (const float*)d_in[27]; const float* da3 = (const float*)d_in[28];
    const float* dW4 = (const float*)d_in[29]; const float* db4 = (const float*)d_in[30];
    float* out = (float*)d_out;

    float* h     = (float*)d_ws;                       // NN*32
    float* t     = h + (size_t)NN * 32;                // NE*32
    float* agg   = t + (size_t)NE * 32;                // NN*32
    float* W2ext = agg + (size_t)NN * 32;              // 32*QC
    int* eperm       = (int*)(W2ext + 32 * QC);        // NE
    int* blockCounts = eperm + NE;                     // HB*NTILES
    int* blockStart  = blockCounts + (size_t)HB * NTILES;  // HB*NTILES
    int* offs        = blockStart + (size_t)HB * NTILES;   // NTILES+1
    int* tileTot     = offs + NTILES + 1;              // NTILES
    size_t need = ((char*)(tileTot + NTILES) - (char*)d_ws);
    bool useF = (ws_size >= need);

    k_w2ext<<<(32 * QC + 255) / 256, 256, 0, stream>>>(enW2, enB2, W2ext);
    k_node_enc<<<NN / 8, 256, 0, stream>>>(nfeats, emb, encW, encB, projW, projB, h);
    k_edge_t<<<NE / 8, 256, 0, stream>>>(efeats, eencW, eencB, enW1, enB1, t);

    if (useF) {
        k_hist2<<<HB, 256, 0, stream>>>(src, blockCounts);
        k_colsum<<<(NTILES + 255) / 256, 256, 0, stream>>>(blockCounts, blockStart, tileTot);
        k_scan1<<<1, 256, 0, stream>>>(tileTot, offs);
        k_scatter2<<<HB, 256, 0, stream>>>(src, blockStart, offs, eperm);
    }

    for (int s = 0; s < 3; ++s) {
        hipMemsetAsync(agg, 0, (size_t)NN * 32 * 4, stream);
        if (useF) {
            k_msgF<<<NTILES, 256, 0, stream>>>(h, W2ext, t, src, dst, eperm, offs, agg);
        } else {
            k_msgC<<<NE / 32, 256, 0, stream>>>(t, src, dst, h, W2ext, agg);
        }
        k_gru<<<NN / 32, 256, 0, stream>>>(agg, convB, gruWi, gruWh, gruBi, gruBh, h);
    }
    k_dec<<<NN / 8, 256, 0, stream>>>(h, dW1, db1, da1, dW2, db2, da2, dW3, db3, da3, dW4, db4, out);
}

// Round 6
// 919.810 us; speedup vs baseline: 2.2876x; 1.6762x over previous
//
#include <hip/hip_runtime.h>
#include <hip/hip_bf16.h>

// MPNN on MI355X — fused tile kernel, MFMA Q-phase, dst-sorted aggregation.
// msg[e,o] = sum_k t[e,k]*Q[src,k,o] + q0[src,o],  Q[n] = h[n] @ W2ext
// W2ext[i][c]: c=kk*32+o -> W2[kk][i*32+o]; c=1024+o -> b2[i*32+o].
// Src-tiles of 8 nodes: one block MFMAs Q (8x1056 fp32) into LDS (stride 1060
// words == 4 mod 32 -> conflict-free rows), then streams the tile's edges.
// Edges also bucketed by dst tile (32 nodes): k_msgF8 writes each msg to its
// dst-sorted slot; k_gruAgg segment-sums + GRU per dst tile. No global atomics.

#define NN 100000
#define NE 320000
#define QC 1056
#define NT_S 12500     // NN/8
#define NT_D 3125      // NN/32
#define HB 64          // bucketing blocks
#define EPB (NE / HB)  // 5000
#define QSTR 1060      // sQ row stride (floats), 1060 % 32 == 4

typedef short bf16x8 __attribute__((ext_vector_type(8)));
typedef float f32x4  __attribute__((ext_vector_type(4)));

__device__ __forceinline__ unsigned short f2bf(float f) {
    unsigned int x = __float_as_uint(f);
    unsigned int r = (x + 0x7fffu + ((x >> 16) & 1u)) >> 16;
    return (unsigned short)r;
}

// ---- build W2ext [32][1056] (fp32, fallback path only)
__global__ __launch_bounds__(256) void k_w2ext(const float* __restrict__ W2,
                                               const float* __restrict__ b2,
                                               float* __restrict__ W2ext) {
    int idx = blockIdx.x * 256 + threadIdx.x;
    if (idx >= 32 * QC) return;
    int i = idx / QC, c = idx % QC;
    float v;
    if (c < 1024) { int k = c >> 5, o = c & 31; v = W2[k * 1024 + i * 32 + o]; }
    else          { v = b2[i * 32 + (c - 1024)]; }
    W2ext[idx] = v;
}

// ---- pack W2ext into bf16 B-fragment layout: W2bf[(ct*64+l)*8+j] = B[kmap(l,j)][ct*16+(l&15)]
// kmap(l,j) = (j>>2)*16 + (l>>4)*4 + (j&3)  (two K=16 blocks of the 16x16x32 MFMA)
__global__ __launch_bounds__(256) void k_w2prep(const float* __restrict__ W2,
                                                const float* __restrict__ b2,
                                                unsigned short* __restrict__ W2bf) {
    int idx = blockIdx.x * 256 + threadIdx.x;
    if (idx >= 66 * 512) return;
    int ct = idx >> 9, l = (idx >> 3) & 63, j = idx & 7;
    int kk = ((j >> 2) << 4) + ((l >> 4) << 2) + (j & 3);
    int c = ct * 16 + (l & 15);
    float v;
    if (c < 1024) { int kb = c >> 5, o = c & 31; v = W2[kb * 1024 + kk * 32 + o]; }
    else          { v = b2[kk * 32 + (c - 1024)]; }
    W2bf[idx] = f2bf(v);
}

// ---- node encoder + projection
__global__ __launch_bounds__(256) void k_node_enc(
    const int* __restrict__ nfeats, const float* __restrict__ emb,
    const float* __restrict__ encW, const float* __restrict__ encB,
    const float* __restrict__ projW, const float* __restrict__ projB,
    float* __restrict__ h) {
    __shared__ float sEncW[1024], sProjW[1024], sEncB[32], sProjB[32];
    __shared__ float sEmb[8][33], sNh[8][33];
    int tid = threadIdx.x;
    for (int i = tid; i < 1024; i += 256) { sEncW[i] = encW[i]; sProjW[i] = projW[i]; }
    if (tid < 32) { sEncB[tid] = encB[tid]; sProjB[tid] = projB[tid]; }
    int ln = tid >> 5, o = tid & 31;
    int node = blockIdx.x * 8 + ln;
    int nt = nfeats[node];
    sEmb[ln][o] = fmaxf(emb[nt * 32 + o], 0.f);
    __syncthreads();
    float acc = sEncB[o];
    #pragma unroll
    for (int i = 0; i < 32; ++i) acc += sEmb[ln][i] * sEncW[i * 32 + o];
    sNh[ln][o] = fmaxf(acc, 0.f);
    __syncthreads();
    float acc2 = sProjB[o];
    #pragma unroll
    for (int i = 0; i < 32; ++i) acc2 += sNh[ln][i] * sProjW[i * 32 + o];
    h[node * 32 + o] = fmaxf(acc2, 0.f);
}

// ---- edge encoder
__global__ __launch_bounds__(256) void k_edge_t(
    const float* __restrict__ efeats,
    const float* __restrict__ eencW, const float* __restrict__ eencB,
    const float* __restrict__ enW1, const float* __restrict__ enB1,
    float* __restrict__ t) {
    __shared__ float sEW[512], sW1[1024], sEB[32], sB1[32];
    __shared__ float sEf[8][17], sEh[8][33];
    int tid = threadIdx.x;
    for (int i = tid; i < 512; i += 256) sEW[i] = eencW[i];
    for (int i = tid; i < 1024; i += 256) sW1[i] = enW1[i];
    if (tid < 32) { sEB[tid] = eencB[tid]; sB1[tid] = enB1[tid]; }
    int ln = tid >> 5, o = tid & 31;
    int e = blockIdx.x * 8 + ln;
    if (o < 16) sEf[ln][o] = efeats[e * 16 + o];
    __syncthreads();
    float acc = sEB[o];
    #pragma unroll
    for (int i = 0; i < 16; ++i) acc += sEf[ln][i] * sEW[i * 32 + o];
    sEh[ln][o] = acc;
    __syncthreads();
    float acc2 = sB1[o];
    #pragma unroll
    for (int i = 0; i < 32; ++i) acc2 += sEh[ln][i] * sW1[i * 32 + o];
    t[e * 32 + o] = fmaxf(acc2, 0.f);
}

// ---- generic counting-sort bucketing (templated on bins / shift)
template<int NT, int SHIFT>
__global__ __launch_bounds__(256) void k_histT(const int* __restrict__ keys,
                                               int* __restrict__ blockCounts) {
    __shared__ int sHist[NT];
    int tid = threadIdx.x, b = blockIdx.x;
    for (int c = tid; c < NT; c += 256) sHist[c] = 0;
    __syncthreads();
    int beg = b * EPB, end = min(beg + EPB, NE);
    for (int e = beg + tid; e < end; e += 256)
        atomicAdd(&sHist[keys[e] >> SHIFT], 1);
    __syncthreads();
    for (int c = tid; c < NT; c += 256) blockCounts[b * NT + c] = sHist[c];
}

template<int NT>
__global__ __launch_bounds__(256) void k_colsumT(const int* __restrict__ blockCounts,
                                                 int* __restrict__ blockStart,
                                                 int* __restrict__ tileTot) {
    int c = blockIdx.x * 256 + threadIdx.x;
    if (c >= NT) return;
    int running = 0;
    #pragma unroll 8
    for (int b = 0; b < HB; ++b) {
        blockStart[b * NT + c] = running;
        running += blockCounts[b * NT + c];
    }
    tileTot[c] = running;
}

template<int NT, int SEG>
__global__ __launch_bounds__(256) void k_scanT(const int* __restrict__ tileTot,
                                               int* __restrict__ offs) {
    __shared__ int sTot[NT];
    __shared__ int sPart[257];
    int tid = threadIdx.x;
    for (int c = tid; c < NT; c += 256) sTot[c] = tileTot[c];
    __syncthreads();
    int base = tid * SEG;
    int loc = 0;
    for (int j = 0; j < SEG; ++j) {
        int c = base + j;
        if (c < NT) { int v = sTot[c]; sTot[c] = loc; loc += v; }
    }
    sPart[tid] = loc;
    __syncthreads();
    if (tid == 0) {
        int s = 0;
        for (int i = 0; i < 256; ++i) { int v = sPart[i]; sPart[i] = s; s += v; }
        sPart[256] = s;
    }
    __syncthreads();
    int add = sPart[tid];
    for (int j = 0; j < SEG; ++j) {
        int c = base + j;
        if (c < NT) sTot[c] += add;
    }
    __syncthreads();
    for (int c = tid; c < NT; c += 256) offs[c] = sTot[c];
    if (tid == 0) offs[NT] = sPart[256];
}

template<int NT, int SHIFT>
__global__ __launch_bounds__(256) void k_scatterT(const int* __restrict__ keys,
                                                  const int* __restrict__ blockStart,
                                                  const int* __restrict__ offs,
                                                  int* __restrict__ eperm) {
    __shared__ int sCur[NT];
    int tid = threadIdx.x, b = blockIdx.x;
    for (int c = tid; c < NT; c += 256)
        sCur[c] = offs[c] + blockStart[b * NT + c];
    __syncthreads();
    int beg = b * EPB, end = min(beg + EPB, NE);
    for (int e = beg + tid; e < end; e += 256) {
        int pos = atomicAdd(&sCur[keys[e] >> SHIFT], 1);
        eperm[pos] = e;
    }
}

// ---- inverse dst permutation: posD[e] = p, rowAtPos[p] = dst row in tile
__global__ __launch_bounds__(256) void k_invperm(const int* __restrict__ epermD,
                                                 const int* __restrict__ dst,
                                                 int* __restrict__ posD,
                                                 int* __restrict__ rowAtPos) {
    int p = blockIdx.x * 256 + threadIdx.x;
    if (p < NE) {
        int e = epermD[p];
        posD[e] = p;
        rowAtPos[p] = dst[e] & 31;
    }
}

// ---- fused per-8-node-src-tile: MFMA Q into LDS (fp32), stream edges.
// MODE 0: atomicAdd into agg[dst]; MODE 1: store msg to msgbuf[posD[e]].
template<int MODE>
__global__ __launch_bounds__(256) void k_msgF8(
    const float* __restrict__ h, const unsigned short* __restrict__ W2bf,
    const float* __restrict__ t, const int* __restrict__ src, const int* __restrict__ dst,
    const int* __restrict__ eperm, const int* __restrict__ offs,
    const int* __restrict__ posD, float* __restrict__ outbuf) {
    __shared__ float sQ[8 * QSTR];     // 33920 B
    __shared__ float sT[32 * 33];      // 4224 B
    __shared__ int sRow[32], sIdx[32], sEdge[32];
    int tid = threadIdx.x;
    int tile = blockIdx.x;
    int beg = offs[tile], end = offs[tile + 1];
    if (beg >= end) return;
    int nodeBase = tile * 8;
    int wave = tid >> 6, lane = tid & 63;

    // A-fragment: row = lane&15 (rows 8..15 zero), k = (lane>>4)*4 + {0..3} and +16
    bf16x8 a;
    #pragma unroll
    for (int j = 0; j < 8; ++j) a[j] = 0;
    int arow = lane & 15;
    if (arow < 8) {
        const float* hp = h + (size_t)(nodeBase + arow) * 32 + ((lane >> 4) << 2);
        float4 x0 = *(const float4*)hp;
        float4 x1 = *(const float4*)(hp + 16);
        a[0] = (short)f2bf(x0.x); a[1] = (short)f2bf(x0.y);
        a[2] = (short)f2bf(x0.z); a[3] = (short)f2bf(x0.w);
        a[4] = (short)f2bf(x1.x); a[5] = (short)f2bf(x1.y);
        a[6] = (short)f2bf(x1.z); a[7] = (short)f2bf(x1.w);
    }
    f32x4 z = {0.f, 0.f, 0.f, 0.f};
    int crow0 = (lane >> 4) << 2;          // C rows crow0..crow0+3
    int ccol = lane & 15;
    for (int ct = wave; ct < 66; ct += 4) {
        bf16x8 b = *(const bf16x8*)(W2bf + (size_t)((ct << 6) + lane) * 8);
        f32x4 acc = __builtin_amdgcn_mfma_f32_16x16x32_bf16(a, b, z, 0, 0, 0);
        if (crow0 < 8) {
            float* qp = sQ + crow0 * QSTR + (ct << 4) + ccol;
            qp[0 * QSTR] = acc[0]; qp[1 * QSTR] = acc[1];
            qp[2 * QSTR] = acc[2]; qp[3 * QSTR] = acc[3];
        }
    }
    __syncthreads();

    // edge phase: 32 edges / iteration
    int el = tid >> 3, l8 = tid & 7;
    for (int s0 = beg; s0 < end; s0 += 32) {
        int nact = min(32, end - s0);
        if (tid < nact) {
            int e = eperm[s0 + tid];
            sEdge[tid] = e;
            sRow[tid] = src[e] - nodeBase;
            sIdx[tid] = MODE ? posD[e] : dst[e];
        }
        __syncthreads();
        for (int idx = tid; idx < (nact << 5); idx += 256) {
            int ee = idx >> 5, k = idx & 31;
            sT[ee * 33 + k] = t[(size_t)sEdge[ee] * 32 + k];
        }
        __syncthreads();
        if (el < nact) {
            const float* qp = sQ + sRow[el] * QSTR + (l8 << 2);
            const float* tp = sT + el * 33;
            float4 qb = *(const float4*)(qp + 1024);
            float a0 = qb.x, a1 = qb.y, a2 = qb.z, a3 = qb.w;
            #pragma unroll 8
            for (int k = 0; k < 32; ++k) {
                float tk = tp[k];
                float4 q = *(const float4*)(qp + (k << 5));
                a0 += tk * q.x; a1 += tk * q.y; a2 += tk * q.z; a3 += tk * q.w;
            }
            if (MODE) {
                *(float4*)(outbuf + (size_t)sIdx[el] * 32 + (l8 << 2)) =
                    make_float4(a0, a1, a2, a3);
            } else {
                float* ap = outbuf + (size_t)sIdx[el] * 32 + (l8 << 2);
                atomicAdd(ap + 0, a0); atomicAdd(ap + 1, a1);
                atomicAdd(ap + 2, a2); atomicAdd(ap + 3, a3);
            }
        }
        __syncthreads();
    }
}

// ---- fallback msg (tiny ws): recompute We per edge
__global__ __launch_bounds__(256) void k_msgC(
    const float* __restrict__ t, const int* __restrict__ src, const int* __restrict__ dst,
    const float* __restrict__ h, const float* __restrict__ W2ext, float* __restrict__ agg) {
    __shared__ float sT[32][33], sH[32][33];
    __shared__ int sSrc[32], sDst[32];
    int tid = threadIdx.x;
    int e0 = blockIdx.x * 32;
    if (tid < 32) sSrc[tid] = src[e0 + tid];
    else if (tid < 64) sDst[tid - 32] = dst[e0 + tid - 32];
    __syncthreads();
    for (int idx = tid; idx < 1024; idx += 256) {
        int el = idx >> 5, k = idx & 31;
        sT[el][k] = t[(e0 + el) * 32 + k];
        sH[el][k] = h[(size_t)sSrc[el] * 32 + k];
    }
    __syncthreads();
    int el = tid >> 3, l8 = tid & 7;
    int c0 = l8 * 4;
    float m0 = 0.f, m1 = 0.f, m2 = 0.f, m3 = 0.f;
    for (int i = 0; i < 32; ++i) {
        const float* wrow = W2ext + i * QC;
        float4 wb = *(const float4*)(wrow + 1024 + c0);
        float w0 = wb.x, w1 = wb.y, w2 = wb.z, w3 = wb.w;
        #pragma unroll 8
        for (int k = 0; k < 32; ++k) {
            float tk = sT[el][k];
            float4 w = *(const float4*)(wrow + k * 32 + c0);
            w0 += tk * w.x; w1 += tk * w.y; w2 += tk * w.z; w3 += tk * w.w;
        }
        float hi = sH[el][i];
        m0 += hi * w0; m1 += hi * w1; m2 += hi * w2; m3 += hi * w3;
    }
    float* ap = agg + (size_t)sDst[el] * 32 + c0;
    atomicAdd(ap + 0, m0); atomicAdd(ap + 1, m1);
    atomicAdd(ap + 2, m2); atomicAdd(ap + 3, m3);
}

// ---- GRU step reading agg[] (MODE 0 / fallback)
__global__ __launch_bounds__(256) void k_gru(
    const float* __restrict__ agg, const float* __restrict__ convB,
    const float* __restrict__ Wi, const float* __restrict__ Wh,
    const float* __restrict__ bi, const float* __restrict__ bh,
    float* __restrict__ h) {
    __shared__ float sWi[3072], sWh[3072], sBi[96], sBh[96], sCb[32];
    __shared__ float sX[8][33], sH[8][33];
    int tid = threadIdx.x;
    for (int i = tid; i < 3072; i += 256) { sWi[i] = Wi[i]; sWh[i] = Wh[i]; }
    if (tid < 96) { sBi[tid] = bi[tid]; sBh[tid] = bh[tid]; }
    if (tid < 32) sCb[tid] = convB[tid];
    int ln = tid >> 5, o = tid & 31;
    for (int g = 0; g < 4; ++g) {
        int node = blockIdx.x * 32 + g * 8 + ln;
        float hv = h[node * 32 + o];
        float av = agg[node * 32 + o];
        __syncthreads();
        sX[ln][o] = fmaxf(av + sCb[o], 0.f);
        sH[ln][o] = hv;
        __syncthreads();
        float air = sBi[o], aiz = sBi[o + 32], ain = sBi[o + 64];
        float ahr = sBh[o], ahz = sBh[o + 32], ahn = sBh[o + 64];
        #pragma unroll 8
        for (int i = 0; i < 32; ++i) {
            float x = sX[ln][i], hh = sH[ln][i];
            air += x * sWi[i * 96 + o];      ahr += hh * sWh[i * 96 + o];
            aiz += x * sWi[i * 96 + o + 32]; ahz += hh * sWh[i * 96 + o + 32];
            ain += x * sWi[i * 96 + o + 64]; ahn += hh * sWh[i * 96 + o + 64];
        }
        float r = 1.f / (1.f + __expf(-(air + ahr)));
        float zz = 1.f / (1.f + __expf(-(aiz + ahz)));
        float ng = tanhf(ain + r * ahn);
        h[node * 32 + o] = (1.f - zz) * ng + zz * hv;
    }
}

// ---- MODE 1: segment-sum dst-sorted msgs in LDS + GRU, per 32-node dst tile
__global__ __launch_bounds__(256) void k_gruAgg(
    const float* __restrict__ msgbuf, const int* __restrict__ rowAtPos,
    const int* __restrict__ offsD, const float* __restrict__ convB,
    const float* __restrict__ Wi, const float* __restrict__ Wh,
    const float* __restrict__ bi, const float* __restrict__ bh,
    float* __restrict__ h) {
    __shared__ float sWi[3072], sWh[3072], sBi[96], sBh[96], sCb[32];
    __shared__ float sAgg[32 * 33];
    __shared__ float sX[8][33], sH[8][33];
    int tid = threadIdx.x;
    int d = blockIdx.x;
    for (int i = tid; i < 3072; i += 256) { sWi[i] = Wi[i]; sWh[i] = Wh[i]; }
    if (tid < 96) { sBi[tid] = bi[tid]; sBh[tid] = bh[tid]; }
    if (tid < 32) sCb[tid] = convB[tid];
    for (int i = tid; i < 32 * 33; i += 256) sAgg[i] = 0.f;
    __syncthreads();
    int beg = offsD[d], end = offsD[d + 1];
    int el = tid >> 5, k = tid & 31;
    for (int p0 = beg; p0 < end; p0 += 8) {
        int p = p0 + el;
        if (p < end) {
            int row = rowAtPos[p];
            atomicAdd(&sAgg[row * 33 + k], msgbuf[(size_t)p * 32 + k]);
        }
    }
    __syncthreads();
    int ln = tid >> 5, o = tid & 31;
    for (int g = 0; g < 4; ++g) {
        int node = d * 32 + g * 8 + ln;
        float hv = h[node * 32 + o];
        __syncthreads();
        sX[ln][o] = fmaxf(sAgg[(g * 8 + ln) * 33 + o] + sCb[o], 0.f);
        sH[ln][o] = hv;
        __syncthreads();
        float air = sBi[o], aiz = sBi[o + 32], ain = sBi[o + 64];
        float ahr = sBh[o], ahz = sBh[o + 32], ahn = sBh[o + 64];
        #pragma unroll 8
        for (int i = 0; i < 32; ++i) {
            float x = sX[ln][i], hh = sH[ln][i];
            air += x * sWi[i * 96 + o];      ahr += hh * sWh[i * 96 + o];
            aiz += x * sWi[i * 96 + o + 32]; ahz += hh * sWh[i * 96 + o + 32];
            ain += x * sWi[i * 96 + o + 64]; ahn += hh * sWh[i * 96 + o + 64];
        }
        float r = 1.f / (1.f + __expf(-(air + ahr)));
        float zz = 1.f / (1.f + __expf(-(aiz + ahz)));
        float ng = tanhf(ain + r * ahn);
        h[node * 32 + o] = (1.f - zz) * ng + zz * hv;
    }
}

// ---- decoder
__global__ __launch_bounds__(256) void k_dec(
    const float* __restrict__ h,
    const float* __restrict__ W1, const float* __restrict__ b1, const float* __restrict__ a1,
    const float* __restrict__ W2, const float* __restrict__ b2, const float* __restrict__ a2,
    const float* __restrict__ W3, const float* __restrict__ b3, const float* __restrict__ a3,
    const float* __restrict__ W4, const float* __restrict__ b4,
    float* __restrict__ out) {
    __shared__ float sW1[1024], sW2[1024], sW3[1024], sW4[96];
    __shared__ float sB1[32], sB2[32], sB3[32], sB4[3];
    __shared__ float sYa[8][33], sYb[8][33];
    int tid = threadIdx.x;
    for (int i = tid; i < 1024; i += 256) { sW1[i] = W1[i]; sW2[i] = W2[i]; sW3[i] = W3[i]; }
    if (tid < 96) sW4[tid] = W4[tid];
    if (tid < 32) { sB1[tid] = b1[tid]; sB2[tid] = b2[tid]; sB3[tid] = b3[tid]; }
    if (tid < 3) sB4[tid] = b4[tid];
    float A1 = a1[0], A2 = a2[0], A3 = a3[0];
    int ln = tid >> 5, o = tid & 31;
    int node = blockIdx.x * 8 + ln;
    sYa[ln][o] = h[node * 32 + o];
    __syncthreads();
    float acc = sB1[o];
    #pragma unroll
    for (int i = 0; i < 32; ++i) acc += sYa[ln][i] * sW1[i * 32 + o];
    acc = acc >= 0.f ? acc : A1 * acc;
    sYb[ln][o] = acc;
    __syncthreads();
    acc = sB2[o];
    #pragma unroll
    for (int i = 0; i < 32; ++i) acc += sYb[ln][i] * sW2[i * 32 + o];
    acc = acc >= 0.f ? acc : A2 * acc;
    __syncthreads();
    sYa[ln][o] = acc;
    __syncthreads();
    acc = sB3[o];
    #pragma unroll
    for (int i = 0; i < 32; ++i) acc += sYa[ln][i] * sW3[i * 32 + o];
    acc = acc >= 0.f ? acc : A3 * acc;
    __syncthreads();
    sYb[ln][o] = acc;
    __syncthreads();
    if (o < 3) {
        float r = sB4[o];
        #pragma unroll
        for (int i = 0; i < 32; ++i) r += sYb[ln][i] * sW4[i * 3 + o];
        out[node * 3 + o] = r;
    }
}

extern "C" void kernel_launch(void* const* d_in, const int* in_sizes, int n_in,
                              void* d_out, int out_size, void* d_ws, size_t ws_size,
                              hipStream_t stream) {
    const int*   nfeats = (const int*)d_in[0];
    const float* efeats = (const float*)d_in[1];
    const int*   src    = (const int*)d_in[2];
    const int*   dst    = (const int*)d_in[3];
    const float* emb    = (const float*)d_in[4];
    const float* encW   = (const float*)d_in[5];
    const float* encB   = (const float*)d_in[6];
    const float* eencW  = (const float*)d_in[7];
    const float* eencB  = (const float*)d_in[8];
    const float* projW  = (const float*)d_in[9];
    const float* projB  = (const float*)d_in[10];
    const float* enW1   = (const float*)d_in[11];
    const float* enB1   = (const float*)d_in[12];
    const float* enW2   = (const float*)d_in[13];
    const float* enB2   = (const float*)d_in[14];
    const float* convB  = (const float*)d_in[15];
    const float* gruWi  = (const float*)d_in[16];
    const float* gruWh  = (const float*)d_in[17];
    const float* gruBi  = (const float*)d_in[18];
    const float* gruBh  = (const float*)d_in[19];
    const float* dW1 = (const float*)d_in[20]; const float* db1 = (const float*)d_in[21]; const float* da1 = (const float*)d_in[22];
    const float* dW2 = (const float*)d_in[23]; const float* db2 = (const float*)d_in[24]; const float* da2 = (const float*)d_in[25];
    const float* dW3 = (const float*)d_in[26]; const float* db3 = (const float*)d_in[27]; const float* da3 = (const float*)d_in[28];
    const float* dW4 = (const float*)d_in[29]; const float* db4 = (const float*)d_in[30];
    float* out = (float*)d_out;
    char* ws = (char*)d_ws;

    // bump allocator (256-B aligned)
    size_t cur = 0;
    auto alloc = [&](size_t n) { size_t p = cur; cur = (cur + n + 255) & ~(size_t)255; return p; };
    size_t o_h   = alloc((size_t)NN * 32 * 4);
    size_t o_t   = alloc((size_t)NE * 32 * 4);
    size_t o_w2e = alloc((size_t)32 * QC * 4);
    size_t afterCommon = cur;                       // fallback agg goes here
    size_t o_w2b = alloc((size_t)66 * 512 * 2);
    size_t o_epS = alloc((size_t)NE * 4);
    size_t o_ofS = alloc((size_t)(NT_S + 1) * 4);
    size_t baseEnd = cur;                           // MODE0 agg goes here
    size_t o_epD = alloc((size_t)NE * 4);
    size_t o_ofD = alloc((size_t)(NT_D + 1) * 4);
    size_t o_pos = alloc((size_t)NE * 4);
    size_t o_row = alloc((size_t)NE * 4);
    size_t o_msg = alloc((size_t)NE * 32 * 4);      // MODE1 msgbuf
    size_t need1 = cur;
    size_t need0 = baseEnd + (size_t)NN * 32 * 4;
    size_t needF = afterCommon + (size_t)NN * 32 * 4;

    int mode;                                       // 1: dst-sorted, 0: atomic, -1: msgC
    if (ws_size >= need1) mode = 1;
    else if (ws_size >= need0) mode = 0;
    else mode = -1;

    float* h     = (float*)(ws + o_h);
    float* t     = (float*)(ws + o_t);
    float* W2ext = (float*)(ws + o_w2e);
    unsigned short* W2bf = (unsigned short*)(ws + o_w2b);
    int* epermS = (int*)(ws + o_epS);
    int* offsS  = (int*)(ws + o_ofS);
    int* epermD = (int*)(ws + o_epD);
    int* offsD  = (int*)(ws + o_ofD);
    int* posD   = (int*)(ws + o_pos);
    int* rowAtPos = (int*)(ws + o_row);
    float* outbuf = (mode == 1) ? (float*)(ws + o_msg)
                  : (mode == 0) ? (float*)(ws + baseEnd)
                                : (float*)(ws + afterCommon);
    // scratch (prologue only) unions into outbuf region
    int* blockCounts = (int*)outbuf;
    int* blockStart  = blockCounts + (size_t)HB * NT_S;
    int* tileTot     = blockStart + (size_t)HB * NT_S;

    k_w2ext<<<(32 * QC + 255) / 256, 256, 0, stream>>>(enW2, enB2, W2ext);
    k_node_enc<<<NN / 8, 256, 0, stream>>>(nfeats, emb, encW, encB, projW, projB, h);
    k_edge_t<<<NE / 8, 256, 0, stream>>>(efeats, eencW, eencB, enW1, enB1, t);

    if (mode >= 0) {
        k_w2prep<<<(66 * 512 + 255) / 256, 256, 0, stream>>>(enW2, enB2, W2bf);
        // src bucketing (8-node tiles)
        k_histT<NT_S, 3><<<HB, 256, 0, stream>>>(src, blockCounts);
        k_colsumT<NT_S><<<(NT_S + 255) / 256, 256, 0, stream>>>(blockCounts, blockStart, tileTot);
        k_scanT<NT_S, 49><<<1, 256, 0, stream>>>(tileTot, offsS);
        k_scatterT<NT_S, 3><<<HB, 256, 0, stream>>>(src, blockStart, offsS, epermS);
        if (mode == 1) {
            // dst bucketing (32-node tiles) + inverse perm
            k_histT<NT_D, 5><<<HB, 256, 0, stream>>>(dst, blockCounts);
            k_colsumT<NT_D><<<(NT_D + 255) / 256, 256, 0, stream>>>(blockCounts, blockStart, tileTot);
            k_scanT<NT_D, 13><<<1, 256, 0, stream>>>(tileTot, offsD);
            k_scatterT<NT_D, 5><<<HB, 256, 0, stream>>>(dst, blockStart, offsD, epermD);
            k_invperm<<<(NE + 255) / 256, 256, 0, stream>>>(epermD, dst, posD, rowAtPos);
        }
    }

    for (int s = 0; s < 3; ++s) {
        if (mode == 1) {
            k_msgF8<1><<<NT_S, 256, 0, stream>>>(h, W2bf, t, src, dst, epermS, offsS, posD, outbuf);
            k_gruAgg<<<NT_D, 256, 0, stream>>>(outbuf, rowAtPos, offsD, convB,
                                               gruWi, gruWh, gruBi, gruBh, h);
        } else if (mode == 0) {
            hipMemsetAsync(outbuf, 0, (size_t)NN * 32 * 4, stream);
            k_msgF8<0><<<NT_S, 256, 0, stream>>>(h, W2bf, t, src, dst, epermS, offsS, nullptr, outbuf);
            k_gru<<<NN / 32, 256, 0, stream>>>(outbuf, convB, gruWi, gruWh, gruBi, gruBh, h);
        } else {
            hipMemsetAsync(outbuf, 0, (size_t)NN * 32 * 4, stream);
            k_msgC<<<NE / 32, 256, 0, stream>>>(t, src, dst, h, W2ext, outbuf);
            k_gru<<<NN / 32, 256, 0, stream>>>(outbuf, convB, gruWi, gruWh, gruBi, gruBh, h);
        }
    }
    k_dec<<<NN / 8, 256, 0, stream>>>(h, dW1, db1, da1, dW2, db2, da2, dW3, db3, da3, dW4, db4, out);
}

// Round 7
// 776.008 us; speedup vs baseline: 2.7115x; 1.1853x over previous
//
#include <hip/hip_runtime.h>
#include <hip/hip_bf16.h>

// MPNN on MI355X — fused tile kernel, MFMA Q-phase, node-sorted aggregation.
// msg[e,o] = sum_k t[e,k]*Q[src,k,o] + q0[src,o],  Q[n] = h[n] @ W2ext
// Src-tiles of 8 nodes: one block MFMAs Q (8x1056 fp32) into LDS, then streams
// the tile's edges, storing each msg at its dst-NODE-sorted slot (posD2).
// k_gruAgg2: 8 threads per node stream the node's contiguous msgs into
// registers (no atomics anywhere), then LDS-staged GRU.

#define NN 100000
#define NE 320000
#define QC 1056
#define NT_S 12500     // NN/8
#define NT_D 3125      // NN/32
#define HB 64          // bucketing blocks
#define EPB (NE / HB)  // 5000
#define QSTR 1060      // sQ row stride (floats), 1060 % 32 == 4

typedef short bf16x8 __attribute__((ext_vector_type(8)));
typedef float f32x4  __attribute__((ext_vector_type(4)));

__device__ __forceinline__ unsigned short f2bf(float f) {
    unsigned int x = __float_as_uint(f);
    unsigned int r = (x + 0x7fffu + ((x >> 16) & 1u)) >> 16;
    return (unsigned short)r;
}

// ---- build W2ext [32][1056] (fp32, fallback path only)
__global__ __launch_bounds__(256) void k_w2ext(const float* __restrict__ W2,
                                               const float* __restrict__ b2,
                                               float* __restrict__ W2ext) {
    int idx = blockIdx.x * 256 + threadIdx.x;
    if (idx >= 32 * QC) return;
    int i = idx / QC, c = idx % QC;
    float v;
    if (c < 1024) { int k = c >> 5, o = c & 31; v = W2[k * 1024 + i * 32 + o]; }
    else          { v = b2[i * 32 + (c - 1024)]; }
    W2ext[idx] = v;
}

// ---- pack W2ext into bf16 B-fragment layout
// W2bf[(ct*64+l)*8+j] = B[kmap(l,j)][ct*16+(l&15)], kmap = (j>>2)*16+(l>>4)*4+(j&3)
__global__ __launch_bounds__(256) void k_w2prep(const float* __restrict__ W2,
                                                const float* __restrict__ b2,
                                                unsigned short* __restrict__ W2bf) {
    int idx = blockIdx.x * 256 + threadIdx.x;
    if (idx >= 66 * 512) return;
    int ct = idx >> 9, l = (idx >> 3) & 63, j = idx & 7;
    int kk = ((j >> 2) << 4) + ((l >> 4) << 2) + (j & 3);
    int c = ct * 16 + (l & 15);
    float v;
    if (c < 1024) { int kb = c >> 5, o = c & 31; v = W2[kb * 1024 + kk * 32 + o]; }
    else          { v = b2[kk * 32 + (c - 1024)]; }
    W2bf[idx] = f2bf(v);
}

// ---- node encoder + projection
__global__ __launch_bounds__(256) void k_node_enc(
    const int* __restrict__ nfeats, const float* __restrict__ emb,
    const float* __restrict__ encW, const float* __restrict__ encB,
    const float* __restrict__ projW, const float* __restrict__ projB,
    float* __restrict__ h) {
    __shared__ float sEncW[1024], sProjW[1024], sEncB[32], sProjB[32];
    __shared__ float sEmb[8][33], sNh[8][33];
    int tid = threadIdx.x;
    for (int i = tid; i < 1024; i += 256) { sEncW[i] = encW[i]; sProjW[i] = projW[i]; }
    if (tid < 32) { sEncB[tid] = encB[tid]; sProjB[tid] = projB[tid]; }
    int ln = tid >> 5, o = tid & 31;
    int node = blockIdx.x * 8 + ln;
    int nt = nfeats[node];
    sEmb[ln][o] = fmaxf(emb[nt * 32 + o], 0.f);
    __syncthreads();
    float acc = sEncB[o];
    #pragma unroll
    for (int i = 0; i < 32; ++i) acc += sEmb[ln][i] * sEncW[i * 32 + o];
    sNh[ln][o] = fmaxf(acc, 0.f);
    __syncthreads();
    float acc2 = sProjB[o];
    #pragma unroll
    for (int i = 0; i < 32; ++i) acc2 += sNh[ln][i] * sProjW[i * 32 + o];
    h[node * 32 + o] = fmaxf(acc2, 0.f);
}

// ---- edge encoder
__global__ __launch_bounds__(256) void k_edge_t(
    const float* __restrict__ efeats,
    const float* __restrict__ eencW, const float* __restrict__ eencB,
    const float* __restrict__ enW1, const float* __restrict__ enB1,
    float* __restrict__ t) {
    __shared__ float sEW[512], sW1[1024], sEB[32], sB1[32];
    __shared__ float sEf[8][17], sEh[8][33];
    int tid = threadIdx.x;
    for (int i = tid; i < 512; i += 256) sEW[i] = eencW[i];
    for (int i = tid; i < 1024; i += 256) sW1[i] = enW1[i];
    if (tid < 32) { sEB[tid] = eencB[tid]; sB1[tid] = enB1[tid]; }
    int ln = tid >> 5, o = tid & 31;
    int e = blockIdx.x * 8 + ln;
    if (o < 16) sEf[ln][o] = efeats[e * 16 + o];
    __syncthreads();
    float acc = sEB[o];
    #pragma unroll
    for (int i = 0; i < 16; ++i) acc += sEf[ln][i] * sEW[i * 32 + o];
    sEh[ln][o] = acc;
    __syncthreads();
    float acc2 = sB1[o];
    #pragma unroll
    for (int i = 0; i < 32; ++i) acc2 += sEh[ln][i] * sW1[i * 32 + o];
    t[e * 32 + o] = fmaxf(acc2, 0.f);
}

// ---- generic counting-sort bucketing
template<int NT, int SHIFT>
__global__ __launch_bounds__(256) void k_histT(const int* __restrict__ keys,
                                               int* __restrict__ blockCounts) {
    __shared__ int sHist[NT];
    int tid = threadIdx.x, b = blockIdx.x;
    for (int c = tid; c < NT; c += 256) sHist[c] = 0;
    __syncthreads();
    int beg = b * EPB, end = min(beg + EPB, NE);
    for (int e = beg + tid; e < end; e += 256)
        atomicAdd(&sHist[keys[e] >> SHIFT], 1);
    __syncthreads();
    for (int c = tid; c < NT; c += 256) blockCounts[b * NT + c] = sHist[c];
}

template<int NT>
__global__ __launch_bounds__(256) void k_colsumT(const int* __restrict__ blockCounts,
                                                 int* __restrict__ blockStart,
                                                 int* __restrict__ tileTot) {
    int c = blockIdx.x * 256 + threadIdx.x;
    if (c >= NT) return;
    int running = 0;
    #pragma unroll 8
    for (int b = 0; b < HB; ++b) {
        blockStart[b * NT + c] = running;
        running += blockCounts[b * NT + c];
    }
    tileTot[c] = running;
}

template<int NT, int SEG>
__global__ __launch_bounds__(256) void k_scanT(const int* __restrict__ tileTot,
                                               int* __restrict__ offs) {
    __shared__ int sTot[NT];
    __shared__ int sPart[257];
    int tid = threadIdx.x;
    for (int c = tid; c < NT; c += 256) sTot[c] = tileTot[c];
    __syncthreads();
    int base = tid * SEG;
    int loc = 0;
    for (int j = 0; j < SEG; ++j) {
        int c = base + j;
        if (c < NT) { int v = sTot[c]; sTot[c] = loc; loc += v; }
    }
    sPart[tid] = loc;
    __syncthreads();
    if (tid == 0) {
        int s = 0;
        for (int i = 0; i < 256; ++i) { int v = sPart[i]; sPart[i] = s; s += v; }
        sPart[256] = s;
    }
    __syncthreads();
    int add = sPart[tid];
    for (int j = 0; j < SEG; ++j) {
        int c = base + j;
        if (c < NT) sTot[c] += add;
    }
    __syncthreads();
    for (int c = tid; c < NT; c += 256) offs[c] = sTot[c];
    if (tid == 0) offs[NT] = sPart[256];
}

template<int NT, int SHIFT>
__global__ __launch_bounds__(256) void k_scatterT(const int* __restrict__ keys,
                                                  const int* __restrict__ blockStart,
                                                  const int* __restrict__ offs,
                                                  int* __restrict__ eperm) {
    __shared__ int sCur[NT];
    int tid = threadIdx.x, b = blockIdx.x;
    for (int c = tid; c < NT; c += 256)
        sCur[c] = offs[c] + blockStart[b * NT + c];
    __syncthreads();
    int beg = b * EPB, end = min(beg + EPB, NE);
    for (int e = beg + tid; e < end; e += 256) {
        int pos = atomicAdd(&sCur[keys[e] >> SHIFT], 1);
        eperm[pos] = e;
    }
}

// ---- second-level sort: within each dst tile, sort by node (32 LDS bins);
// emits epermD2 (node-contiguous) and nodeOffs[NN+1]
__global__ __launch_bounds__(256) void k_sortNode(
    const int* __restrict__ epermD, const int* __restrict__ dst,
    const int* __restrict__ offsD, int* __restrict__ epermD2,
    int* __restrict__ nodeOffs) {
    __shared__ int sCnt[32], sStart[32];
    int tid = threadIdx.x, d = blockIdx.x;
    int beg = offsD[d], end = offsD[d + 1];
    if (tid < 32) sCnt[tid] = 0;
    __syncthreads();
    for (int p = beg + tid; p < end; p += 256)
        atomicAdd(&sCnt[dst[epermD[p]] & 31], 1);
    __syncthreads();
    if (tid == 0) {
        int s = beg;
        for (int r = 0; r < 32; ++r) { sStart[r] = s; s += sCnt[r]; }
    }
    __syncthreads();
    if (tid < 32) {
        nodeOffs[d * 32 + tid] = sStart[tid];
        sCnt[tid] = sStart[tid];       // reuse as cursor
    }
    if (d == NT_D - 1 && tid == 0) nodeOffs[NN] = end;
    __syncthreads();
    for (int p = beg + tid; p < end; p += 256) {
        int e = epermD[p];
        int pos = atomicAdd(&sCnt[dst[e] & 31], 1);
        epermD2[pos] = e;
    }
}

// ---- inverse permutation: posD2[e] = node-sorted slot
__global__ __launch_bounds__(256) void k_invperm2(const int* __restrict__ epermD2,
                                                  int* __restrict__ posD2) {
    int p = blockIdx.x * 256 + threadIdx.x;
    if (p < NE) posD2[epermD2[p]] = p;
}

// ---- fused per-8-node-src-tile: MFMA Q into LDS (fp32), stream edges.
// MODE 0: atomicAdd into agg[dst]; MODE 1: store msg to msgbuf[posD2[e]].
template<int MODE>
__global__ __launch_bounds__(256) void k_msgF8(
    const float* __restrict__ h, const unsigned short* __restrict__ W2bf,
    const float* __restrict__ t, const int* __restrict__ src, const int* __restrict__ dst,
    const int* __restrict__ eperm, const int* __restrict__ offs,
    const int* __restrict__ posD2, float* __restrict__ outbuf) {
    __shared__ float sQ[8 * QSTR];     // 33920 B
    __shared__ float sT[32 * 33];      // 4224 B
    __shared__ int sRow[32], sIdx[32], sEdge[32];
    int tid = threadIdx.x;
    int tile = blockIdx.x;
    int beg = offs[tile], end = offs[tile + 1];
    if (beg >= end) return;
    int nodeBase = tile * 8;
    int wave = tid >> 6, lane = tid & 63;

    bf16x8 a;
    #pragma unroll
    for (int j = 0; j < 8; ++j) a[j] = 0;
    int arow = lane & 15;
    if (arow < 8) {
        const float* hp = h + (size_t)(nodeBase + arow) * 32 + ((lane >> 4) << 2);
        float4 x0 = *(const float4*)hp;
        float4 x1 = *(const float4*)(hp + 16);
        a[0] = (short)f2bf(x0.x); a[1] = (short)f2bf(x0.y);
        a[2] = (short)f2bf(x0.z); a[3] = (short)f2bf(x0.w);
        a[4] = (short)f2bf(x1.x); a[5] = (short)f2bf(x1.y);
        a[6] = (short)f2bf(x1.z); a[7] = (short)f2bf(x1.w);
    }
    f32x4 z = {0.f, 0.f, 0.f, 0.f};
    int crow0 = (lane >> 4) << 2;
    int ccol = lane & 15;
    for (int ct = wave; ct < 66; ct += 4) {
        bf16x8 b = *(const bf16x8*)(W2bf + (size_t)((ct << 6) + lane) * 8);
        f32x4 acc = __builtin_amdgcn_mfma_f32_16x16x32_bf16(a, b, z, 0, 0, 0);
        if (crow0 < 8) {
            float* qp = sQ + crow0 * QSTR + (ct << 4) + ccol;
            qp[0 * QSTR] = acc[0]; qp[1 * QSTR] = acc[1];
            qp[2 * QSTR] = acc[2]; qp[3 * QSTR] = acc[3];
        }
    }
    __syncthreads();

    int el = tid >> 3, l8 = tid & 7;
    for (int s0 = beg; s0 < end; s0 += 32) {
        int nact = min(32, end - s0);
        if (tid < nact) {
            int e = eperm[s0 + tid];
            sEdge[tid] = e;
            sRow[tid] = src[e] - nodeBase;
            sIdx[tid] = MODE ? posD2[e] : dst[e];
        }
        __syncthreads();
        for (int idx = tid; idx < (nact << 5); idx += 256) {
            int ee = idx >> 5, k = idx & 31;
            sT[ee * 33 + k] = t[(size_t)sEdge[ee] * 32 + k];
        }
        __syncthreads();
        if (el < nact) {
            const float* qp = sQ + sRow[el] * QSTR + (l8 << 2);
            const float* tp = sT + el * 33;
            float4 qb = *(const float4*)(qp + 1024);
            float a0 = qb.x, a1 = qb.y, a2 = qb.z, a3 = qb.w;
            #pragma unroll 8
            for (int k = 0; k < 32; ++k) {
                float tk = tp[k];
                float4 q = *(const float4*)(qp + (k << 5));
                a0 += tk * q.x; a1 += tk * q.y; a2 += tk * q.z; a3 += tk * q.w;
            }
            if (MODE) {
                *(float4*)(outbuf + (size_t)sIdx[el] * 32 + (l8 << 2)) =
                    make_float4(a0, a1, a2, a3);
            } else {
                float* ap = outbuf + (size_t)sIdx[el] * 32 + (l8 << 2);
                atomicAdd(ap + 0, a0); atomicAdd(ap + 1, a1);
                atomicAdd(ap + 2, a2); atomicAdd(ap + 3, a3);
            }
        }
        __syncthreads();
    }
}

// ---- fallback msg (tiny ws): recompute We per edge
__global__ __launch_bounds__(256) void k_msgC(
    const float* __restrict__ t, const int* __restrict__ src, const int* __restrict__ dst,
    const float* __restrict__ h, const float* __restrict__ W2ext, float* __restrict__ agg) {
    __shared__ float sT[32][33], sH[32][33];
    __shared__ int sSrc[32], sDst[32];
    int tid = threadIdx.x;
    int e0 = blockIdx.x * 32;
    if (tid < 32) sSrc[tid] = src[e0 + tid];
    else if (tid < 64) sDst[tid - 32] = dst[e0 + tid - 32];
    __syncthreads();
    for (int idx = tid; idx < 1024; idx += 256) {
        int el = idx >> 5, k = idx & 31;
        sT[el][k] = t[(e0 + el) * 32 + k];
        sH[el][k] = h[(size_t)sSrc[el] * 32 + k];
    }
    __syncthreads();
    int el = tid >> 3, l8 = tid & 7;
    int c0 = l8 * 4;
    float m0 = 0.f, m1 = 0.f, m2 = 0.f, m3 = 0.f;
    for (int i = 0; i < 32; ++i) {
        const float* wrow = W2ext + i * QC;
        float4 wb = *(const float4*)(wrow + 1024 + c0);
        float w0 = wb.x, w1 = wb.y, w2 = wb.z, w3 = wb.w;
        #pragma unroll 8
        for (int k = 0; k < 32; ++k) {
            float tk = sT[el][k];
            float4 w = *(const float4*)(wrow + k * 32 + c0);
            w0 += tk * w.x; w1 += tk * w.y; w2 += tk * w.z; w3 += tk * w.w;
        }
        float hi = sH[el][i];
        m0 += hi * w0; m1 += hi * w1; m2 += hi * w2; m3 += hi * w3;
    }
    float* ap = agg + (size_t)sDst[el] * 32 + c0;
    atomicAdd(ap + 0, m0); atomicAdd(ap + 1, m1);
    atomicAdd(ap + 2, m2); atomicAdd(ap + 3, m3);
}

// ---- GRU step reading agg[] (MODE 0 / fallback)
__global__ __launch_bounds__(256) void k_gru(
    const float* __restrict__ agg, const float* __restrict__ convB,
    const float* __restrict__ Wi, const float* __restrict__ Wh,
    const float* __restrict__ bi, const float* __restrict__ bh,
    float* __restrict__ h) {
    __shared__ float sWi[3072], sWh[3072], sBi[96], sBh[96], sCb[32];
    __shared__ float sX[8][33], sH[8][33];
    int tid = threadIdx.x;
    for (int i = tid; i < 3072; i += 256) { sWi[i] = Wi[i]; sWh[i] = Wh[i]; }
    if (tid < 96) { sBi[tid] = bi[tid]; sBh[tid] = bh[tid]; }
    if (tid < 32) sCb[tid] = convB[tid];
    int ln = tid >> 5, o = tid & 31;
    for (int g = 0; g < 4; ++g) {
        int node = blockIdx.x * 32 + g * 8 + ln;
        float hv = h[node * 32 + o];
        float av = agg[node * 32 + o];
        __syncthreads();
        sX[ln][o] = fmaxf(av + sCb[o], 0.f);
        sH[ln][o] = hv;
        __syncthreads();
        float air = sBi[o], aiz = sBi[o + 32], ain = sBi[o + 64];
        float ahr = sBh[o], ahz = sBh[o + 32], ahn = sBh[o + 64];
        #pragma unroll 8
        for (int i = 0; i < 32; ++i) {
            float x = sX[ln][i], hh = sH[ln][i];
            air += x * sWi[i * 96 + o];      ahr += hh * sWh[i * 96 + o];
            aiz += x * sWi[i * 96 + o + 32]; ahz += hh * sWh[i * 96 + o + 32];
            ain += x * sWi[i * 96 + o + 64]; ahn += hh * sWh[i * 96 + o + 64];
        }
        float r = 1.f / (1.f + __expf(-(air + ahr)));
        float zz = 1.f / (1.f + __expf(-(aiz + ahz)));
        float ng = tanhf(ain + r * ahn);
        h[node * 32 + o] = (1.f - zz) * ng + zz * hv;
    }
}

// ---- MODE 1: per 32-node dst tile, 8 threads/node register segment-sum + GRU
__global__ __launch_bounds__(256) void k_gruAgg2(
    const float* __restrict__ msgbuf, const int* __restrict__ nodeOffs,
    const float* __restrict__ convB,
    const float* __restrict__ Wi, const float* __restrict__ Wh,
    const float* __restrict__ bi, const float* __restrict__ bh,
    float* __restrict__ h) {
    __shared__ float sWi[3072], sWh[3072], sBi[96], sBh[96], sCb[32];
    __shared__ float sAgg[32 * 33];
    __shared__ float sX[8][33], sH[8][33];
    int tid = threadIdx.x;
    int d = blockIdx.x;
    for (int i = tid; i < 3072; i += 256) { sWi[i] = Wi[i]; sWh[i] = Wh[i]; }
    if (tid < 96) { sBi[tid] = bi[tid]; sBh[tid] = bh[tid]; }
    if (tid < 32) sCb[tid] = convB[tid];

    int n8 = tid >> 3, l8 = tid & 7;       // node row 0..31, col group 0..7
    int node = d * 32 + n8;
    int nb = nodeOffs[node], ne2 = nodeOffs[node + 1];
    float a0 = 0.f, a1 = 0.f, a2 = 0.f, a3 = 0.f;
    for (int p = nb; p < ne2; ++p) {
        float4 v = *(const float4*)(msgbuf + (size_t)p * 32 + (l8 << 2));
        a0 += v.x; a1 += v.y; a2 += v.z; a3 += v.w;
    }
    float* sp = sAgg + n8 * 33 + (l8 << 2);
    sp[0] = a0; sp[1] = a1; sp[2] = a2; sp[3] = a3;
    __syncthreads();

    int ln = tid >> 5, o = tid & 31;
    for (int g = 0; g < 4; ++g) {
        int nd = d * 32 + g * 8 + ln;
        float hv = h[nd * 32 + o];
        __syncthreads();
        sX[ln][o] = fmaxf(sAgg[(g * 8 + ln) * 33 + o] + sCb[o], 0.f);
        sH[ln][o] = hv;
        __syncthreads();
        float air = sBi[o], aiz = sBi[o + 32], ain = sBi[o + 64];
        float ahr = sBh[o], ahz = sBh[o + 32], ahn = sBh[o + 64];
        #pragma unroll 8
        for (int i = 0; i < 32; ++i) {
            float x = sX[ln][i], hh = sH[ln][i];
            air += x * sWi[i * 96 + o];      ahr += hh * sWh[i * 96 + o];
            aiz += x * sWi[i * 96 + o + 32]; ahz += hh * sWh[i * 96 + o + 32];
            ain += x * sWi[i * 96 + o + 64]; ahn += hh * sWh[i * 96 + o + 64];
        }
        float r = 1.f / (1.f + __expf(-(air + ahr)));
        float zz = 1.f / (1.f + __expf(-(aiz + ahz)));
        float ng = tanhf(ain + r * ahn);
        h[nd * 32 + o] = (1.f - zz) * ng + zz * hv;
    }
}

// ---- decoder
__global__ __launch_bounds__(256) void k_dec(
    const float* __restrict__ h,
    const float* __restrict__ W1, const float* __restrict__ b1, const float* __restrict__ a1,
    const float* __restrict__ W2, const float* __restrict__ b2, const float* __restrict__ a2,
    const float* __restrict__ W3, const float* __restrict__ b3, const float* __restrict__ a3,
    const float* __restrict__ W4, const float* __restrict__ b4,
    float* __restrict__ out) {
    __shared__ float sW1[1024], sW2[1024], sW3[1024], sW4[96];
    __shared__ float sB1[32], sB2[32], sB3[32], sB4[3];
    __shared__ float sYa[8][33], sYb[8][33];
    int tid = threadIdx.x;
    for (int i = tid; i < 1024; i += 256) { sW1[i] = W1[i]; sW2[i] = W2[i]; sW3[i] = W3[i]; }
    if (tid < 96) sW4[tid] = W4[tid];
    if (tid < 32) { sB1[tid] = b1[tid]; sB2[tid] = b2[tid]; sB3[tid] = b3[tid]; }
    if (tid < 3) sB4[tid] = b4[tid];
    float A1 = a1[0], A2 = a2[0], A3 = a3[0];
    int ln = tid >> 5, o = tid & 31;
    int node = blockIdx.x * 8 + ln;
    sYa[ln][o] = h[node * 32 + o];
    __syncthreads();
    float acc = sB1[o];
    #pragma unroll
    for (int i = 0; i < 32; ++i) acc += sYa[ln][i] * sW1[i * 32 + o];
    acc = acc >= 0.f ? acc : A1 * acc;
    sYb[ln][o] = acc;
    __syncthreads();
    acc = sB2[o];
    #pragma unroll
    for (int i = 0; i < 32; ++i) acc += sYb[ln][i] * sW2[i * 32 + o];
    acc = acc >= 0.f ? acc : A2 * acc;
    __syncthreads();
    sYa[ln][o] = acc;
    __syncthreads();
    acc = sB3[o];
    #pragma unroll
    for (int i = 0; i < 32; ++i) acc += sYa[ln][i] * sW3[i * 32 + o];
    acc = acc >= 0.f ? acc : A3 * acc;
    __syncthreads();
    sYb[ln][o] = acc;
    __syncthreads();
    if (o < 3) {
        float r = sB4[o];
        #pragma unroll
        for (int i = 0; i < 32; ++i) r += sYb[ln][i] * sW4[i * 3 + o];
        out[node * 3 + o] = r;
    }
}

extern "C" void kernel_launch(void* const* d_in, const int* in_sizes, int n_in,
                              void* d_out, int out_size, void* d_ws, size_t ws_size,
                              hipStream_t stream) {
    const int*   nfeats = (const int*)d_in[0];
    const float* efeats = (const float*)d_in[1];
    const int*   src    = (const int*)d_in[2];
    const int*   dst    = (const int*)d_in[3];
    const float* emb    = (const float*)d_in[4];
    const float* encW   = (const float*)d_in[5];
    const float* encB   = (const float*)d_in[6];
    const float* eencW  = (const float*)d_in[7];
    const float* eencB  = (const float*)d_in[8];
    const float* projW  = (const float*)d_in[9];
    const float* projB  = (const float*)d_in[10];
    const float* enW1   = (const float*)d_in[11];
    const float* enB1   = (const float*)d_in[12];
    const float* enW2   = (const float*)d_in[13];
    const float* enB2   = (const float*)d_in[14];
    const float* convB  = (const float*)d_in[15];
    const float* gruWi  = (const float*)d_in[16];
    const float* gruWh  = (const float*)d_in[17];
    const float* gruBi  = (const float*)d_in[18];
    const float* gruBh  = (const float*)d_in[19];
    const float* dW1 = (const float*)d_in[20]; const float* db1 = (const float*)d_in[21]; const float* da1 = (const float*)d_in[22];
    const float* dW2 = (const float*)d_in[23]; const float* db2 = (const float*)d_in[24]; const float* da2 = (const float*)d_in[25];
    const float* dW3 = (const float*)d_in[26]; const float* db3 = (const float*)d_in[27]; const float* da3 = (const float*)d_in[28];
    const float* dW4 = (const float*)d_in[29]; const float* db4 = (const float*)d_in[30];
    float* out = (float*)d_out;
    char* ws = (char*)d_ws;

    // bump allocator (256-B aligned)
    size_t cur = 0;
    auto alloc = [&](size_t n) { size_t p = cur; cur = (cur + n + 255) & ~(size_t)255; return p; };
    size_t o_h   = alloc((size_t)NN * 32 * 4);
    size_t o_t   = alloc((size_t)NE * 32 * 4);
    size_t o_w2e = alloc((size_t)32 * QC * 4);
    size_t afterCommon = cur;                       // fallback agg goes here
    size_t o_w2b = alloc((size_t)66 * 512 * 2);
    size_t o_epS = alloc((size_t)NE * 4);
    size_t o_ofS = alloc((size_t)(NT_S + 1) * 4);
    size_t baseEnd = cur;                           // MODE0 agg goes here
    size_t o_epD  = alloc((size_t)NE * 4);
    size_t o_ofD  = alloc((size_t)(NT_D + 1) * 4);
    size_t o_epD2 = alloc((size_t)NE * 4);
    size_t o_pos2 = alloc((size_t)NE * 4);
    size_t o_noff = alloc((size_t)(NN + 1) * 4);
    size_t o_msg  = alloc((size_t)NE * 32 * 4);     // MODE1 msgbuf
    size_t need1 = cur;
    size_t need0 = baseEnd + (size_t)NN * 32 * 4;

    int mode;                                       // 1: node-sorted, 0: atomic, -1: msgC
    if (ws_size >= need1) mode = 1;
    else if (ws_size >= need0) mode = 0;
    else mode = -1;

    float* h     = (float*)(ws + o_h);
    float* t     = (float*)(ws + o_t);
    float* W2ext = (float*)(ws + o_w2e);
    unsigned short* W2bf = (unsigned short*)(ws + o_w2b);
    int* epermS  = (int*)(ws + o_epS);
    int* offsS   = (int*)(ws + o_ofS);
    int* epermD  = (int*)(ws + o_epD);
    int* offsD   = (int*)(ws + o_ofD);
    int* epermD2 = (int*)(ws + o_epD2);
    int* posD2   = (int*)(ws + o_pos2);
    int* nodeOffs = (int*)(ws + o_noff);
    float* outbuf = (mode == 1) ? (float*)(ws + o_msg)
                  : (mode == 0) ? (float*)(ws + baseEnd)
                                : (float*)(ws + afterCommon);
    // scratch (prologue only) unions into outbuf region
    int* blockCounts = (int*)outbuf;
    int* blockStart  = blockCounts + (size_t)HB * NT_S;
    int* tileTot     = blockStart + (size_t)HB * NT_S;

    k_w2ext<<<(32 * QC + 255) / 256, 256, 0, stream>>>(enW2, enB2, W2ext);
    k_node_enc<<<NN / 8, 256, 0, stream>>>(nfeats, emb, encW, encB, projW, projB, h);
    k_edge_t<<<NE / 8, 256, 0, stream>>>(efeats, eencW, eencB, enW1, enB1, t);

    if (mode >= 0) {
        k_w2prep<<<(66 * 512 + 255) / 256, 256, 0, stream>>>(enW2, enB2, W2bf);
        // src bucketing (8-node tiles)
        k_histT<NT_S, 3><<<HB, 256, 0, stream>>>(src, blockCounts);
        k_colsumT<NT_S><<<(NT_S + 255) / 256, 256, 0, stream>>>(blockCounts, blockStart, tileTot);
        k_scanT<NT_S, 49><<<1, 256, 0, stream>>>(tileTot, offsS);
        k_scatterT<NT_S, 3><<<HB, 256, 0, stream>>>(src, blockStart, offsS, epermS);
        if (mode == 1) {
            // dst bucketing (32-node tiles) -> per-node sort -> inverse perm
            k_histT<NT_D, 5><<<HB, 256, 0, stream>>>(dst, blockCounts);
            k_colsumT<NT_D><<<(NT_D + 255) / 256, 256, 0, stream>>>(blockCounts, blockStart, tileTot);
            k_scanT<NT_D, 13><<<1, 256, 0, stream>>>(tileTot, offsD);
            k_scatterT<NT_D, 5><<<HB, 256, 0, stream>>>(dst, blockStart, offsD, epermD);
            k_sortNode<<<NT_D, 256, 0, stream>>>(epermD, dst, offsD, epermD2, nodeOffs);
            k_invperm2<<<(NE + 255) / 256, 256, 0, stream>>>(epermD2, posD2);
        }
    }

    for (int s = 0; s < 3; ++s) {
        if (mode == 1) {
            k_msgF8<1><<<NT_S, 256, 0, stream>>>(h, W2bf, t, src, dst, epermS, offsS, posD2, outbuf);
            k_gruAgg2<<<NT_D, 256, 0, stream>>>(outbuf, nodeOffs, convB,
                                                gruWi, gruWh, gruBi, gruBh, h);
        } else if (mode == 0) {
            hipMemsetAsync(outbuf, 0, (size_t)NN * 32 * 4, stream);
            k_msgF8<0><<<NT_S, 256, 0, stream>>>(h, W2bf, t, src, dst, epermS, offsS, nullptr, outbuf);
            k_gru<<<NN / 32, 256, 0, stream>>>(outbuf, convB, gruWi, gruWh, gruBi, gruBh, h);
        } else {
            hipMemsetAsync(outbuf, 0, (size_t)NN * 32 * 4, stream);
            k_msgC<<<NE / 32, 256, 0, stream>>>(t, src, dst, h, W2ext, outbuf);
            k_gru<<<NN / 32, 256, 0, stream>>>(outbuf, convB, gruWi, gruWh, gruBi, gruBh, h);
        }
    }
    k_dec<<<NN / 8, 256, 0, stream>>>(h, dW1, db1, da1, dW2, db2, da2, dW3, db3, da3, dW4, db4, out);
}

// Round 8
// 757.201 us; speedup vs baseline: 2.7789x; 1.0248x over previous
//
#include <hip/hip_runtime.h>
#include <hip/hip_bf16.h>

// MPNN on MI355X — fused tile kernel, MFMA Q-phase, node-sorted aggregation.
// msg[e,o] = sum_k t[e,k]*Q[src,k,o] + q0[src,o],  Q[n] = h[n] @ W2ext
// Src-tiles of 8 nodes: one block MFMAs Q (8x1056, bf16) into LDS (17KB ->
// 8 blocks/CU), then streams the tile's edges: t-row loaded as one coalesced
// float4 per thread and broadcast via __shfl in the 8-lane group; msg stored
// at its dst-NODE-sorted slot (posD2). k_gruAgg2: 2 dst-tiles/block, register
// segment-sum, 2 barriers/tile. No global atomics anywhere (MODE1).

#define NN 100000
#define NE 320000
#define QC 1056
#define NT_S 12500     // NN/8
#define NT_D 3125      // NN/32
#define HB 64          // bucketing blocks
#define EPB (NE / HB)  // 5000
#define QSTRH 1064     // sQ row stride (shorts)

typedef short bf16x8 __attribute__((ext_vector_type(8)));
typedef float f32x4  __attribute__((ext_vector_type(4)));

__device__ __forceinline__ float bf2f(unsigned short u) {
    return __uint_as_float(((unsigned int)u) << 16);
}
__device__ __forceinline__ unsigned short f2bf(float f) {
    unsigned int x = __float_as_uint(f);
    unsigned int r = (x + 0x7fffu + ((x >> 16) & 1u)) >> 16;
    return (unsigned short)r;
}

// ---- build W2ext [32][1056] (fp32, fallback path only)
__global__ __launch_bounds__(256) void k_w2ext(const float* __restrict__ W2,
                                               const float* __restrict__ b2,
                                               float* __restrict__ W2ext) {
    int idx = blockIdx.x * 256 + threadIdx.x;
    if (idx >= 32 * QC) return;
    int i = idx / QC, c = idx % QC;
    float v;
    if (c < 1024) { int k = c >> 5, o = c & 31; v = W2[k * 1024 + i * 32 + o]; }
    else          { v = b2[i * 32 + (c - 1024)]; }
    W2ext[idx] = v;
}

// ---- pack W2ext into bf16 B-fragment layout
// W2bf[(ct*64+l)*8+j] = B[kmap(l,j)][ct*16+(l&15)], kmap = (j>>2)*16+(l>>4)*4+(j&3)
__global__ __launch_bounds__(256) void k_w2prep(const float* __restrict__ W2,
                                                const float* __restrict__ b2,
                                                unsigned short* __restrict__ W2bf) {
    int idx = blockIdx.x * 256 + threadIdx.x;
    if (idx >= 66 * 512) return;
    int ct = idx >> 9, l = (idx >> 3) & 63, j = idx & 7;
    int kk = ((j >> 2) << 4) + ((l >> 4) << 2) + (j & 3);
    int c = ct * 16 + (l & 15);
    float v;
    if (c < 1024) { int kb = c >> 5, o = c & 31; v = W2[kb * 1024 + kk * 32 + o]; }
    else          { v = b2[kk * 32 + (c - 1024)]; }
    W2bf[idx] = f2bf(v);
}

// ---- node encoder + projection
__global__ __launch_bounds__(256) void k_node_enc(
    const int* __restrict__ nfeats, const float* __restrict__ emb,
    const float* __restrict__ encW, const float* __restrict__ encB,
    const float* __restrict__ projW, const float* __restrict__ projB,
    float* __restrict__ h) {
    __shared__ float sEncW[1024], sProjW[1024], sEncB[32], sProjB[32];
    __shared__ float sEmb[8][33], sNh[8][33];
    int tid = threadIdx.x;
    for (int i = tid; i < 1024; i += 256) { sEncW[i] = encW[i]; sProjW[i] = projW[i]; }
    if (tid < 32) { sEncB[tid] = encB[tid]; sProjB[tid] = projB[tid]; }
    int ln = tid >> 5, o = tid & 31;
    int node = blockIdx.x * 8 + ln;
    int nt = nfeats[node];
    sEmb[ln][o] = fmaxf(emb[nt * 32 + o], 0.f);
    __syncthreads();
    float acc = sEncB[o];
    #pragma unroll
    for (int i = 0; i < 32; ++i) acc += sEmb[ln][i] * sEncW[i * 32 + o];
    sNh[ln][o] = fmaxf(acc, 0.f);
    __syncthreads();
    float acc2 = sProjB[o];
    #pragma unroll
    for (int i = 0; i < 32; ++i) acc2 += sNh[ln][i] * sProjW[i * 32 + o];
    h[node * 32 + o] = fmaxf(acc2, 0.f);
}

// ---- edge encoder
__global__ __launch_bounds__(256) void k_edge_t(
    const float* __restrict__ efeats,
    const float* __restrict__ eencW, const float* __restrict__ eencB,
    const float* __restrict__ enW1, const float* __restrict__ enB1,
    float* __restrict__ t) {
    __shared__ float sEW[512], sW1[1024], sEB[32], sB1[32];
    __shared__ float sEf[8][17], sEh[8][33];
    int tid = threadIdx.x;
    for (int i = tid; i < 512; i += 256) sEW[i] = eencW[i];
    for (int i = tid; i < 1024; i += 256) sW1[i] = enW1[i];
    if (tid < 32) { sEB[tid] = eencB[tid]; sB1[tid] = enB1[tid]; }
    int ln = tid >> 5, o = tid & 31;
    int e = blockIdx.x * 8 + ln;
    if (o < 16) sEf[ln][o] = efeats[e * 16 + o];
    __syncthreads();
    float acc = sEB[o];
    #pragma unroll
    for (int i = 0; i < 16; ++i) acc += sEf[ln][i] * sEW[i * 32 + o];
    sEh[ln][o] = acc;
    __syncthreads();
    float acc2 = sB1[o];
    #pragma unroll
    for (int i = 0; i < 32; ++i) acc2 += sEh[ln][i] * sW1[i * 32 + o];
    t[e * 32 + o] = fmaxf(acc2, 0.f);
}

// ---- generic counting-sort bucketing
template<int NT, int SHIFT>
__global__ __launch_bounds__(256) void k_histT(const int* __restrict__ keys,
                                               int* __restrict__ blockCounts) {
    __shared__ int sHist[NT];
    int tid = threadIdx.x, b = blockIdx.x;
    for (int c = tid; c < NT; c += 256) sHist[c] = 0;
    __syncthreads();
    int beg = b * EPB, end = min(beg + EPB, NE);
    for (int e = beg + tid; e < end; e += 256)
        atomicAdd(&sHist[keys[e] >> SHIFT], 1);
    __syncthreads();
    for (int c = tid; c < NT; c += 256) blockCounts[b * NT + c] = sHist[c];
}

template<int NT>
__global__ __launch_bounds__(256) void k_colsumT(const int* __restrict__ blockCounts,
                                                 int* __restrict__ blockStart,
                                                 int* __restrict__ tileTot) {
    int c = blockIdx.x * 256 + threadIdx.x;
    if (c >= NT) return;
    int running = 0;
    #pragma unroll 8
    for (int b = 0; b < HB; ++b) {
        blockStart[b * NT + c] = running;
        running += blockCounts[b * NT + c];
    }
    tileTot[c] = running;
}

template<int NT, int SEG>
__global__ __launch_bounds__(256) void k_scanT(const int* __restrict__ tileTot,
                                               int* __restrict__ offs) {
    __shared__ int sTot[NT];
    __shared__ int sPart[257];
    int tid = threadIdx.x;
    for (int c = tid; c < NT; c += 256) sTot[c] = tileTot[c];
    __syncthreads();
    int base = tid * SEG;
    int loc = 0;
    for (int j = 0; j < SEG; ++j) {
        int c = base + j;
        if (c < NT) { int v = sTot[c]; sTot[c] = loc; loc += v; }
    }
    sPart[tid] = loc;
    __syncthreads();
    if (tid == 0) {
        int s = 0;
        for (int i = 0; i < 256; ++i) { int v = sPart[i]; sPart[i] = s; s += v; }
        sPart[256] = s;
    }
    __syncthreads();
    int add = sPart[tid];
    for (int j = 0; j < SEG; ++j) {
        int c = base + j;
        if (c < NT) sTot[c] += add;
    }
    __syncthreads();
    for (int c = tid; c < NT; c += 256) offs[c] = sTot[c];
    if (tid == 0) offs[NT] = sPart[256];
}

template<int NT, int SHIFT>
__global__ __launch_bounds__(256) void k_scatterT(const int* __restrict__ keys,
                                                  const int* __restrict__ blockStart,
                                                  const int* __restrict__ offs,
                                                  int* __restrict__ eperm) {
    __shared__ int sCur[NT];
    int tid = threadIdx.x, b = blockIdx.x;
    for (int c = tid; c < NT; c += 256)
        sCur[c] = offs[c] + blockStart[b * NT + c];
    __syncthreads();
    int beg = b * EPB, end = min(beg + EPB, NE);
    for (int e = beg + tid; e < end; e += 256) {
        int pos = atomicAdd(&sCur[keys[e] >> SHIFT], 1);
        eperm[pos] = e;
    }
}

// ---- second-level sort: within each dst tile, sort by node (32 LDS bins)
__global__ __launch_bounds__(256) void k_sortNode(
    const int* __restrict__ epermD, const int* __restrict__ dst,
    const int* __restrict__ offsD, int* __restrict__ epermD2,
    int* __restrict__ nodeOffs) {
    __shared__ int sCnt[32], sStart[32];
    int tid = threadIdx.x, d = blockIdx.x;
    int beg = offsD[d], end = offsD[d + 1];
    if (tid < 32) sCnt[tid] = 0;
    __syncthreads();
    for (int p = beg + tid; p < end; p += 256)
        atomicAdd(&sCnt[dst[epermD[p]] & 31], 1);
    __syncthreads();
    if (tid == 0) {
        int s = beg;
        for (int r = 0; r < 32; ++r) { sStart[r] = s; s += sCnt[r]; }
    }
    __syncthreads();
    if (tid < 32) {
        nodeOffs[d * 32 + tid] = sStart[tid];
        sCnt[tid] = sStart[tid];       // reuse as cursor
    }
    if (d == NT_D - 1 && tid == 0) nodeOffs[NN] = end;
    __syncthreads();
    for (int p = beg + tid; p < end; p += 256) {
        int e = epermD[p];
        int pos = atomicAdd(&sCnt[dst[e] & 31], 1);
        epermD2[pos] = e;
    }
}

// ---- inverse permutation: posD2[e] = node-sorted slot
__global__ __launch_bounds__(256) void k_invperm2(const int* __restrict__ epermD2,
                                                  int* __restrict__ posD2) {
    int p = blockIdx.x * 256 + threadIdx.x;
    if (p < NE) posD2[epermD2[p]] = p;
}

// ---- fused per-8-node-src-tile: MFMA Q -> bf16 LDS, stream edges.
// MODE 0: atomicAdd into agg[dst]; MODE 1: store msg to msgbuf[posD2[e]].
template<int MODE>
__global__ __launch_bounds__(256) void k_msgF8(
    const float* __restrict__ h, const unsigned short* __restrict__ W2bf,
    const float* __restrict__ t, const int* __restrict__ src, const int* __restrict__ dst,
    const int* __restrict__ eperm, const int* __restrict__ offs,
    const int* __restrict__ posD2, float* __restrict__ outbuf) {
    __shared__ unsigned short sQ[8 * QSTRH];   // 17024 B
    __shared__ int sRow[32], sIdx[32], sEdge[32];
    int tid = threadIdx.x;
    int tile = blockIdx.x;
    int beg = offs[tile], end = offs[tile + 1];
    if (beg >= end) return;
    int nodeBase = tile * 8;
    int wave = tid >> 6, lane = tid & 63;

    // A-fragment: row = lane&15 (rows 8..15 zero)
    bf16x8 a;
    #pragma unroll
    for (int j = 0; j < 8; ++j) a[j] = 0;
    int arow = lane & 15;
    if (arow < 8) {
        const float* hp = h + (size_t)(nodeBase + arow) * 32 + ((lane >> 4) << 2);
        float4 x0 = *(const float4*)hp;
        float4 x1 = *(const float4*)(hp + 16);
        a[0] = (short)f2bf(x0.x); a[1] = (short)f2bf(x0.y);
        a[2] = (short)f2bf(x0.z); a[3] = (short)f2bf(x0.w);
        a[4] = (short)f2bf(x1.x); a[5] = (short)f2bf(x1.y);
        a[6] = (short)f2bf(x1.z); a[7] = (short)f2bf(x1.w);
    }
    f32x4 z = {0.f, 0.f, 0.f, 0.f};
    int crow0 = (lane >> 4) << 2;
    int ccol = lane & 15;
    for (int ct = wave; ct < 66; ct += 4) {
        bf16x8 b = *(const bf16x8*)(W2bf + (size_t)((ct << 6) + lane) * 8);
        f32x4 acc = __builtin_amdgcn_mfma_f32_16x16x32_bf16(a, b, z, 0, 0, 0);
        if (crow0 < 8) {
            unsigned short* qp = sQ + crow0 * QSTRH + (ct << 4) + ccol;
            qp[0 * QSTRH] = f2bf(acc[0]); qp[1 * QSTRH] = f2bf(acc[1]);
            qp[2 * QSTRH] = f2bf(acc[2]); qp[3 * QSTRH] = f2bf(acc[3]);
        }
    }
    __syncthreads();

    int el = tid >> 3, l8 = tid & 7;
    int gbase = (tid & 63) & 56;          // first lane of this 8-lane group
    for (int s0 = beg; s0 < end; s0 += 32) {
        int nact = min(32, end - s0);
        if (tid < nact) {
            int e = eperm[s0 + tid];
            sEdge[tid] = e;
            sRow[tid] = src[e] - nodeBase;
            sIdx[tid] = MODE ? posD2[e] : dst[e];
        }
        __syncthreads();
        if (el < nact) {
            int e = sEdge[el];
            float4 tv = *(const float4*)(t + (size_t)e * 32 + (l8 << 2));
            const unsigned short* qp = sQ + sRow[el] * QSTRH + (l8 << 2);
            ushort4 qb = *(const ushort4*)(qp + 1024);
            float a0 = bf2f(qb.x), a1 = bf2f(qb.y), a2 = bf2f(qb.z), a3 = bf2f(qb.w);
            #pragma unroll
            for (int kk = 0; kk < 8; ++kk) {
                float t0 = __shfl(tv.x, gbase + kk, 64);
                float t1 = __shfl(tv.y, gbase + kk, 64);
                float t2 = __shfl(tv.z, gbase + kk, 64);
                float t3 = __shfl(tv.w, gbase + kk, 64);
                ushort4 q0 = *(const ushort4*)(qp + ((kk << 2) + 0) * 32);
                ushort4 q1 = *(const ushort4*)(qp + ((kk << 2) + 1) * 32);
                ushort4 q2 = *(const ushort4*)(qp + ((kk << 2) + 2) * 32);
                ushort4 q3 = *(const ushort4*)(qp + ((kk << 2) + 3) * 32);
                a0 += t0 * bf2f(q0.x); a1 += t0 * bf2f(q0.y);
                a2 += t0 * bf2f(q0.z); a3 += t0 * bf2f(q0.w);
                a0 += t1 * bf2f(q1.x); a1 += t1 * bf2f(q1.y);
                a2 += t1 * bf2f(q1.z); a3 += t1 * bf2f(q1.w);
                a0 += t2 * bf2f(q2.x); a1 += t2 * bf2f(q2.y);
                a2 += t2 * bf2f(q2.z); a3 += t2 * bf2f(q2.w);
                a0 += t3 * bf2f(q3.x); a1 += t3 * bf2f(q3.y);
                a2 += t3 * bf2f(q3.z); a3 += t3 * bf2f(q3.w);
            }
            if (MODE) {
                *(float4*)(outbuf + (size_t)sIdx[el] * 32 + (l8 << 2)) =
                    make_float4(a0, a1, a2, a3);
            } else {
                float* ap = outbuf + (size_t)sIdx[el] * 32 + (l8 << 2);
                atomicAdd(ap + 0, a0); atomicAdd(ap + 1, a1);
                atomicAdd(ap + 2, a2); atomicAdd(ap + 3, a3);
            }
        }
        __syncthreads();
    }
}

// ---- fallback msg (tiny ws): recompute We per edge
__global__ __launch_bounds__(256) void k_msgC(
    const float* __restrict__ t, const int* __restrict__ src, const int* __restrict__ dst,
    const float* __restrict__ h, const float* __restrict__ W2ext, float* __restrict__ agg) {
    __shared__ float sT[32][33], sH[32][33];
    __shared__ int sSrc[32], sDst[32];
    int tid = threadIdx.x;
    int e0 = blockIdx.x * 32;
    if (tid < 32) sSrc[tid] = src[e0 + tid];
    else if (tid < 64) sDst[tid - 32] = dst[e0 + tid - 32];
    __syncthreads();
    for (int idx = tid; idx < 1024; idx += 256) {
        int el = idx >> 5, k = idx & 31;
        sT[el][k] = t[(e0 + el) * 32 + k];
        sH[el][k] = h[(size_t)sSrc[el] * 32 + k];
    }
    __syncthreads();
    int el = tid >> 3, l8 = tid & 7;
    int c0 = l8 * 4;
    float m0 = 0.f, m1 = 0.f, m2 = 0.f, m3 = 0.f;
    for (int i = 0; i < 32; ++i) {
        const float* wrow = W2ext + i * QC;
        float4 wb = *(const float4*)(wrow + 1024 + c0);
        float w0 = wb.x, w1 = wb.y, w2 = wb.z, w3 = wb.w;
        #pragma unroll 8
        for (int k = 0; k < 32; ++k) {
            float tk = sT[el][k];
            float4 w = *(const float4*)(wrow + k * 32 + c0);
            w0 += tk * w.x; w1 += tk * w.y; w2 += tk * w.z; w3 += tk * w.w;
        }
        float hi = sH[el][i];
        m0 += hi * w0; m1 += hi * w1; m2 += hi * w2; m3 += hi * w3;
    }
    float* ap = agg + (size_t)sDst[el] * 32 + c0;
    atomicAdd(ap + 0, m0); atomicAdd(ap + 1, m1);
    atomicAdd(ap + 2, m2); atomicAdd(ap + 3, m3);
}

// ---- GRU step reading agg[] (MODE 0 / fallback)
__global__ __launch_bounds__(256) void k_gru(
    const float* __restrict__ agg, const float* __restrict__ convB,
    const float* __restrict__ Wi, const float* __restrict__ Wh,
    const float* __restrict__ bi, const float* __restrict__ bh,
    float* __restrict__ h) {
    __shared__ float sWi[3072], sWh[3072], sBi[96], sBh[96], sCb[32];
    __shared__ float sX[8][33], sH[8][33];
    int tid = threadIdx.x;
    for (int i = tid; i < 3072; i += 256) { sWi[i] = Wi[i]; sWh[i] = Wh[i]; }
    if (tid < 96) { sBi[tid] = bi[tid]; sBh[tid] = bh[tid]; }
    if (tid < 32) sCb[tid] = convB[tid];
    int ln = tid >> 5, o = tid & 31;
    for (int g = 0; g < 4; ++g) {
        int node = blockIdx.x * 32 + g * 8 + ln;
        float hv = h[node * 32 + o];
        float av = agg[node * 32 + o];
        __syncthreads();
        sX[ln][o] = fmaxf(av + sCb[o], 0.f);
        sH[ln][o] = hv;
        __syncthreads();
        float air = sBi[o], aiz = sBi[o + 32], ain = sBi[o + 64];
        float ahr = sBh[o], ahz = sBh[o + 32], ahn = sBh[o + 64];
        #pragma unroll 8
        for (int i = 0; i < 32; ++i) {
            float x = sX[ln][i], hh = sH[ln][i];
            air += x * sWi[i * 96 + o];      ahr += hh * sWh[i * 96 + o];
            aiz += x * sWi[i * 96 + o + 32]; ahz += hh * sWh[i * 96 + o + 32];
            ain += x * sWi[i * 96 + o + 64]; ahn += hh * sWh[i * 96 + o + 64];
        }
        float r = 1.f / (1.f + __expf(-(air + ahr)));
        float zz = 1.f / (1.f + __expf(-(aiz + ahz)));
        float ng = tanhf(ain + r * ahn);
        h[node * 32 + o] = (1.f - zz) * ng + zz * hv;
    }
}

// ---- MODE 1: 2 dst tiles per block; register segment-sum; 2 barriers/tile
__global__ __launch_bounds__(256) void k_gruAgg2(
    const float* __restrict__ msgbuf, const int* __restrict__ nodeOffs,
    const float* __restrict__ convB,
    const float* __restrict__ Wi, const float* __restrict__ Wh,
    const float* __restrict__ bi, const float* __restrict__ bh,
    float* __restrict__ h) {
    __shared__ float sWi[3072], sWh[3072], sBi[96], sBh[96], sCb[32];
    __shared__ float sAgg[32 * 33];    // x = relu(agg + cb)
    __shared__ float sH[32 * 33];
    int tid = threadIdx.x;
    for (int i = tid; i < 3072; i += 256) { sWi[i] = Wi[i]; sWh[i] = Wh[i]; }
    if (tid < 96) { sBi[tid] = bi[tid]; sBh[tid] = bh[tid]; }
    if (tid < 32) sCb[tid] = convB[tid];

    int n8 = tid >> 3, l8 = tid & 7;
    int ln = tid >> 5, o = tid & 31;
    int dEnd = min(blockIdx.x * 2 + 2, NT_D);
    for (int d = blockIdx.x * 2; d < dEnd; ++d) {
        __syncthreads();                   // weights ready / sAgg,sH reuse safe
        int node = d * 32 + n8;
        int nb = nodeOffs[node], ne2 = nodeOffs[node + 1];
        float a0 = 0.f, a1 = 0.f, a2 = 0.f, a3 = 0.f;
        for (int p = nb; p < ne2; ++p) {
            float4 v = *(const float4*)(msgbuf + (size_t)p * 32 + (l8 << 2));
            a0 += v.x; a1 += v.y; a2 += v.z; a3 += v.w;
        }
        int c0 = l8 << 2;
        float* sp = sAgg + n8 * 33 + c0;
        sp[0] = fmaxf(a0 + sCb[c0 + 0], 0.f);
        sp[1] = fmaxf(a1 + sCb[c0 + 1], 0.f);
        sp[2] = fmaxf(a2 + sCb[c0 + 2], 0.f);
        sp[3] = fmaxf(a3 + sCb[c0 + 3], 0.f);
        for (int idx = tid; idx < 1024; idx += 256)
            sH[(idx >> 5) * 33 + (idx & 31)] = h[(size_t)d * 1024 + idx];
        __syncthreads();
        #pragma unroll
        for (int g = 0; g < 4; ++g) {
            int r = g * 8 + ln;
            const float* xp = sAgg + r * 33;
            const float* hp = sH + r * 33;
            float air = sBi[o], aiz = sBi[o + 32], ain = sBi[o + 64];
            float ahr = sBh[o], ahz = sBh[o + 32], ahn = sBh[o + 64];
            #pragma unroll 8
            for (int i = 0; i < 32; ++i) {
                float x = xp[i], hh = hp[i];
                air += x * sWi[i * 96 + o];      ahr += hh * sWh[i * 96 + o];
                aiz += x * sWi[i * 96 + o + 32]; ahz += hh * sWh[i * 96 + o + 32];
                ain += x * sWi[i * 96 + o + 64]; ahn += hh * sWh[i * 96 + o + 64];
            }
            float rr = 1.f / (1.f + __expf(-(air + ahr)));
            float zz = 1.f / (1.f + __expf(-(aiz + ahz)));
            float ng = tanhf(ain + rr * ahn);
            h[(size_t)(d * 32 + r) * 32 + o] = (1.f - zz) * ng + zz * hp[o];
        }
    }
}

// ---- decoder
__global__ __launch_bounds__(256) void k_dec(
    const float* __restrict__ h,
    const float* __restrict__ W1, const float* __restrict__ b1, const float* __restrict__ a1,
    const float* __restrict__ W2, const float* __restrict__ b2, const float* __restrict__ a2,
    const float* __restrict__ W3, const float* __restrict__ b3, const float* __restrict__ a3,
    const float* __restrict__ W4, const float* __restrict__ b4,
    float* __restrict__ out) {
    __shared__ float sW1[1024], sW2[1024], sW3[1024], sW4[96];
    __shared__ float sB1[32], sB2[32], sB3[32], sB4[3];
    __shared__ float sYa[8][33], sYb[8][33];
    int tid = threadIdx.x;
    for (int i = tid; i < 1024; i += 256) { sW1[i] = W1[i]; sW2[i] = W2[i]; sW3[i] = W3[i]; }
    if (tid < 96) sW4[tid] = W4[tid];
    if (tid < 32) { sB1[tid] = b1[tid]; sB2[tid] = b2[tid]; sB3[tid] = b3[tid]; }
    if (tid < 3) sB4[tid] = b4[tid];
    float A1 = a1[0], A2 = a2[0], A3 = a3[0];
    int ln = tid >> 5, o = tid & 31;
    int node = blockIdx.x * 8 + ln;
    sYa[ln][o] = h[node * 32 + o];
    __syncthreads();
    float acc = sB1[o];
    #pragma unroll
    for (int i = 0; i < 32; ++i) acc += sYa[ln][i] * sW1[i * 32 + o];
    acc = acc >= 0.f ? acc : A1 * acc;
    sYb[ln][o] = acc;
    __syncthreads();
    acc = sB2[o];
    #pragma unroll
    for (int i = 0; i < 32; ++i) acc += sYb[ln][i] * sW2[i * 32 + o];
    acc = acc >= 0.f ? acc : A2 * acc;
    __syncthreads();
    sYa[ln][o] = acc;
    __syncthreads();
    acc = sB3[o];
    #pragma unroll
    for (int i = 0; i < 32; ++i) acc += sYa[ln][i] * sW3[i * 32 + o];
    acc = acc >= 0.f ? acc : A3 * acc;
    __syncthreads();
    sYb[ln][o] = acc;
    __syncthreads();
    if (o < 3) {
        float r = sB4[o];
        #pragma unroll
        for (int i = 0; i < 32; ++i) r += sYb[ln][i] * sW4[i * 3 + o];
        out[node * 3 + o] = r;
    }
}

extern "C" void kernel_launch(void* const* d_in, const int* in_sizes, int n_in,
                              void* d_out, int out_size, void* d_ws, size_t ws_size,
                              hipStream_t stream) {
    const int*   nfeats = (const int*)d_in[0];
    const float* efeats = (const float*)d_in[1];
    const int*   src    = (const int*)d_in[2];
    const int*   dst    = (const int*)d_in[3];
    const float* emb    = (const float*)d_in[4];
    const float* encW   = (const float*)d_in[5];
    const float* encB   = (const float*)d_in[6];
    const float* eencW  = (const float*)d_in[7];
    const float* eencB  = (const float*)d_in[8];
    const float* projW  = (const float*)d_in[9];
    const float* projB  = (const float*)d_in[10];
    const float* enW1   = (const float*)d_in[11];
    const float* enB1   = (const float*)d_in[12];
    const float* enW2   = (const float*)d_in[13];
    const float* enB2   = (const float*)d_in[14];
    const float* convB  = (const float*)d_in[15];
    const float* gruWi  = (const float*)d_in[16];
    const float* gruWh  = (const float*)d_in[17];
    const float* gruBi  = (const float*)d_in[18];
    const float* gruBh  = (const float*)d_in[19];
    const float* dW1 = (const float*)d_in[20]; const float* db1 = (const float*)d_in[21]; const float* da1 = (const float*)d_in[22];
    const float* dW2 = (const float*)d_in[23]; const float* db2 = (const float*)d_in[24]; const float* da2 = (const float*)d_in[25];
    const float* dW3 = (const float*)d_in[26]; const float* db3 = (const float*)d_in[27]; const float* da3 = (const float*)d_in[28];
    const float* dW4 = (const float*)d_in[29]; const float* db4 = (const float*)d_in[30];
    float* out = (float*)d_out;
    char* ws = (char*)d_ws;

    // bump allocator (256-B aligned)
    size_t cur = 0;
    auto alloc = [&](size_t n) { size_t p = cur; cur = (cur + n + 255) & ~(size_t)255; return p; };
    size_t o_h   = alloc((size_t)NN * 32 * 4);
    size_t o_t   = alloc((size_t)NE * 32 * 4);
    size_t o_w2e = alloc((size_t)32 * QC * 4);
    size_t afterCommon = cur;                       // fallback agg goes here
    size_t o_w2b = alloc((size_t)66 * 512 * 2);
    size_t o_epS = alloc((size_t)NE * 4);
    size_t o_ofS = alloc((size_t)(NT_S + 1) * 4);
    size_t baseEnd = cur;                           // MODE0 agg goes here
    size_t o_epD  = alloc((size_t)NE * 4);
    size_t o_ofD  = alloc((size_t)(NT_D + 1) * 4);
    size_t o_epD2 = alloc((size_t)NE * 4);
    size_t o_pos2 = alloc((size_t)NE * 4);
    size_t o_noff = alloc((size_t)(NN + 1) * 4);
    size_t o_msg  = alloc((size_t)NE * 32 * 4);     // MODE1 msgbuf
    size_t need1 = cur;
    size_t need0 = baseEnd + (size_t)NN * 32 * 4;

    int mode;                                       // 1: node-sorted, 0: atomic, -1: msgC
    if (ws_size >= need1) mode = 1;
    else if (ws_size >= need0) mode = 0;
    else mode = -1;

    float* h     = (float*)(ws + o_h);
    float* t     = (float*)(ws + o_t);
    float* W2ext = (float*)(ws + o_w2e);
    unsigned short* W2bf = (unsigned short*)(ws + o_w2b);
    int* epermS  = (int*)(ws + o_epS);
    int* offsS   = (int*)(ws + o_ofS);
    int* epermD  = (int*)(ws + o_epD);
    int* offsD   = (int*)(ws + o_ofD);
    int* epermD2 = (int*)(ws + o_epD2);
    int* posD2   = (int*)(ws + o_pos2);
    int* nodeOffs = (int*)(ws + o_noff);
    float* outbuf = (mode == 1) ? (float*)(ws + o_msg)
                  : (mode == 0) ? (float*)(ws + baseEnd)
                                : (float*)(ws + afterCommon);
    // scratch (prologue only) unions into outbuf region
    int* blockCounts = (int*)outbuf;
    int* blockStart  = blockCounts + (size_t)HB * NT_S;
    int* tileTot     = blockStart + (size_t)HB * NT_S;

    k_w2ext<<<(32 * QC + 255) / 256, 256, 0, stream>>>(enW2, enB2, W2ext);
    k_node_enc<<<NN / 8, 256, 0, stream>>>(nfeats, emb, encW, encB, projW, projB, h);
    k_edge_t<<<NE / 8, 256, 0, stream>>>(efeats, eencW, eencB, enW1, enB1, t);

    if (mode >= 0) {
        k_w2prep<<<(66 * 512 + 255) / 256, 256, 0, stream>>>(enW2, enB2, W2bf);
        // src bucketing (8-node tiles)
        k_histT<NT_S, 3><<<HB, 256, 0, stream>>>(src, blockCounts);
        k_colsumT<NT_S><<<(NT_S + 255) / 256, 256, 0, stream>>>(blockCounts, blockStart, tileTot);
        k_scanT<NT_S, 49><<<1, 256, 0, stream>>>(tileTot, offsS);
        k_scatterT<NT_S, 3><<<HB, 256, 0, stream>>>(src, blockStart, offsS, epermS);
        if (mode == 1) {
            // dst bucketing (32-node tiles) -> per-node sort -> inverse perm
            k_histT<NT_D, 5><<<HB, 256, 0, stream>>>(dst, blockCounts);
            k_colsumT<NT_D><<<(NT_D + 255) / 256, 256, 0, stream>>>(blockCounts, blockStart, tileTot);
            k_scanT<NT_D, 13><<<1, 256, 0, stream>>>(tileTot, offsD);
            k_scatterT<NT_D, 5><<<HB, 256, 0, stream>>>(dst, blockStart, offsD, epermD);
            k_sortNode<<<NT_D, 256, 0, stream>>>(epermD, dst, offsD, epermD2, nodeOffs);
            k_invperm2<<<(NE + 255) / 256, 256, 0, stream>>>(epermD2, posD2);
        }
    }

    for (int s = 0; s < 3; ++s) {
        if (mode == 1) {
            k_msgF8<1><<<NT_S, 256, 0, stream>>>(h, W2bf, t, src, dst, epermS, offsS, posD2, outbuf);
            k_gruAgg2<<<(NT_D + 1) / 2, 256, 0, stream>>>(outbuf, nodeOffs, convB,
                                                          gruWi, gruWh, gruBi, gruBh, h);
        } else if (mode == 0) {
            hipMemsetAsync(outbuf, 0, (size_t)NN * 32 * 4, stream);
            k_msgF8<0><<<NT_S, 256, 0, stream>>>(h, W2bf, t, src, dst, epermS, offsS, nullptr, outbuf);
            k_gru<<<NN / 32, 256, 0, stream>>>(outbuf, convB, gruWi, gruWh, gruBi, gruBh, h);
        } else {
            hipMemsetAsync(outbuf, 0, (size_t)NN * 32 * 4, stream);
            k_msgC<<<NE / 32, 256, 0, stream>>>(t, src, dst, h, W2ext, outbuf);
            k_gru<<<NN / 32, 256, 0, stream>>>(outbuf, convB, gruWi, gruWh, gruBi, gruBh, h);
        }
    }
    k_dec<<<NN / 8, 256, 0, stream>>>(h, dW1, db1, da1, dW2, db2, da2, dW3, db3, da3, dW4, db4, out);
}

// Round 9
// 688.318 us; speedup vs baseline: 3.0570x; 1.1001x over previous
//
#include <hip/hip_runtime.h>
#include <hip/hip_bf16.h>

// MPNN on MI355X — fused 16-node-tile kernel, MFMA Q-phase, fully pre-sorted streams.
// msg[e,o] = sum_k t[e,k]*Q[src,k,o] + q0[src,o],  Q[n] = h[n] @ W2ext
// Prologue sorts edges by 16-node src tile; t is materialized in src-sorted order
// (tS), srcS/idxS give per-position src node and dst-node-sorted write slot.
// k_msgF16: per tile, MFMA Q (16x1056 bf16) into LDS, stream edges (all reads
// coalesced), write msg to node-sorted slot. k_gruAgg2: register segment-sum
// per dst node + GRU, 4 dst-tiles/block. No global atomics (MODE1).

#define NN 100000
#define NE 320000
#define QC 1056
#define NTS 6250      // NN/16 src tiles
#define NT_D 3125     // NN/32 dst tiles
#define HB 128        // bucketing blocks
#define EPB (NE / HB) // 2500
#define QSTRH 1064    // sQ row stride (shorts)

typedef short bf16x8 __attribute__((ext_vector_type(8)));
typedef float f32x4  __attribute__((ext_vector_type(4)));

__device__ __forceinline__ float bf2f(unsigned short u) {
    return __uint_as_float(((unsigned int)u) << 16);
}
__device__ __forceinline__ unsigned short f2bf(float f) {
    unsigned int x = __float_as_uint(f);
    unsigned int r = (x + 0x7fffu + ((x >> 16) & 1u)) >> 16;
    return (unsigned short)r;
}

// ---- build W2ext [32][1056] (fp32, msgC fallback only)
__global__ __launch_bounds__(256) void k_w2ext(const float* __restrict__ W2,
                                               const float* __restrict__ b2,
                                               float* __restrict__ W2ext) {
    int idx = blockIdx.x * 256 + threadIdx.x;
    if (idx >= 32 * QC) return;
    int i = idx / QC, c = idx % QC;
    float v;
    if (c < 1024) { int k = c >> 5, o = c & 31; v = W2[k * 1024 + i * 32 + o]; }
    else          { v = b2[i * 32 + (c - 1024)]; }
    W2ext[idx] = v;
}

// ---- pack W2ext into bf16 B-fragment layout
// W2bf[(ct*64+l)*8+j] = B[kmap(l,j)][ct*16+(l&15)], kmap = (j>>2)*16+(l>>4)*4+(j&3)
__global__ __launch_bounds__(256) void k_w2prep(const float* __restrict__ W2,
                                                const float* __restrict__ b2,
                                                unsigned short* __restrict__ W2bf) {
    int idx = blockIdx.x * 256 + threadIdx.x;
    if (idx >= 66 * 512) return;
    int ct = idx >> 9, l = (idx >> 3) & 63, j = idx & 7;
    int kk = ((j >> 2) << 4) + ((l >> 4) << 2) + (j & 3);
    int c = ct * 16 + (l & 15);
    float v;
    if (c < 1024) { int kb = c >> 5, o = c & 31; v = W2[kb * 1024 + kk * 32 + o]; }
    else          { v = b2[kk * 32 + (c - 1024)]; }
    W2bf[idx] = f2bf(v);
}

// ---- node encoder + projection
__global__ __launch_bounds__(256) void k_node_enc(
    const int* __restrict__ nfeats, const float* __restrict__ emb,
    const float* __restrict__ encW, const float* __restrict__ encB,
    const float* __restrict__ projW, const float* __restrict__ projB,
    float* __restrict__ h) {
    __shared__ float sEncW[1024], sProjW[1024], sEncB[32], sProjB[32];
    __shared__ float sEmb[8][33], sNh[8][33];
    int tid = threadIdx.x;
    for (int i = tid; i < 1024; i += 256) { sEncW[i] = encW[i]; sProjW[i] = projW[i]; }
    if (tid < 32) { sEncB[tid] = encB[tid]; sProjB[tid] = projB[tid]; }
    int ln = tid >> 5, o = tid & 31;
    int node = blockIdx.x * 8 + ln;
    int nt = nfeats[node];
    sEmb[ln][o] = fmaxf(emb[nt * 32 + o], 0.f);
    __syncthreads();
    float acc = sEncB[o];
    #pragma unroll
    for (int i = 0; i < 32; ++i) acc += sEmb[ln][i] * sEncW[i * 32 + o];
    sNh[ln][o] = fmaxf(acc, 0.f);
    __syncthreads();
    float acc2 = sProjB[o];
    #pragma unroll
    for (int i = 0; i < 32; ++i) acc2 += sNh[ln][i] * sProjW[i * 32 + o];
    h[node * 32 + o] = fmaxf(acc2, 0.f);
}

// ---- edge encoder; writes t row to posS[e] (src-sorted) when posS != nullptr
__global__ __launch_bounds__(256) void k_edge_t(
    const float* __restrict__ efeats,
    const float* __restrict__ eencW, const float* __restrict__ eencB,
    const float* __restrict__ enW1, const float* __restrict__ enB1,
    const int* __restrict__ posS, float* __restrict__ t) {
    __shared__ float sEW[512], sW1[1024], sEB[32], sB1[32];
    __shared__ float sEf[8][17], sEh[8][33];
    int tid = threadIdx.x;
    for (int i = tid; i < 512; i += 256) sEW[i] = eencW[i];
    for (int i = tid; i < 1024; i += 256) sW1[i] = enW1[i];
    if (tid < 32) { sEB[tid] = eencB[tid]; sB1[tid] = enB1[tid]; }
    int ln = tid >> 5, o = tid & 31;
    int e = blockIdx.x * 8 + ln;
    if (o < 16) sEf[ln][o] = efeats[e * 16 + o];
    __syncthreads();
    float acc = sEB[o];
    #pragma unroll
    for (int i = 0; i < 16; ++i) acc += sEf[ln][i] * sEW[i * 32 + o];
    sEh[ln][o] = acc;
    __syncthreads();
    float acc2 = sB1[o];
    #pragma unroll
    for (int i = 0; i < 32; ++i) acc2 += sEh[ln][i] * sW1[i * 32 + o];
    int row = posS ? posS[e] : e;
    t[(size_t)row * 32 + o] = fmaxf(acc2, 0.f);
}

// ---- generic counting-sort bucketing
template<int NT, int SHIFT>
__global__ __launch_bounds__(256) void k_histT(const int* __restrict__ keys,
                                               int* __restrict__ blockCounts) {
    __shared__ int sHist[NT];
    int tid = threadIdx.x, b = blockIdx.x;
    for (int c = tid; c < NT; c += 256) sHist[c] = 0;
    __syncthreads();
    int beg = b * EPB, end = min(beg + EPB, NE);
    for (int e = beg + tid; e < end; e += 256)
        atomicAdd(&sHist[keys[e] >> SHIFT], 1);
    __syncthreads();
    for (int c = tid; c < NT; c += 256) blockCounts[b * NT + c] = sHist[c];
}

template<int NT>
__global__ __launch_bounds__(256) void k_colsumT(const int* __restrict__ blockCounts,
                                                 int* __restrict__ blockStart,
                                                 int* __restrict__ tileTot) {
    int c = blockIdx.x * 256 + threadIdx.x;
    if (c >= NT) return;
    int running = 0;
    #pragma unroll 8
    for (int b = 0; b < HB; ++b) {
        blockStart[b * NT + c] = running;
        running += blockCounts[b * NT + c];
    }
    tileTot[c] = running;
}

template<int NT, int SEG>
__global__ __launch_bounds__(256) void k_scanT(const int* __restrict__ tileTot,
                                               int* __restrict__ offs) {
    __shared__ int sTot[NT];
    __shared__ int sPart[257];
    int tid = threadIdx.x;
    for (int c = tid; c < NT; c += 256) sTot[c] = tileTot[c];
    __syncthreads();
    int base = tid * SEG;
    int loc = 0;
    for (int j = 0; j < SEG; ++j) {
        int c = base + j;
        if (c < NT) { int v = sTot[c]; sTot[c] = loc; loc += v; }
    }
    sPart[tid] = loc;
    __syncthreads();
    if (tid == 0) {
        int s = 0;
        for (int i = 0; i < 256; ++i) { int v = sPart[i]; sPart[i] = s; s += v; }
        sPart[256] = s;
    }
    __syncthreads();
    int add = sPart[tid];
    for (int j = 0; j < SEG; ++j) {
        int c = base + j;
        if (c < NT) sTot[c] += add;
    }
    __syncthreads();
    for (int c = tid; c < NT; c += 256) offs[c] = sTot[c];
    if (tid == 0) offs[NT] = sPart[256];
}

template<int NT, int SHIFT>
__global__ __launch_bounds__(256) void k_scatterT(const int* __restrict__ keys,
                                                  const int* __restrict__ blockStart,
                                                  const int* __restrict__ offs,
                                                  int* __restrict__ eperm) {
    __shared__ int sCur[NT];
    int tid = threadIdx.x, b = blockIdx.x;
    for (int c = tid; c < NT; c += 256)
        sCur[c] = offs[c] + blockStart[b * NT + c];
    __syncthreads();
    int beg = b * EPB, end = min(beg + EPB, NE);
    for (int e = beg + tid; e < end; e += 256) {
        int pos = atomicAdd(&sCur[keys[e] >> SHIFT], 1);
        eperm[pos] = e;
    }
}

// ---- second-level sort: within each dst tile, sort by node (32 LDS bins)
__global__ __launch_bounds__(256) void k_sortNode(
    const int* __restrict__ epermD, const int* __restrict__ dst,
    const int* __restrict__ offsD, int* __restrict__ epermD2,
    int* __restrict__ nodeOffs) {
    __shared__ int sCnt[32], sStart[32];
    int tid = threadIdx.x, d = blockIdx.x;
    int beg = offsD[d], end = offsD[d + 1];
    if (tid < 32) sCnt[tid] = 0;
    __syncthreads();
    for (int p = beg + tid; p < end; p += 256)
        atomicAdd(&sCnt[dst[epermD[p]] & 31], 1);
    __syncthreads();
    if (tid == 0) {
        int s = beg;
        for (int r = 0; r < 32; ++r) { sStart[r] = s; s += sCnt[r]; }
    }
    __syncthreads();
    if (tid < 32) {
        nodeOffs[d * 32 + tid] = sStart[tid];
        sCnt[tid] = sStart[tid];       // reuse as cursor
    }
    if (d == NT_D - 1 && tid == 0) nodeOffs[NN] = end;
    __syncthreads();
    for (int p = beg + tid; p < end; p += 256) {
        int e = epermD[p];
        int pos = atomicAdd(&sCnt[dst[e] & 31], 1);
        epermD2[pos] = e;
    }
}

// ---- inverse permutation: pos[eperm[p]] = p
__global__ __launch_bounds__(256) void k_invperm(const int* __restrict__ eperm,
                                                 int* __restrict__ pos) {
    int p = blockIdx.x * 256 + threadIdx.x;
    if (p < NE) pos[eperm[p]] = p;
}

// ---- gather key into src-sorted positions: out[p] = key[epermS[p]]
__global__ __launch_bounds__(256) void k_gatherKey(const int* __restrict__ epermS,
                                                   const int* __restrict__ key,
                                                   int* __restrict__ out) {
    int p = blockIdx.x * 256 + threadIdx.x;
    if (p < NE) out[p] = key[epermS[p]];
}

// ---- idxS[posS[epermD2[q]]] = q  (src-sorted position -> dst-node-sorted slot)
__global__ __launch_bounds__(256) void k_scatterIdx(const int* __restrict__ epermD2,
                                                    const int* __restrict__ posS,
                                                    int* __restrict__ idxS) {
    int q = blockIdx.x * 256 + threadIdx.x;
    if (q < NE) idxS[posS[epermD2[q]]] = q;
}

// ---- fused per-16-node-src-tile: MFMA Q -> bf16 LDS, stream edges.
// MODE 0: atomicAdd into agg[idxS=dst]; MODE 1: store to msgbuf[idxS=slot].
template<int MODE>
__global__ __launch_bounds__(256) void k_msgF16(
    const float* __restrict__ h, const unsigned short* __restrict__ W2bf,
    const float* __restrict__ tS, const int* __restrict__ srcS,
    const int* __restrict__ idxS, const int* __restrict__ offs,
    float* __restrict__ outbuf) {
    __shared__ unsigned short sQ[16 * QSTRH];   // 34048 B
    __shared__ int sRow[32], sIdx[32];
    int tid = threadIdx.x;
    int tile = blockIdx.x;
    int beg = offs[tile], end = offs[tile + 1];
    if (beg >= end) return;
    int nodeBase = tile * 16;
    int wave = tid >> 6, lane = tid & 63;

    // A-fragment: all 16 rows used
    int arow = lane & 15;
    const float* hp = h + (size_t)(nodeBase + arow) * 32 + ((lane >> 4) << 2);
    float4 x0 = *(const float4*)hp;
    float4 x1 = *(const float4*)(hp + 16);
    bf16x8 a;
    a[0] = (short)f2bf(x0.x); a[1] = (short)f2bf(x0.y);
    a[2] = (short)f2bf(x0.z); a[3] = (short)f2bf(x0.w);
    a[4] = (short)f2bf(x1.x); a[5] = (short)f2bf(x1.y);
    a[6] = (short)f2bf(x1.z); a[7] = (short)f2bf(x1.w);

    f32x4 z = {0.f, 0.f, 0.f, 0.f};
    int crow0 = (lane >> 4) << 2;
    int ccol = lane & 15;
    for (int ct = wave; ct < 66; ct += 4) {
        bf16x8 b = *(const bf16x8*)(W2bf + (size_t)((ct << 6) + lane) * 8);
        f32x4 acc = __builtin_amdgcn_mfma_f32_16x16x32_bf16(a, b, z, 0, 0, 0);
        unsigned short* qp = sQ + crow0 * QSTRH + (ct << 4) + ccol;
        qp[0 * QSTRH] = f2bf(acc[0]); qp[1 * QSTRH] = f2bf(acc[1]);
        qp[2 * QSTRH] = f2bf(acc[2]); qp[3 * QSTRH] = f2bf(acc[3]);
    }
    __syncthreads();

    int el = tid >> 3, l8 = tid & 7;
    int gbase = lane & 56;                // first lane of this 8-lane group
    for (int s0 = beg; s0 < end; s0 += 32) {
        int nact = min(32, end - s0);
        if (tid < nact) {
            sRow[tid] = srcS[s0 + tid] - nodeBase;
            sIdx[tid] = idxS[s0 + tid];
        }
        __syncthreads();
        if (el < nact) {
            float4 tv = *(const float4*)(tS + (size_t)(s0 + el) * 32 + (l8 << 2));
            const unsigned short* qp = sQ + sRow[el] * QSTRH + (l8 << 2);
            ushort4 qb = *(const ushort4*)(qp + 1024);
            float a0 = bf2f(qb.x), a1 = bf2f(qb.y), a2 = bf2f(qb.z), a3 = bf2f(qb.w);
            #pragma unroll
            for (int kk = 0; kk < 8; ++kk) {
                float t0 = __shfl(tv.x, gbase + kk, 64);
                float t1 = __shfl(tv.y, gbase + kk, 64);
                float t2 = __shfl(tv.z, gbase + kk, 64);
                float t3 = __shfl(tv.w, gbase + kk, 64);
                ushort4 q0 = *(const ushort4*)(qp + ((kk << 2) + 0) * 32);
                ushort4 q1 = *(const ushort4*)(qp + ((kk << 2) + 1) * 32);
                ushort4 q2 = *(const ushort4*)(qp + ((kk << 2) + 2) * 32);
                ushort4 q3 = *(const ushort4*)(qp + ((kk << 2) + 3) * 32);
                a0 += t0 * bf2f(q0.x); a1 += t0 * bf2f(q0.y);
                a2 += t0 * bf2f(q0.z); a3 += t0 * bf2f(q0.w);
                a0 += t1 * bf2f(q1.x); a1 += t1 * bf2f(q1.y);
                a2 += t1 * bf2f(q1.z); a3 += t1 * bf2f(q1.w);
                a0 += t2 * bf2f(q2.x); a1 += t2 * bf2f(q2.y);
                a2 += t2 * bf2f(q2.z); a3 += t2 * bf2f(q2.w);
                a0 += t3 * bf2f(q3.x); a1 += t3 * bf2f(q3.y);
                a2 += t3 * bf2f(q3.z); a3 += t3 * bf2f(q3.w);
            }
            if (MODE) {
                *(float4*)(outbuf + (size_t)sIdx[el] * 32 + (l8 << 2)) =
                    make_float4(a0, a1, a2, a3);
            } else {
                float* ap = outbuf + (size_t)sIdx[el] * 32 + (l8 << 2);
                atomicAdd(ap + 0, a0); atomicAdd(ap + 1, a1);
                atomicAdd(ap + 2, a2); atomicAdd(ap + 3, a3);
            }
        }
        __syncthreads();
    }
}

// ---- fallback msg (tiny ws): recompute We per edge (t in original order)
__global__ __launch_bounds__(256) void k_msgC(
    const float* __restrict__ t, const int* __restrict__ src, const int* __restrict__ dst,
    const float* __restrict__ h, const float* __restrict__ W2ext, float* __restrict__ agg) {
    __shared__ float sT[32][33], sH[32][33];
    __shared__ int sSrc[32], sDst[32];
    int tid = threadIdx.x;
    int e0 = blockIdx.x * 32;
    if (tid < 32) sSrc[tid] = src[e0 + tid];
    else if (tid < 64) sDst[tid - 32] = dst[e0 + tid - 32];
    __syncthreads();
    for (int idx = tid; idx < 1024; idx += 256) {
        int el = idx >> 5, k = idx & 31;
        sT[el][k] = t[(e0 + el) * 32 + k];
        sH[el][k] = h[(size_t)sSrc[el] * 32 + k];
    }
    __syncthreads();
    int el = tid >> 3, l8 = tid & 7;
    int c0 = l8 * 4;
    float m0 = 0.f, m1 = 0.f, m2 = 0.f, m3 = 0.f;
    for (int i = 0; i < 32; ++i) {
        const float* wrow = W2ext + i * QC;
        float4 wb = *(const float4*)(wrow + 1024 + c0);
        float w0 = wb.x, w1 = wb.y, w2 = wb.z, w3 = wb.w;
        #pragma unroll 8
        for (int k = 0; k < 32; ++k) {
            float tk = sT[el][k];
            float4 w = *(const float4*)(wrow + k * 32 + c0);
            w0 += tk * w.x; w1 += tk * w.y; w2 += tk * w.z; w3 += tk * w.w;
        }
        float hi = sH[el][i];
        m0 += hi * w0; m1 += hi * w1; m2 += hi * w2; m3 += hi * w3;
    }
    float* ap = agg + (size_t)sDst[el] * 32 + c0;
    atomicAdd(ap + 0, m0); atomicAdd(ap + 1, m1);
    atomicAdd(ap + 2, m2); atomicAdd(ap + 3, m3);
}

// ---- GRU step reading agg[] (MODE 0 / fallback)
__global__ __launch_bounds__(256) void k_gru(
    const float* __restrict__ agg, const float* __restrict__ convB,
    const float* __restrict__ Wi, const float* __restrict__ Wh,
    const float* __restrict__ bi, const float* __restrict__ bh,
    float* __restrict__ h) {
    __shared__ float sWi[3072], sWh[3072], sBi[96], sBh[96], sCb[32];
    __shared__ float sX[8][33], sH[8][33];
    int tid = threadIdx.x;
    for (int i = tid; i < 3072; i += 256) { sWi[i] = Wi[i]; sWh[i] = Wh[i]; }
    if (tid < 96) { sBi[tid] = bi[tid]; sBh[tid] = bh[tid]; }
    if (tid < 32) sCb[tid] = convB[tid];
    int ln = tid >> 5, o = tid & 31;
    for (int g = 0; g < 4; ++g) {
        int node = blockIdx.x * 32 + g * 8 + ln;
        float hv = h[node * 32 + o];
        float av = agg[node * 32 + o];
        __syncthreads();
        sX[ln][o] = fmaxf(av + sCb[o], 0.f);
        sH[ln][o] = hv;
        __syncthreads();
        float air = sBi[o], aiz = sBi[o + 32], ain = sBi[o + 64];
        float ahr = sBh[o], ahz = sBh[o + 32], ahn = sBh[o + 64];
        #pragma unroll 8
        for (int i = 0; i < 32; ++i) {
            float x = sX[ln][i], hh = sH[ln][i];
            air += x * sWi[i * 96 + o];      ahr += hh * sWh[i * 96 + o];
            aiz += x * sWi[i * 96 + o + 32]; ahz += hh * sWh[i * 96 + o + 32];
            ain += x * sWi[i * 96 + o + 64]; ahn += hh * sWh[i * 96 + o + 64];
        }
        float r = 1.f / (1.f + __expf(-(air + ahr)));
        float zz = 1.f / (1.f + __expf(-(aiz + ahz)));
        float ng = tanhf(ain + r * ahn);
        h[node * 32 + o] = (1.f - zz) * ng + zz * hv;
    }
}

// ---- MODE 1: 4 dst tiles per block; register segment-sum; 2 barriers/tile
__global__ __launch_bounds__(256) void k_gruAgg2(
    const float* __restrict__ msgbuf, const int* __restrict__ nodeOffs,
    const float* __restrict__ convB,
    const float* __restrict__ Wi, const float* __restrict__ Wh,
    const float* __restrict__ bi, const float* __restrict__ bh,
    float* __restrict__ h) {
    __shared__ float sWi[3072], sWh[3072], sBi[96], sBh[96], sCb[32];
    __shared__ float sAgg[32 * 33];    // x = relu(agg + cb)
    __shared__ float sH[32 * 33];
    int tid = threadIdx.x;
    for (int i = tid; i < 3072; i += 256) { sWi[i] = Wi[i]; sWh[i] = Wh[i]; }
    if (tid < 96) { sBi[tid] = bi[tid]; sBh[tid] = bh[tid]; }
    if (tid < 32) sCb[tid] = convB[tid];

    int n8 = tid >> 3, l8 = tid & 7;
    int ln = tid >> 5, o = tid & 31;
    int dEnd = min(blockIdx.x * 4 + 4, NT_D);
    for (int d = blockIdx.x * 4; d < dEnd; ++d) {
        __syncthreads();                   // weights ready / sAgg,sH reuse safe
        int node = d * 32 + n8;
        int nb = nodeOffs[node], ne2 = nodeOffs[node + 1];
        float a0 = 0.f, a1 = 0.f, a2 = 0.f, a3 = 0.f;
        for (int p = nb; p < ne2; ++p) {
            float4 v = *(const float4*)(msgbuf + (size_t)p * 32 + (l8 << 2));
            a0 += v.x; a1 += v.y; a2 += v.z; a3 += v.w;
        }
        int c0 = l8 << 2;
        float* sp = sAgg + n8 * 33 + c0;
        sp[0] = fmaxf(a0 + sCb[c0 + 0], 0.f);
        sp[1] = fmaxf(a1 + sCb[c0 + 1], 0.f);
        sp[2] = fmaxf(a2 + sCb[c0 + 2], 0.f);
        sp[3] = fmaxf(a3 + sCb[c0 + 3], 0.f);
        for (int idx = tid; idx < 1024; idx += 256)
            sH[(idx >> 5) * 33 + (idx & 31)] = h[(size_t)d * 1024 + idx];
        __syncthreads();
        #pragma unroll
        for (int g = 0; g < 4; ++g) {
            int r = g * 8 + ln;
            const float* xp = sAgg + r * 33;
            const float* hpp = sH + r * 33;
            float air = sBi[o], aiz = sBi[o + 32], ain = sBi[o + 64];
            float ahr = sBh[o], ahz = sBh[o + 32], ahn = sBh[o + 64];
            #pragma unroll 8
            for (int i = 0; i < 32; ++i) {
                float x = xp[i], hh = hpp[i];
                air += x * sWi[i * 96 + o];      ahr += hh * sWh[i * 96 + o];
                aiz += x * sWi[i * 96 + o + 32]; ahz += hh * sWh[i * 96 + o + 32];
                ain += x * sWi[i * 96 + o + 64]; ahn += hh * sWh[i * 96 + o + 64];
            }
            float rr = 1.f / (1.f + __expf(-(air + ahr)));
            float zz = 1.f / (1.f + __expf(-(aiz + ahz)));
            float ng = tanhf(ain + rr * ahn);
            h[(size_t)(d * 32 + r) * 32 + o] = (1.f - zz) * ng + zz * hpp[o];
        }
    }
}

// ---- decoder
__global__ __launch_bounds__(256) void k_dec(
    const float* __restrict__ h,
    const float* __restrict__ W1, const float* __restrict__ b1, const float* __restrict__ a1,
    const float* __restrict__ W2, const float* __restrict__ b2, const float* __restrict__ a2,
    const float* __restrict__ W3, const float* __restrict__ b3, const float* __restrict__ a3,
    const float* __restrict__ W4, const float* __restrict__ b4,
    float* __restrict__ out) {
    __shared__ float sW1[1024], sW2[1024], sW3[1024], sW4[96];
    __shared__ float sB1[32], sB2[32], sB3[32], sB4[3];
    __shared__ float sYa[8][33], sYb[8][33];
    int tid = threadIdx.x;
    for (int i = tid; i < 1024; i += 256) { sW1[i] = W1[i]; sW2[i] = W2[i]; sW3[i] = W3[i]; }
    if (tid < 96) sW4[tid] = W4[tid];
    if (tid < 32) { sB1[tid] = b1[tid]; sB2[tid] = b2[tid]; sB3[tid] = b3[tid]; }
    if (tid < 3) sB4[tid] = b4[tid];
    float A1 = a1[0], A2 = a2[0], A3 = a3[0];
    int ln = tid >> 5, o = tid & 31;
    int node = blockIdx.x * 8 + ln;
    sYa[ln][o] = h[node * 32 + o];
    __syncthreads();
    float acc = sB1[o];
    #pragma unroll
    for (int i = 0; i < 32; ++i) acc += sYa[ln][i] * sW1[i * 32 + o];
    acc = acc >= 0.f ? acc : A1 * acc;
    sYb[ln][o] = acc;
    __syncthreads();
    acc = sB2[o];
    #pragma unroll
    for (int i = 0; i < 32; ++i) acc += sYb[ln][i] * sW2[i * 32 + o];
    acc = acc >= 0.f ? acc : A2 * acc;
    __syncthreads();
    sYa[ln][o] = acc;
    __syncthreads();
    acc = sB3[o];
    #pragma unroll
    for (int i = 0; i < 32; ++i) acc += sYa[ln][i] * sW3[i * 32 + o];
    acc = acc >= 0.f ? acc : A3 * acc;
    __syncthreads();
    sYb[ln][o] = acc;
    __syncthreads();
    if (o < 3) {
        float r = sB4[o];
        #pragma unroll
        for (int i = 0; i < 32; ++i) r += sYb[ln][i] * sW4[i * 3 + o];
        out[node * 3 + o] = r;
    }
}

extern "C" void kernel_launch(void* const* d_in, const int* in_sizes, int n_in,
                              void* d_out, int out_size, void* d_ws, size_t ws_size,
                              hipStream_t stream) {
    const int*   nfeats = (const int*)d_in[0];
    const float* efeats = (const float*)d_in[1];
    const int*   src    = (const int*)d_in[2];
    const int*   dst    = (const int*)d_in[3];
    const float* emb    = (const float*)d_in[4];
    const float* encW   = (const float*)d_in[5];
    const float* encB   = (const float*)d_in[6];
    const float* eencW  = (const float*)d_in[7];
    const float* eencB  = (const float*)d_in[8];
    const float* projW  = (const float*)d_in[9];
    const float* projB  = (const float*)d_in[10];
    const float* enW1   = (const float*)d_in[11];
    const float* enB1   = (const float*)d_in[12];
    const float* enW2   = (const float*)d_in[13];
    const float* enB2   = (const float*)d_in[14];
    const float* convB  = (const float*)d_in[15];
    const float* gruWi  = (const float*)d_in[16];
    const float* gruWh  = (const float*)d_in[17];
    const float* gruBi  = (const float*)d_in[18];
    const float* gruBh  = (const float*)d_in[19];
    const float* dW1 = (const float*)d_in[20]; const float* db1 = (const float*)d_in[21]; const float* da1 = (const float*)d_in[22];
    const float* dW2 = (const float*)d_in[23]; const float* db2 = (const float*)d_in[24]; const float* da2 = (const float*)d_in[25];
    const float* dW3 = (const float*)d_in[26]; const float* db3 = (const float*)d_in[27]; const float* da3 = (const float*)d_in[28];
    const float* dW4 = (const float*)d_in[29]; const float* db4 = (const float*)d_in[30];
    float* out = (float*)d_out;
    char* ws = (char*)d_ws;

    // bump allocator (256-B aligned)
    size_t cur = 0;
    auto alloc = [&](size_t n) { size_t p = cur; cur = (cur + n + 255) & ~(size_t)255; return p; };
    size_t o_h   = alloc((size_t)NN * 32 * 4);
    size_t o_t   = alloc((size_t)NE * 32 * 4);      // tS (or t in fallback)
    size_t o_w2e = alloc((size_t)32 * QC * 4);
    size_t afterCommon = cur;                       // fallback agg goes here
    size_t o_w2b = alloc((size_t)66 * 512 * 2);
    size_t o_epS = alloc((size_t)NE * 4);
    size_t o_ofS = alloc((size_t)(NTS + 1) * 4);
    size_t o_posS = alloc((size_t)NE * 4);
    size_t o_srcS = alloc((size_t)NE * 4);
    size_t o_idxS = alloc((size_t)NE * 4);
    size_t baseEnd = cur;                           // MODE0 agg goes here
    size_t o_epD  = alloc((size_t)NE * 4);
    size_t o_ofD  = alloc((size_t)(NT_D + 1) * 4);
    size_t o_epD2 = alloc((size_t)NE * 4);
    size_t o_noff = alloc((size_t)(NN + 1) * 4);
    size_t o_msg  = alloc((size_t)NE * 32 * 4);     // MODE1 msgbuf
    size_t need1 = cur;
    size_t need0 = baseEnd + (size_t)NN * 32 * 4;

    int mode;                                       // 1: node-sorted, 0: atomic, -1: msgC
    if (ws_size >= need1) mode = 1;
    else if (ws_size >= need0) mode = 0;
    else mode = -1;

    float* h     = (float*)(ws + o_h);
    float* tS    = (float*)(ws + o_t);
    float* W2ext = (float*)(ws + o_w2e);
    unsigned short* W2bf = (unsigned short*)(ws + o_w2b);
    int* epermS  = (int*)(ws + o_epS);
    int* offsS   = (int*)(ws + o_ofS);
    int* posS    = (int*)(ws + o_posS);
    int* srcS    = (int*)(ws + o_srcS);
    int* idxS    = (int*)(ws + o_idxS);
    int* epermD  = (int*)(ws + o_epD);
    int* offsD   = (int*)(ws + o_ofD);
    int* epermD2 = (int*)(ws + o_epD2);
    int* nodeOffs = (int*)(ws + o_noff);
    float* outbuf = (mode == 1) ? (float*)(ws + o_msg)
                  : (mode == 0) ? (float*)(ws + baseEnd)
                                : (float*)(ws + afterCommon);
    // scratch (prologue only) unions into outbuf region
    int* blockCounts = (int*)outbuf;                      // HB*NTS = 3.2 MB
    int* blockStart  = blockCounts + (size_t)HB * NTS;    // 3.2 MB
    int* tileTot     = blockStart + (size_t)HB * NTS;     // 25 KB

    k_node_enc<<<NN / 8, 256, 0, stream>>>(nfeats, emb, encW, encB, projW, projB, h);

    if (mode >= 0) {
        k_w2prep<<<(66 * 512 + 255) / 256, 256, 0, stream>>>(enW2, enB2, W2bf);
        // src bucketing (16-node tiles)
        k_histT<NTS, 4><<<HB, 256, 0, stream>>>(src, blockCounts);
        k_colsumT<NTS><<<(NTS + 255) / 256, 256, 0, stream>>>(blockCounts, blockStart, tileTot);
        k_scanT<NTS, 25><<<1, 256, 0, stream>>>(tileTot, offsS);
        k_scatterT<NTS, 4><<<HB, 256, 0, stream>>>(src, blockStart, offsS, epermS);
        k_invperm<<<(NE + 255) / 256, 256, 0, stream>>>(epermS, posS);
        k_gatherKey<<<(NE + 255) / 256, 256, 0, stream>>>(epermS, src, srcS);
        if (mode == 1) {
            // dst bucketing (32-node tiles) -> per-node sort -> idxS via posS
            k_histT<NT_D, 5><<<HB, 256, 0, stream>>>(dst, blockCounts);
            k_colsumT<NT_D><<<(NT_D + 255) / 256, 256, 0, stream>>>(blockCounts, blockStart, tileTot);
            k_scanT<NT_D, 13><<<1, 256, 0, stream>>>(tileTot, offsD);
            k_scatterT<NT_D, 5><<<HB, 256, 0, stream>>>(dst, blockStart, offsD, epermD);
            k_sortNode<<<NT_D, 256, 0, stream>>>(epermD, dst, offsD, epermD2, nodeOffs);
            k_scatterIdx<<<(NE + 255) / 256, 256, 0, stream>>>(epermD2, posS, idxS);
        } else {
            k_gatherKey<<<(NE + 255) / 256, 256, 0, stream>>>(epermS, dst, idxS);
        }
        k_edge_t<<<NE / 8, 256, 0, stream>>>(efeats, eencW, eencB, enW1, enB1, posS, tS);
    } else {
        k_w2ext<<<(32 * QC + 255) / 256, 256, 0, stream>>>(enW2, enB2, W2ext);
        k_edge_t<<<NE / 8, 256, 0, stream>>>(efeats, eencW, eencB, enW1, enB1, nullptr, tS);
    }

    for (int s = 0; s < 3; ++s) {
        if (mode == 1) {
            k_msgF16<1><<<NTS, 256, 0, stream>>>(h, W2bf, tS, srcS, idxS, offsS, outbuf);
            k_gruAgg2<<<(NT_D + 3) / 4, 256, 0, stream>>>(outbuf, nodeOffs, convB,
                                                          gruWi, gruWh, gruBi, gruBh, h);
        } else if (mode == 0) {
            hipMemsetAsync(outbuf, 0, (size_t)NN * 32 * 4, stream);
            k_msgF16<0><<<NTS, 256, 0, stream>>>(h, W2bf, tS, srcS, idxS, offsS, outbuf);
            k_gru<<<NN / 32, 256, 0, stream>>>(outbuf, convB, gruWi, gruWh, gruBi, gruBh, h);
        } else {
            hipMemsetAsync(outbuf, 0, (size_t)NN * 32 * 4, stream);
            k_msgC<<<NE / 32, 256, 0, stream>>>(tS, src, dst, h, W2ext, outbuf);
            k_gru<<<NN / 32, 256, 0, stream>>>(outbuf, convB, gruWi, gruWh, gruBi, gruBh, h);
        }
    }
    k_dec<<<NN / 8, 256, 0, stream>>>(h, dW1, db1, da1, dW2, db2, da2, dW3, db3, da3, dW4, db4, out);
}

// Round 10
// 640.092 us; speedup vs baseline: 3.2873x; 1.0753x over previous
//
#include <hip/hip_runtime.h>
#include <hip/hip_bf16.h>

// MPNN on MI355X — fused 16-node-tile kernel, MFMA Q-phase, fully pre-sorted streams.
// msg[e,o] = sum_k t[e,k]*Q[src,k,o] + q0[src,o],  Q[n] = h[n] @ W2ext
// Prologue sorts edges by 16-node src tile; t materialized in src-sorted order (tS,
// gather-read + coalesced write); srcS/idxS give per-position src node and dst-node-
// sorted write slot. k_msgF16: per tile, MFMA Q (16x1056 bf16) into LDS, stream edges,
// write msg to node-sorted slot. k_gruAgg3: 1024-thread blocks = 4 dst-tiles sharing
// one weight stage (2 blocks/CU, ~100% occupancy), register segment-sum + GRU.

#define NN 100000
#define NE 320000
#define QC 1056
#define NTS 6250      // NN/16 src tiles
#define NT_D 3125     // NN/32 dst tiles
#define HB 128        // bucketing blocks
#define EPB (NE / HB) // 2500
#define QSTRH 1064    // sQ row stride (shorts)

typedef short bf16x8 __attribute__((ext_vector_type(8)));
typedef float f32x4  __attribute__((ext_vector_type(4)));

__device__ __forceinline__ float bf2f(unsigned short u) {
    return __uint_as_float(((unsigned int)u) << 16);
}
__device__ __forceinline__ unsigned short f2bf(float f) {
    unsigned int x = __float_as_uint(f);
    unsigned int r = (x + 0x7fffu + ((x >> 16) & 1u)) >> 16;
    return (unsigned short)r;
}

// ---- build W2ext [32][1056] (fp32, msgC fallback only)
__global__ __launch_bounds__(256) void k_w2ext(const float* __restrict__ W2,
                                               const float* __restrict__ b2,
                                               float* __restrict__ W2ext) {
    int idx = blockIdx.x * 256 + threadIdx.x;
    if (idx >= 32 * QC) return;
    int i = idx / QC, c = idx % QC;
    float v;
    if (c < 1024) { int k = c >> 5, o = c & 31; v = W2[k * 1024 + i * 32 + o]; }
    else          { v = b2[i * 32 + (c - 1024)]; }
    W2ext[idx] = v;
}

// ---- pack W2ext into bf16 B-fragment layout
// W2bf[(ct*64+l)*8+j] = B[kmap(l,j)][ct*16+(l&15)], kmap = (j>>2)*16+(l>>4)*4+(j&3)
__global__ __launch_bounds__(256) void k_w2prep(const float* __restrict__ W2,
                                                const float* __restrict__ b2,
                                                unsigned short* __restrict__ W2bf) {
    int idx = blockIdx.x * 256 + threadIdx.x;
    if (idx >= 66 * 512) return;
    int ct = idx >> 9, l = (idx >> 3) & 63, j = idx & 7;
    int kk = ((j >> 2) << 4) + ((l >> 4) << 2) + (j & 3);
    int c = ct * 16 + (l & 15);
    float v;
    if (c < 1024) { int kb = c >> 5, o = c & 31; v = W2[kb * 1024 + kk * 32 + o]; }
    else          { v = b2[kk * 32 + (c - 1024)]; }
    W2bf[idx] = f2bf(v);
}

// ---- node encoder + projection
__global__ __launch_bounds__(256) void k_node_enc(
    const int* __restrict__ nfeats, const float* __restrict__ emb,
    const float* __restrict__ encW, const float* __restrict__ encB,
    const float* __restrict__ projW, const float* __restrict__ projB,
    float* __restrict__ h) {
    __shared__ float sEncW[1024], sProjW[1024], sEncB[32], sProjB[32];
    __shared__ float sEmb[8][33], sNh[8][33];
    int tid = threadIdx.x;
    for (int i = tid; i < 1024; i += 256) { sEncW[i] = encW[i]; sProjW[i] = projW[i]; }
    if (tid < 32) { sEncB[tid] = encB[tid]; sProjB[tid] = projB[tid]; }
    int ln = tid >> 5, o = tid & 31;
    int node = blockIdx.x * 8 + ln;
    int nt = nfeats[node];
    sEmb[ln][o] = fmaxf(emb[nt * 32 + o], 0.f);
    __syncthreads();
    float acc = sEncB[o];
    #pragma unroll
    for (int i = 0; i < 32; ++i) acc += sEmb[ln][i] * sEncW[i * 32 + o];
    sNh[ln][o] = fmaxf(acc, 0.f);
    __syncthreads();
    float acc2 = sProjB[o];
    #pragma unroll
    for (int i = 0; i < 32; ++i) acc2 += sNh[ln][i] * sProjW[i * 32 + o];
    h[node * 32 + o] = fmaxf(acc2, 0.f);
}

// ---- edge encoder: 64 edges/block; gather efeats[eperm[p]], coalesced tS[p] write
__global__ __launch_bounds__(256) void k_edge_t2(
    const float* __restrict__ efeats,
    const float* __restrict__ eencW, const float* __restrict__ eencB,
    const float* __restrict__ enW1, const float* __restrict__ enB1,
    const int* __restrict__ eperm, float* __restrict__ tS) {
    __shared__ float sEW[512], sW1[1024], sEB[32], sB1[32];
    __shared__ float sEf[8][17], sEh[8][33];
    int tid = threadIdx.x;
    for (int i = tid; i < 512; i += 256) sEW[i] = eencW[i];
    for (int i = tid; i < 1024; i += 256) sW1[i] = enW1[i];
    if (tid < 32) { sEB[tid] = eencB[tid]; sB1[tid] = enB1[tid]; }
    int ln = tid >> 5, o = tid & 31;
    __syncthreads();
    // barrier ordering per iter: wr(sEf);B1;mm1;wr(sEh);B2;mm2;wr(tS).
    // sEf(next) write safe after B2 (all mm1 done); sEh(next) write safe after
    // B1(next) (all mm2 done by program order before B1(next)).
    for (int g = 0; g < 8; ++g) {
        int p = blockIdx.x * 64 + g * 8 + ln;
        int e = eperm ? eperm[p] : p;
        if (o < 16) sEf[ln][o] = efeats[(size_t)e * 16 + o];
        __syncthreads();
        float acc = sEB[o];
        #pragma unroll
        for (int i = 0; i < 16; ++i) acc += sEf[ln][i] * sEW[i * 32 + o];
        sEh[ln][o] = acc;
        __syncthreads();
        float acc2 = sB1[o];
        #pragma unroll
        for (int i = 0; i < 32; ++i) acc2 += sEh[ln][i] * sW1[i * 32 + o];
        tS[(size_t)p * 32 + o] = fmaxf(acc2, 0.f);
    }
}

// ---- generic counting-sort bucketing
template<int NT, int SHIFT>
__global__ __launch_bounds__(256) void k_histT(const int* __restrict__ keys,
                                               int* __restrict__ blockCounts) {
    __shared__ int sHist[NT];
    int tid = threadIdx.x, b = blockIdx.x;
    for (int c = tid; c < NT; c += 256) sHist[c] = 0;
    __syncthreads();
    int beg = b * EPB, end = min(beg + EPB, NE);
    for (int e = beg + tid; e < end; e += 256)
        atomicAdd(&sHist[keys[e] >> SHIFT], 1);
    __syncthreads();
    for (int c = tid; c < NT; c += 256) blockCounts[b * NT + c] = sHist[c];
}

template<int NT>
__global__ __launch_bounds__(256) void k_colsumT(const int* __restrict__ blockCounts,
                                                 int* __restrict__ blockStart,
                                                 int* __restrict__ tileTot) {
    int c = blockIdx.x * 256 + threadIdx.x;
    if (c >= NT) return;
    int running = 0;
    #pragma unroll 8
    for (int b = 0; b < HB; ++b) {
        blockStart[b * NT + c] = running;
        running += blockCounts[b * NT + c];
    }
    tileTot[c] = running;
}

template<int NT, int SEG>
__global__ __launch_bounds__(256) void k_scanT(const int* __restrict__ tileTot,
                                               int* __restrict__ offs) {
    __shared__ int sTot[NT];
    __shared__ int sPart[257];
    int tid = threadIdx.x;
    for (int c = tid; c < NT; c += 256) sTot[c] = tileTot[c];
    __syncthreads();
    int base = tid * SEG;
    int loc = 0;
    for (int j = 0; j < SEG; ++j) {
        int c = base + j;
        if (c < NT) { int v = sTot[c]; sTot[c] = loc; loc += v; }
    }
    sPart[tid] = loc;
    __syncthreads();
    if (tid == 0) {
        int s = 0;
        for (int i = 0; i < 256; ++i) { int v = sPart[i]; sPart[i] = s; s += v; }
        sPart[256] = s;
    }
    __syncthreads();
    int add = sPart[tid];
    for (int j = 0; j < SEG; ++j) {
        int c = base + j;
        if (c < NT) sTot[c] += add;
    }
    __syncthreads();
    for (int c = tid; c < NT; c += 256) offs[c] = sTot[c];
    if (tid == 0) offs[NT] = sPart[256];
}

template<int NT, int SHIFT>
__global__ __launch_bounds__(256) void k_scatterT(const int* __restrict__ keys,
                                                  const int* __restrict__ blockStart,
                                                  const int* __restrict__ offs,
                                                  int* __restrict__ eperm) {
    __shared__ int sCur[NT];
    int tid = threadIdx.x, b = blockIdx.x;
    for (int c = tid; c < NT; c += 256)
        sCur[c] = offs[c] + blockStart[b * NT + c];
    __syncthreads();
    int beg = b * EPB, end = min(beg + EPB, NE);
    for (int e = beg + tid; e < end; e += 256) {
        int pos = atomicAdd(&sCur[keys[e] >> SHIFT], 1);
        eperm[pos] = e;
    }
}

// ---- second-level sort: within each dst tile, sort by node (32 LDS bins)
__global__ __launch_bounds__(256) void k_sortNode(
    const int* __restrict__ epermD, const int* __restrict__ dst,
    const int* __restrict__ offsD, int* __restrict__ epermD2,
    int* __restrict__ nodeOffs) {
    __shared__ int sCnt[32], sStart[32];
    int tid = threadIdx.x, d = blockIdx.x;
    int beg = offsD[d], end = offsD[d + 1];
    if (tid < 32) sCnt[tid] = 0;
    __syncthreads();
    for (int p = beg + tid; p < end; p += 256)
        atomicAdd(&sCnt[dst[epermD[p]] & 31], 1);
    __syncthreads();
    if (tid == 0) {
        int s = beg;
        for (int r = 0; r < 32; ++r) { sStart[r] = s; s += sCnt[r]; }
    }
    __syncthreads();
    if (tid < 32) {
        nodeOffs[d * 32 + tid] = sStart[tid];
        sCnt[tid] = sStart[tid];       // reuse as cursor
    }
    if (d == NT_D - 1 && tid == 0) nodeOffs[NN] = end;
    __syncthreads();
    for (int p = beg + tid; p < end; p += 256) {
        int e = epermD[p];
        int pos = atomicAdd(&sCnt[dst[e] & 31], 1);
        epermD2[pos] = e;
    }
}

// ---- inverse permutation: pos[eperm[p]] = p
__global__ __launch_bounds__(256) void k_invperm(const int* __restrict__ eperm,
                                                 int* __restrict__ pos) {
    int p = blockIdx.x * 256 + threadIdx.x;
    if (p < NE) pos[eperm[p]] = p;
}

// ---- gather key into src-sorted positions: out[p] = key[epermS[p]]
__global__ __launch_bounds__(256) void k_gatherKey(const int* __restrict__ epermS,
                                                   const int* __restrict__ key,
                                                   int* __restrict__ out) {
    int p = blockIdx.x * 256 + threadIdx.x;
    if (p < NE) out[p] = key[epermS[p]];
}

// ---- idxS[posS[epermD2[q]]] = q  (src-sorted position -> dst-node-sorted slot)
__global__ __launch_bounds__(256) void k_scatterIdx(const int* __restrict__ epermD2,
                                                    const int* __restrict__ posS,
                                                    int* __restrict__ idxS) {
    int q = blockIdx.x * 256 + threadIdx.x;
    if (q < NE) idxS[posS[epermD2[q]]] = q;
}

// ---- fused per-16-node-src-tile: MFMA Q -> bf16 LDS, stream edges.
// MODE 0: atomicAdd into agg[idxS=dst]; MODE 1: store to msgbuf[idxS=slot].
template<int MODE>
__global__ __launch_bounds__(256) void k_msgF16(
    const float* __restrict__ h, const unsigned short* __restrict__ W2bf,
    const float* __restrict__ tS, const int* __restrict__ srcS,
    const int* __restrict__ idxS, const int* __restrict__ offs,
    float* __restrict__ outbuf) {
    __shared__ unsigned short sQ[16 * QSTRH];   // 34048 B
    __shared__ int sRow[32], sIdx[32];
    int tid = threadIdx.x;
    int tile = blockIdx.x;
    int beg = offs[tile], end = offs[tile + 1];
    if (beg >= end) return;
    int nodeBase = tile * 16;
    int wave = tid >> 6, lane = tid & 63;

    // A-fragment: all 16 rows used
    int arow = lane & 15;
    const float* hp = h + (size_t)(nodeBase + arow) * 32 + ((lane >> 4) << 2);
    float4 x0 = *(const float4*)hp;
    float4 x1 = *(const float4*)(hp + 16);
    bf16x8 a;
    a[0] = (short)f2bf(x0.x); a[1] = (short)f2bf(x0.y);
    a[2] = (short)f2bf(x0.z); a[3] = (short)f2bf(x0.w);
    a[4] = (short)f2bf(x1.x); a[5] = (short)f2bf(x1.y);
    a[6] = (short)f2bf(x1.z); a[7] = (short)f2bf(x1.w);

    f32x4 z = {0.f, 0.f, 0.f, 0.f};
    int crow0 = (lane >> 4) << 2;
    int ccol = lane & 15;
    for (int ct = wave; ct < 66; ct += 4) {
        bf16x8 b = *(const bf16x8*)(W2bf + (size_t)((ct << 6) + lane) * 8);
        f32x4 acc = __builtin_amdgcn_mfma_f32_16x16x32_bf16(a, b, z, 0, 0, 0);
        unsigned short* qp = sQ + crow0 * QSTRH + (ct << 4) + ccol;
        qp[0 * QSTRH] = f2bf(acc[0]); qp[1 * QSTRH] = f2bf(acc[1]);
        qp[2 * QSTRH] = f2bf(acc[2]); qp[3 * QSTRH] = f2bf(acc[3]);
    }
    __syncthreads();

    int el = tid >> 3, l8 = tid & 7;
    int gbase = lane & 56;                // first lane of this 8-lane group
    for (int s0 = beg; s0 < end; s0 += 32) {
        int nact = min(32, end - s0);
        if (tid < nact) {
            sRow[tid] = srcS[s0 + tid] - nodeBase;
            sIdx[tid] = idxS[s0 + tid];
        }
        __syncthreads();
        if (el < nact) {
            float4 tv = *(const float4*)(tS + (size_t)(s0 + el) * 32 + (l8 << 2));
            const unsigned short* qp = sQ + sRow[el] * QSTRH + (l8 << 2);
            ushort4 qb = *(const ushort4*)(qp + 1024);
            float a0 = bf2f(qb.x), a1 = bf2f(qb.y), a2 = bf2f(qb.z), a3 = bf2f(qb.w);
            #pragma unroll
            for (int kk = 0; kk < 8; ++kk) {
                float t0 = __shfl(tv.x, gbase + kk, 64);
                float t1 = __shfl(tv.y, gbase + kk, 64);
                float t2 = __shfl(tv.z, gbase + kk, 64);
                float t3 = __shfl(tv.w, gbase + kk, 64);
                ushort4 q0 = *(const ushort4*)(qp + ((kk << 2) + 0) * 32);
                ushort4 q1 = *(const ushort4*)(qp + ((kk << 2) + 1) * 32);
                ushort4 q2 = *(const ushort4*)(qp + ((kk << 2) + 2) * 32);
                ushort4 q3 = *(const ushort4*)(qp + ((kk << 2) + 3) * 32);
                a0 += t0 * bf2f(q0.x); a1 += t0 * bf2f(q0.y);
                a2 += t0 * bf2f(q0.z); a3 += t0 * bf2f(q0.w);
                a0 += t1 * bf2f(q1.x); a1 += t1 * bf2f(q1.y);
                a2 += t1 * bf2f(q1.z); a3 += t1 * bf2f(q1.w);
                a0 += t2 * bf2f(q2.x); a1 += t2 * bf2f(q2.y);
                a2 += t2 * bf2f(q2.z); a3 += t2 * bf2f(q2.w);
                a0 += t3 * bf2f(q3.x); a1 += t3 * bf2f(q3.y);
                a2 += t3 * bf2f(q3.z); a3 += t3 * bf2f(q3.w);
            }
            if (MODE) {
                *(float4*)(outbuf + (size_t)sIdx[el] * 32 + (l8 << 2)) =
                    make_float4(a0, a1, a2, a3);
            } else {
                float* ap = outbuf + (size_t)sIdx[el] * 32 + (l8 << 2);
                atomicAdd(ap + 0, a0); atomicAdd(ap + 1, a1);
                atomicAdd(ap + 2, a2); atomicAdd(ap + 3, a3);
            }
        }
        __syncthreads();
    }
}

// ---- fallback msg (tiny ws): recompute We per edge (t in original order)
__global__ __launch_bounds__(256) void k_msgC(
    const float* __restrict__ t, const int* __restrict__ src, const int* __restrict__ dst,
    const float* __restrict__ h, const float* __restrict__ W2ext, float* __restrict__ agg) {
    __shared__ float sT[32][33], sH[32][33];
    __shared__ int sSrc[32], sDst[32];
    int tid = threadIdx.x;
    int e0 = blockIdx.x * 32;
    if (tid < 32) sSrc[tid] = src[e0 + tid];
    else if (tid < 64) sDst[tid - 32] = dst[e0 + tid - 32];
    __syncthreads();
    for (int idx = tid; idx < 1024; idx += 256) {
        int el = idx >> 5, k = idx & 31;
        sT[el][k] = t[(e0 + el) * 32 + k];
        sH[el][k] = h[(size_t)sSrc[el] * 32 + k];
    }
    __syncthreads();
    int el = tid >> 3, l8 = tid & 7;
    int c0 = l8 * 4;
    float m0 = 0.f, m1 = 0.f, m2 = 0.f, m3 = 0.f;
    for (int i = 0; i < 32; ++i) {
        const float* wrow = W2ext + i * QC;
        float4 wb = *(const float4*)(wrow + 1024 + c0);
        float w0 = wb.x, w1 = wb.y, w2 = wb.z, w3 = wb.w;
        #pragma unroll 8
        for (int k = 0; k < 32; ++k) {
            float tk = sT[el][k];
            float4 w = *(const float4*)(wrow + k * 32 + c0);
            w0 += tk * w.x; w1 += tk * w.y; w2 += tk * w.z; w3 += tk * w.w;
        }
        float hi = sH[el][i];
        m0 += hi * w0; m1 += hi * w1; m2 += hi * w2; m3 += hi * w3;
    }
    float* ap = agg + (size_t)sDst[el] * 32 + c0;
    atomicAdd(ap + 0, m0); atomicAdd(ap + 1, m1);
    atomicAdd(ap + 2, m2); atomicAdd(ap + 3, m3);
}

// ---- GRU step reading agg[] (MODE 0 / fallback)
__global__ __launch_bounds__(256) void k_gru(
    const float* __restrict__ agg, const float* __restrict__ convB,
    const float* __restrict__ Wi, const float* __restrict__ Wh,
    const float* __restrict__ bi, const float* __restrict__ bh,
    float* __restrict__ h) {
    __shared__ float sWi[3072], sWh[3072], sBi[96], sBh[96], sCb[32];
    __shared__ float sX[8][33], sH[8][33];
    int tid = threadIdx.x;
    for (int i = tid; i < 3072; i += 256) { sWi[i] = Wi[i]; sWh[i] = Wh[i]; }
    if (tid < 96) { sBi[tid] = bi[tid]; sBh[tid] = bh[tid]; }
    if (tid < 32) sCb[tid] = convB[tid];
    int ln = tid >> 5, o = tid & 31;
    for (int g = 0; g < 4; ++g) {
        int node = blockIdx.x * 32 + g * 8 + ln;
        float hv = h[node * 32 + o];
        float av = agg[node * 32 + o];
        __syncthreads();
        sX[ln][o] = fmaxf(av + sCb[o], 0.f);
        sH[ln][o] = hv;
        __syncthreads();
        float air = sBi[o], aiz = sBi[o + 32], ain = sBi[o + 64];
        float ahr = sBh[o], ahz = sBh[o + 32], ahn = sBh[o + 64];
        #pragma unroll 8
        for (int i = 0; i < 32; ++i) {
            float x = sX[ln][i], hh = sH[ln][i];
            air += x * sWi[i * 96 + o];      ahr += hh * sWh[i * 96 + o];
            aiz += x * sWi[i * 96 + o + 32]; ahz += hh * sWh[i * 96 + o + 32];
            ain += x * sWi[i * 96 + o + 64]; ahn += hh * sWh[i * 96 + o + 64];
        }
        float r = 1.f / (1.f + __expf(-(air + ahr)));
        float zz = 1.f / (1.f + __expf(-(aiz + ahz)));
        float ng = tanhf(ain + r * ahn);
        h[node * 32 + o] = (1.f - zz) * ng + zz * hv;
    }
}

// ---- MODE 1: 1024-thread block = 4 dst tiles sharing one weight stage.
// Register segment-sum per node (raw + relu(conv_b) applied with global convB),
// one barrier, then GRU. ~59 KB LDS -> 2 blocks/CU, 32 waves/CU.
__global__ __launch_bounds__(1024) void k_gruAgg3(
    const float* __restrict__ msgbuf, const int* __restrict__ nodeOffs,
    const float* __restrict__ convB,
    const float* __restrict__ Wi, const float* __restrict__ Wh,
    const float* __restrict__ bi, const float* __restrict__ bh,
    float* __restrict__ h) {
    __shared__ float sWi[3072], sWh[3072], sBi[96], sBh[96];
    __shared__ float sAgg[4][32 * 33];
    __shared__ float sH[4][32 * 33];
    int tid = threadIdx.x;
    for (int i = tid; i < 3072; i += 1024) { sWi[i] = Wi[i]; sWh[i] = Wh[i]; }
    if (tid < 96) { sBi[tid] = bi[tid]; sBh[tid] = bh[tid]; }
    int sub = tid >> 8, stid = tid & 255;
    int d = blockIdx.x * 4 + sub;
    bool act = d < NT_D;
    int n8 = stid >> 3, l8 = stid & 7;
    if (act) {
        int node = d * 32 + n8;
        int nb = nodeOffs[node], ne2 = nodeOffs[node + 1];
        float a0 = 0.f, a1 = 0.f, a2 = 0.f, a3 = 0.f;
        for (int p = nb; p < ne2; ++p) {
            float4 v = *(const float4*)(msgbuf + (size_t)p * 32 + (l8 << 2));
            a0 += v.x; a1 += v.y; a2 += v.z; a3 += v.w;
        }
        int c0 = l8 << 2;
        float4 cb = *(const float4*)(convB + c0);   // global, L2-cached
        float* sp = sAgg[sub] + n8 * 33 + c0;
        sp[0] = fmaxf(a0 + cb.x, 0.f);
        sp[1] = fmaxf(a1 + cb.y, 0.f);
        sp[2] = fmaxf(a2 + cb.z, 0.f);
        sp[3] = fmaxf(a3 + cb.w, 0.f);
        for (int idx = stid; idx < 1024; idx += 256)
            sH[sub][(idx >> 5) * 33 + (idx & 31)] = h[(size_t)d * 1024 + idx];
    }
    __syncthreads();
    if (act) {
        int ln = stid >> 5, o = stid & 31;
        #pragma unroll
        for (int g = 0; g < 4; ++g) {
            int r = g * 8 + ln;
            const float* xp = sAgg[sub] + r * 33;
            const float* hpp = sH[sub] + r * 33;
            float air = sBi[o], aiz = sBi[o + 32], ain = sBi[o + 64];
            float ahr = sBh[o], ahz = sBh[o + 32], ahn = sBh[o + 64];
            #pragma unroll 8
            for (int i = 0; i < 32; ++i) {
                float x = xp[i], hh = hpp[i];
                air += x * sWi[i * 96 + o];      ahr += hh * sWh[i * 96 + o];
                aiz += x * sWi[i * 96 + o + 32]; ahz += hh * sWh[i * 96 + o + 32];
                ain += x * sWi[i * 96 + o + 64]; ahn += hh * sWh[i * 96 + o + 64];
            }
            float rr = 1.f / (1.f + __expf(-(air + ahr)));
            float zz = 1.f / (1.f + __expf(-(aiz + ahz)));
            float ng = tanhf(ain + rr * ahn);
            h[(size_t)(d * 32 + r) * 32 + o] = (1.f - zz) * ng + zz * hpp[o];
        }
    }
}

// ---- decoder
__global__ __launch_bounds__(256) void k_dec(
    const float* __restrict__ h,
    const float* __restrict__ W1, const float* __restrict__ b1, const float* __restrict__ a1,
    const float* __restrict__ W2, const float* __restrict__ b2, const float* __restrict__ a2,
    const float* __restrict__ W3, const float* __restrict__ b3, const float* __restrict__ a3,
    const float* __restrict__ W4, const float* __restrict__ b4,
    float* __restrict__ out) {
    __shared__ float sW1[1024], sW2[1024], sW3[1024], sW4[96];
    __shared__ float sB1[32], sB2[32], sB3[32], sB4[3];
    __shared__ float sYa[8][33], sYb[8][33];
    int tid = threadIdx.x;
    for (int i = tid; i < 1024; i += 256) { sW1[i] = W1[i]; sW2[i] = W2[i]; sW3[i] = W3[i]; }
    if (tid < 96) sW4[tid] = W4[tid];
    if (tid < 32) { sB1[tid] = b1[tid]; sB2[tid] = b2[tid]; sB3[tid] = b3[tid]; }
    if (tid < 3) sB4[tid] = b4[tid];
    float A1 = a1[0], A2 = a2[0], A3 = a3[0];
    int ln = tid >> 5, o = tid & 31;
    int node = blockIdx.x * 8 + ln;
    sYa[ln][o] = h[node * 32 + o];
    __syncthreads();
    float acc = sB1[o];
    #pragma unroll
    for (int i = 0; i < 32; ++i) acc += sYa[ln][i] * sW1[i * 32 + o];
    acc = acc >= 0.f ? acc : A1 * acc;
    sYb[ln][o] = acc;
    __syncthreads();
    acc = sB2[o];
    #pragma unroll
    for (int i = 0; i < 32; ++i) acc += sYb[ln][i] * sW2[i * 32 + o];
    acc = acc >= 0.f ? acc : A2 * acc;
    __syncthreads();
    sYa[ln][o] = acc;
    __syncthreads();
    acc = sB3[o];
    #pragma unroll
    for (int i = 0; i < 32; ++i) acc += sYa[ln][i] * sW3[i * 32 + o];
    acc = acc >= 0.f ? acc : A3 * acc;
    __syncthreads();
    sYb[ln][o] = acc;
    __syncthreads();
    if (o < 3) {
        float r = sB4[o];
        #pragma unroll
        for (int i = 0; i < 32; ++i) r += sYb[ln][i] * sW4[i * 3 + o];
        out[node * 3 + o] = r;
    }
}

extern "C" void kernel_launch(void* const* d_in, const int* in_sizes, int n_in,
                              void* d_out, int out_size, void* d_ws, size_t ws_size,
                              hipStream_t stream) {
    const int*   nfeats = (const int*)d_in[0];
    const float* efeats = (const float*)d_in[1];
    const int*   src    = (const int*)d_in[2];
    const int*   dst    = (const int*)d_in[3];
    const float* emb    = (const float*)d_in[4];
    const float* encW   = (const float*)d_in[5];
    const float* encB   = (const float*)d_in[6];
    const float* eencW  = (const float*)d_in[7];
    const float* eencB  = (const float*)d_in[8];
    const float* projW  = (const float*)d_in[9];
    const float* projB  = (const float*)d_in[10];
    const float* enW1   = (const float*)d_in[11];
    const float* enB1   = (const float*)d_in[12];
    const float* enW2   = (const float*)d_in[13];
    const float* enB2   = (const float*)d_in[14];
    const float* convB  = (const float*)d_in[15];
    const float* gruWi  = (const float*)d_in[16];
    const float* gruWh  = (const float*)d_in[17];
    const float* gruBi  = (const float*)d_in[18];
    const float* gruBh  = (const float*)d_in[19];
    const float* dW1 = (const float*)d_in[20]; const float* db1 = (const float*)d_in[21]; const float* da1 = (const float*)d_in[22];
    const float* dW2 = (const float*)d_in[23]; const float* db2 = (const float*)d_in[24]; const float* da2 = (const float*)d_in[25];
    const float* dW3 = (const float*)d_in[26]; const float* db3 = (const float*)d_in[27]; const float* da3 = (const float*)d_in[28];
    const float* dW4 = (const float*)d_in[29]; const float* db4 = (const float*)d_in[30];
    float* out = (float*)d_out;
    char* ws = (char*)d_ws;

    // bump allocator (256-B aligned)
    size_t cur = 0;
    auto alloc = [&](size_t n) { size_t p = cur; cur = (cur + n + 255) & ~(size_t)255; return p; };
    size_t o_h   = alloc((size_t)NN * 32 * 4);
    size_t o_t   = alloc((size_t)NE * 32 * 4);      // tS (or t in fallback)
    size_t o_w2e = alloc((size_t)32 * QC * 4);
    size_t afterCommon = cur;                       // fallback agg goes here
    size_t o_w2b = alloc((size_t)66 * 512 * 2);
    size_t o_epS = alloc((size_t)NE * 4);
    size_t o_ofS = alloc((size_t)(NTS + 1) * 4);
    size_t o_posS = alloc((size_t)NE * 4);
    size_t o_srcS = alloc((size_t)NE * 4);
    size_t o_idxS = alloc((size_t)NE * 4);
    size_t baseEnd = cur;                           // MODE0 agg goes here
    size_t o_epD  = alloc((size_t)NE * 4);
    size_t o_ofD  = alloc((size_t)(NT_D + 1) * 4);
    size_t o_epD2 = alloc((size_t)NE * 4);
    size_t o_noff = alloc((size_t)(NN + 1) * 4);
    size_t o_msg  = alloc((size_t)NE * 32 * 4);     // MODE1 msgbuf
    size_t need1 = cur;
    size_t need0 = baseEnd + (size_t)NN * 32 * 4;

    int mode;                                       // 1: node-sorted, 0: atomic, -1: msgC
    if (ws_size >= need1) mode = 1;
    else if (ws_size >= need0) mode = 0;
    else mode = -1;

    float* h     = (float*)(ws + o_h);
    float* tS    = (float*)(ws + o_t);
    float* W2ext = (float*)(ws + o_w2e);
    unsigned short* W2bf = (unsigned short*)(ws + o_w2b);
    int* epermS  = (int*)(ws + o_epS);
    int* offsS   = (int*)(ws + o_ofS);
    int* posS    = (int*)(ws + o_posS);
    int* srcS    = (int*)(ws + o_srcS);
    int* idxS    = (int*)(ws + o_idxS);
    int* epermD  = (int*)(ws + o_epD);
    int* offsD   = (int*)(ws + o_ofD);
    int* epermD2 = (int*)(ws + o_epD2);
    int* nodeOffs = (int*)(ws + o_noff);
    float* outbuf = (mode == 1) ? (float*)(ws + o_msg)
                  : (mode == 0) ? (float*)(ws + baseEnd)
                                : (float*)(ws + afterCommon);
    // scratch (prologue only) unions into outbuf region
    int* blockCounts = (int*)outbuf;                      // HB*NTS = 3.2 MB
    int* blockStart  = blockCounts + (size_t)HB * NTS;    // 3.2 MB
    int* tileTot     = blockStart + (size_t)HB * NTS;     // 25 KB

    k_node_enc<<<NN / 8, 256, 0, stream>>>(nfeats, emb, encW, encB, projW, projB, h);

    if (mode >= 0) {
        k_w2prep<<<(66 * 512 + 255) / 256, 256, 0, stream>>>(enW2, enB2, W2bf);
        // src bucketing (16-node tiles)
        k_histT<NTS, 4><<<HB, 256, 0, stream>>>(src, blockCounts);
        k_colsumT<NTS><<<(NTS + 255) / 256, 256, 0, stream>>>(blockCounts, blockStart, tileTot);
        k_scanT<NTS, 25><<<1, 256, 0, stream>>>(tileTot, offsS);
        k_scatterT<NTS, 4><<<HB, 256, 0, stream>>>(src, blockStart, offsS, epermS);
        k_invperm<<<(NE + 255) / 256, 256, 0, stream>>>(epermS, posS);
        k_gatherKey<<<(NE + 255) / 256, 256, 0, stream>>>(epermS, src, srcS);
        if (mode == 1) {
            // dst bucketing (32-node tiles) -> per-node sort -> idxS via posS
            k_histT<NT_D, 5><<<HB, 256, 0, stream>>>(dst, blockCounts);
            k_colsumT<NT_D><<<(NT_D + 255) / 256, 256, 0, stream>>>(blockCounts, blockStart, tileTot);
            k_scanT<NT_D, 13><<<1, 256, 0, stream>>>(tileTot, offsD);
            k_scatterT<NT_D, 5><<<HB, 256, 0, stream>>>(dst, blockStart, offsD, epermD);
            k_sortNode<<<NT_D, 256, 0, stream>>>(epermD, dst, offsD, epermD2, nodeOffs);
            k_scatterIdx<<<(NE + 255) / 256, 256, 0, stream>>>(epermD2, posS, idxS);
        } else {
            k_gatherKey<<<(NE + 255) / 256, 256, 0, stream>>>(epermS, dst, idxS);
        }
        k_edge_t2<<<NE / 64, 256, 0, stream>>>(efeats, eencW, eencB, enW1, enB1, epermS, tS);
    } else {
        k_w2ext<<<(32 * QC + 255) / 256, 256, 0, stream>>>(enW2, enB2, W2ext);
        k_edge_t2<<<NE / 64, 256, 0, stream>>>(efeats, eencW, eencB, enW1, enB1, nullptr, tS);
    }

    for (int s = 0; s < 3; ++s) {
        if (mode == 1) {
            k_msgF16<1><<<NTS, 256, 0, stream>>>(h, W2bf, tS, srcS, idxS, offsS, outbuf);
            k_gruAgg3<<<(NT_D + 3) / 4, 1024, 0, stream>>>(outbuf, nodeOffs, convB,
                                                           gruWi, gruWh, gruBi, gruBh, h);
        } else if (mode == 0) {
            hipMemsetAsync(outbuf, 0, (size_t)NN * 32 * 4, stream);
            k_msgF16<0><<<NTS, 256, 0, stream>>>(h, W2bf, tS, srcS, idxS, offsS, outbuf);
            k_gru<<<NN / 32, 256, 0, stream>>>(outbuf, convB, gruWi, gruWh, gruBi, gruBh, h);
        } else {
            hipMemsetAsync(outbuf, 0, (size_t)NN * 32 * 4, stream);
            k_msgC<<<NE / 32, 256, 0, stream>>>(tS, src, dst, h, W2ext, outbuf);
            k_gru<<<NN / 32, 256, 0, stream>>>(outbuf, convB, gruWi, gruWh, gruBi, gruBh, h);
        }
    }
    k_dec<<<NN / 8, 256, 0, stream>>>(h, dW1, db1, da1, dW2, db2, da2, dW3, db3, da3, dW4, db4, out);
}

// Round 11
// 503.035 us; speedup vs baseline: 4.1830x; 1.2725x over previous
//
#include <hip/hip_runtime.h>
#include <hip/hip_bf16.h>

// MPNN on MI355X — fused 16-node-tile msg kernel + MFMA GRU, fully pre-sorted streams.
// msg[e,o] = sum_k t[e,k]*Q[src,k,o] + q0[src,o],  Q[n] = h[n] @ W2ext
// k_msgF16: per 16-node src tile, MFMA Q (16x1056 bf16) into LDS, stream edges,
// write msg to dst-node-sorted slot. k_gruAgg4: per 32-node dst tile, register
// segment-sum -> X in LDS, then GRU gates via 18 split-bf16 MFMAs per wave
// ([X|H](32x64) @ [[Wi],[Wh]](64x96)); no weight staging, no global atomics.

#define NN 100000
#define NE 320000
#define QC 1056
#define NTS 6250      // NN/16 src tiles
#define NT_D 3125     // NN/32 dst tiles
#define HB 128        // bucketing blocks
#define EPB (NE / HB) // 2500
#define QSTRH 1064    // sQ row stride (shorts)

typedef short bf16x8 __attribute__((ext_vector_type(8)));
typedef float f32x4  __attribute__((ext_vector_type(4)));

__device__ __forceinline__ float bf2f(unsigned short u) {
    return __uint_as_float(((unsigned int)u) << 16);
}
__device__ __forceinline__ unsigned short f2bf(float f) {
    unsigned int x = __float_as_uint(f);
    unsigned int r = (x + 0x7fffu + ((x >> 16) & 1u)) >> 16;
    return (unsigned short)r;
}
__device__ __forceinline__ float sigm(float x) {
    return 1.f / (1.f + __expf(-x));
}

// ---- build W2ext [32][1056] (fp32, msgC fallback only)
__global__ __launch_bounds__(256) void k_w2ext(const float* __restrict__ W2,
                                               const float* __restrict__ b2,
                                               float* __restrict__ W2ext) {
    int idx = blockIdx.x * 256 + threadIdx.x;
    if (idx >= 32 * QC) return;
    int i = idx / QC, c = idx % QC;
    float v;
    if (c < 1024) { int k = c >> 5, o = c & 31; v = W2[k * 1024 + i * 32 + o]; }
    else          { v = b2[i * 32 + (c - 1024)]; }
    W2ext[idx] = v;
}

// ---- pack W2ext into bf16 B-fragment layout
// W2bf[(ct*64+l)*8+j] = B[kmap(l,j)][ct*16+(l&15)], kmap = (j>>2)*16+(l>>4)*4+(j&3)
__global__ __launch_bounds__(256) void k_w2prep(const float* __restrict__ W2,
                                                const float* __restrict__ b2,
                                                unsigned short* __restrict__ W2bf) {
    int idx = blockIdx.x * 256 + threadIdx.x;
    if (idx >= 66 * 512) return;
    int ct = idx >> 9, l = (idx >> 3) & 63, j = idx & 7;
    int kk = ((j >> 2) << 4) + ((l >> 4) << 2) + (j & 3);
    int c = ct * 16 + (l & 15);
    float v;
    if (c < 1024) { int kb = c >> 5, o = c & 31; v = W2[kb * 1024 + kk * 32 + o]; }
    else          { v = b2[kk * 32 + (c - 1024)]; }
    W2bf[idx] = f2bf(v);
}

// ---- pack combined GRU weights [[Wi],[Wh]] (64x96) into B-frag bf16 hi/lo
// idx = ((nt*2+kt)*64 + l)*8 + j ; k = kmap(l,j); col = nt*16+(l&15)
__global__ __launch_bounds__(256) void k_wgru(const float* __restrict__ Wi,
                                              const float* __restrict__ Wh,
                                              unsigned short* __restrict__ Whi,
                                              unsigned short* __restrict__ Wlo) {
    int idx = blockIdx.x * 256 + threadIdx.x;
    if (idx >= 6144) return;
    int j = idx & 7, l = (idx >> 3) & 63, kt = (idx >> 9) & 1, nt = idx >> 10;
    int k = ((j >> 2) << 4) + ((l >> 4) << 2) + (j & 3);
    int col = nt * 16 + (l & 15);
    float v = kt ? Wh[k * 96 + col] : Wi[k * 96 + col];
    unsigned short hi = f2bf(v);
    Whi[idx] = hi;
    Wlo[idx] = f2bf(v - bf2f(hi));
}

// ---- node encoder + projection
__global__ __launch_bounds__(256) void k_node_enc(
    const int* __restrict__ nfeats, const float* __restrict__ emb,
    const float* __restrict__ encW, const float* __restrict__ encB,
    const float* __restrict__ projW, const float* __restrict__ projB,
    float* __restrict__ h) {
    __shared__ float sEncW[1024], sProjW[1024], sEncB[32], sProjB[32];
    __shared__ float sEmb[8][33], sNh[8][33];
    int tid = threadIdx.x;
    for (int i = tid; i < 1024; i += 256) { sEncW[i] = encW[i]; sProjW[i] = projW[i]; }
    if (tid < 32) { sEncB[tid] = encB[tid]; sProjB[tid] = projB[tid]; }
    int ln = tid >> 5, o = tid & 31;
    int node = blockIdx.x * 8 + ln;
    int nt = nfeats[node];
    sEmb[ln][o] = fmaxf(emb[nt * 32 + o], 0.f);
    __syncthreads();
    float acc = sEncB[o];
    #pragma unroll
    for (int i = 0; i < 32; ++i) acc += sEmb[ln][i] * sEncW[i * 32 + o];
    sNh[ln][o] = fmaxf(acc, 0.f);
    __syncthreads();
    float acc2 = sProjB[o];
    #pragma unroll
    for (int i = 0; i < 32; ++i) acc2 += sNh[ln][i] * sProjW[i * 32 + o];
    h[node * 32 + o] = fmaxf(acc2, 0.f);
}

// ---- edge encoder: 64 edges/block; gather efeats[eperm[p]], coalesced tS[p] write
__global__ __launch_bounds__(256) void k_edge_t2(
    const float* __restrict__ efeats,
    const float* __restrict__ eencW, const float* __restrict__ eencB,
    const float* __restrict__ enW1, const float* __restrict__ enB1,
    const int* __restrict__ eperm, float* __restrict__ tS) {
    __shared__ float sEW[512], sW1[1024], sEB[32], sB1[32];
    __shared__ float sEf[8][17], sEh[8][33];
    int tid = threadIdx.x;
    for (int i = tid; i < 512; i += 256) sEW[i] = eencW[i];
    for (int i = tid; i < 1024; i += 256) sW1[i] = enW1[i];
    if (tid < 32) { sEB[tid] = eencB[tid]; sB1[tid] = enB1[tid]; }
    int ln = tid >> 5, o = tid & 31;
    __syncthreads();
    for (int g = 0; g < 8; ++g) {
        int p = blockIdx.x * 64 + g * 8 + ln;
        int e = eperm ? eperm[p] : p;
        if (o < 16) sEf[ln][o] = efeats[(size_t)e * 16 + o];
        __syncthreads();
        float acc = sEB[o];
        #pragma unroll
        for (int i = 0; i < 16; ++i) acc += sEf[ln][i] * sEW[i * 32 + o];
        sEh[ln][o] = acc;
        __syncthreads();
        float acc2 = sB1[o];
        #pragma unroll
        for (int i = 0; i < 32; ++i) acc2 += sEh[ln][i] * sW1[i * 32 + o];
        tS[(size_t)p * 32 + o] = fmaxf(acc2, 0.f);
    }
}

// ---- generic counting-sort bucketing
template<int NT, int SHIFT>
__global__ __launch_bounds__(256) void k_histT(const int* __restrict__ keys,
                                               int* __restrict__ blockCounts) {
    __shared__ int sHist[NT];
    int tid = threadIdx.x, b = blockIdx.x;
    for (int c = tid; c < NT; c += 256) sHist[c] = 0;
    __syncthreads();
    int beg = b * EPB, end = min(beg + EPB, NE);
    for (int e = beg + tid; e < end; e += 256)
        atomicAdd(&sHist[keys[e] >> SHIFT], 1);
    __syncthreads();
    for (int c = tid; c < NT; c += 256) blockCounts[b * NT + c] = sHist[c];
}

template<int NT>
__global__ __launch_bounds__(256) void k_colsumT(const int* __restrict__ blockCounts,
                                                 int* __restrict__ blockStart,
                                                 int* __restrict__ tileTot) {
    int c = blockIdx.x * 256 + threadIdx.x;
    if (c >= NT) return;
    int running = 0;
    #pragma unroll 8
    for (int b = 0; b < HB; ++b) {
        blockStart[b * NT + c] = running;
        running += blockCounts[b * NT + c];
    }
    tileTot[c] = running;
}

template<int NT, int SEG>
__global__ __launch_bounds__(256) void k_scanT(const int* __restrict__ tileTot,
                                               int* __restrict__ offs) {
    __shared__ int sTot[NT];
    __shared__ int sPart[257];
    int tid = threadIdx.x;
    for (int c = tid; c < NT; c += 256) sTot[c] = tileTot[c];
    __syncthreads();
    int base = tid * SEG;
    int loc = 0;
    for (int j = 0; j < SEG; ++j) {
        int c = base + j;
        if (c < NT) { int v = sTot[c]; sTot[c] = loc; loc += v; }
    }
    sPart[tid] = loc;
    __syncthreads();
    if (tid == 0) {
        int s = 0;
        for (int i = 0; i < 256; ++i) { int v = sPart[i]; sPart[i] = s; s += v; }
        sPart[256] = s;
    }
    __syncthreads();
    int add = sPart[tid];
    for (int j = 0; j < SEG; ++j) {
        int c = base + j;
        if (c < NT) sTot[c] += add;
    }
    __syncthreads();
    for (int c = tid; c < NT; c += 256) offs[c] = sTot[c];
    if (tid == 0) offs[NT] = sPart[256];
}

template<int NT, int SHIFT>
__global__ __launch_bounds__(256) void k_scatterT(const int* __restrict__ keys,
                                                  const int* __restrict__ blockStart,
                                                  const int* __restrict__ offs,
                                                  int* __restrict__ eperm) {
    __shared__ int sCur[NT];
    int tid = threadIdx.x, b = blockIdx.x;
    for (int c = tid; c < NT; c += 256)
        sCur[c] = offs[c] + blockStart[b * NT + c];
    __syncthreads();
    int beg = b * EPB, end = min(beg + EPB, NE);
    for (int e = beg + tid; e < end; e += 256) {
        int pos = atomicAdd(&sCur[keys[e] >> SHIFT], 1);
        eperm[pos] = e;
    }
}

// ---- second-level sort: within each dst tile, sort by node (32 LDS bins)
__global__ __launch_bounds__(256) void k_sortNode(
    const int* __restrict__ epermD, const int* __restrict__ dst,
    const int* __restrict__ offsD, int* __restrict__ epermD2,
    int* __restrict__ nodeOffs) {
    __shared__ int sCnt[32], sStart[32];
    int tid = threadIdx.x, d = blockIdx.x;
    int beg = offsD[d], end = offsD[d + 1];
    if (tid < 32) sCnt[tid] = 0;
    __syncthreads();
    for (int p = beg + tid; p < end; p += 256)
        atomicAdd(&sCnt[dst[epermD[p]] & 31], 1);
    __syncthreads();
    if (tid == 0) {
        int s = beg;
        for (int r = 0; r < 32; ++r) { sStart[r] = s; s += sCnt[r]; }
    }
    __syncthreads();
    if (tid < 32) {
        nodeOffs[d * 32 + tid] = sStart[tid];
        sCnt[tid] = sStart[tid];       // reuse as cursor
    }
    if (d == NT_D - 1 && tid == 0) nodeOffs[NN] = end;
    __syncthreads();
    for (int p = beg + tid; p < end; p += 256) {
        int e = epermD[p];
        int pos = atomicAdd(&sCnt[dst[e] & 31], 1);
        epermD2[pos] = e;
    }
}

// ---- inverse permutation: pos[eperm[p]] = p
__global__ __launch_bounds__(256) void k_invperm(const int* __restrict__ eperm,
                                                 int* __restrict__ pos) {
    int p = blockIdx.x * 256 + threadIdx.x;
    if (p < NE) pos[eperm[p]] = p;
}

// ---- gather key into src-sorted positions: out[p] = key[epermS[p]]
__global__ __launch_bounds__(256) void k_gatherKey(const int* __restrict__ epermS,
                                                   const int* __restrict__ key,
                                                   int* __restrict__ out) {
    int p = blockIdx.x * 256 + threadIdx.x;
    if (p < NE) out[p] = key[epermS[p]];
}

// ---- idxS[posS[epermD2[q]]] = q  (src-sorted position -> dst-node-sorted slot)
__global__ __launch_bounds__(256) void k_scatterIdx(const int* __restrict__ epermD2,
                                                    const int* __restrict__ posS,
                                                    int* __restrict__ idxS) {
    int q = blockIdx.x * 256 + threadIdx.x;
    if (q < NE) idxS[posS[epermD2[q]]] = q;
}

// ---- fused per-16-node-src-tile: MFMA Q -> bf16 LDS, stream edges.
// MODE 0: atomicAdd into agg[idxS=dst]; MODE 1: store to msgbuf[idxS=slot].
template<int MODE>
__global__ __launch_bounds__(256) void k_msgF16(
    const float* __restrict__ h, const unsigned short* __restrict__ W2bf,
    const float* __restrict__ tS, const int* __restrict__ srcS,
    const int* __restrict__ idxS, const int* __restrict__ offs,
    float* __restrict__ outbuf) {
    __shared__ unsigned short sQ[16 * QSTRH];   // 34048 B
    __shared__ int sRow[32], sIdx[32];
    int tid = threadIdx.x;
    int tile = blockIdx.x;
    int beg = offs[tile], end = offs[tile + 1];
    if (beg >= end) return;
    int nodeBase = tile * 16;
    int wave = tid >> 6, lane = tid & 63;

    int arow = lane & 15;
    const float* hp = h + (size_t)(nodeBase + arow) * 32 + ((lane >> 4) << 2);
    float4 x0 = *(const float4*)hp;
    float4 x1 = *(const float4*)(hp + 16);
    bf16x8 a;
    a[0] = (short)f2bf(x0.x); a[1] = (short)f2bf(x0.y);
    a[2] = (short)f2bf(x0.z); a[3] = (short)f2bf(x0.w);
    a[4] = (short)f2bf(x1.x); a[5] = (short)f2bf(x1.y);
    a[6] = (short)f2bf(x1.z); a[7] = (short)f2bf(x1.w);

    f32x4 z = {0.f, 0.f, 0.f, 0.f};
    int crow0 = (lane >> 4) << 2;
    int ccol = lane & 15;
    for (int ct = wave; ct < 66; ct += 4) {
        bf16x8 b = *(const bf16x8*)(W2bf + (size_t)((ct << 6) + lane) * 8);
        f32x4 acc = __builtin_amdgcn_mfma_f32_16x16x32_bf16(a, b, z, 0, 0, 0);
        unsigned short* qp = sQ + crow0 * QSTRH + (ct << 4) + ccol;
        qp[0 * QSTRH] = f2bf(acc[0]); qp[1 * QSTRH] = f2bf(acc[1]);
        qp[2 * QSTRH] = f2bf(acc[2]); qp[3 * QSTRH] = f2bf(acc[3]);
    }
    __syncthreads();

    int el = tid >> 3, l8 = tid & 7;
    int gbase = lane & 56;
    for (int s0 = beg; s0 < end; s0 += 32) {
        int nact = min(32, end - s0);
        if (tid < nact) {
            sRow[tid] = srcS[s0 + tid] - nodeBase;
            sIdx[tid] = idxS[s0 + tid];
        }
        __syncthreads();
        if (el < nact) {
            float4 tv = *(const float4*)(tS + (size_t)(s0 + el) * 32 + (l8 << 2));
            const unsigned short* qp = sQ + sRow[el] * QSTRH + (l8 << 2);
            ushort4 qb = *(const ushort4*)(qp + 1024);
            float a0 = bf2f(qb.x), a1 = bf2f(qb.y), a2 = bf2f(qb.z), a3 = bf2f(qb.w);
            #pragma unroll
            for (int kk = 0; kk < 8; ++kk) {
                float t0 = __shfl(tv.x, gbase + kk, 64);
                float t1 = __shfl(tv.y, gbase + kk, 64);
                float t2 = __shfl(tv.z, gbase + kk, 64);
                float t3 = __shfl(tv.w, gbase + kk, 64);
                ushort4 q0 = *(const ushort4*)(qp + ((kk << 2) + 0) * 32);
                ushort4 q1 = *(const ushort4*)(qp + ((kk << 2) + 1) * 32);
                ushort4 q2 = *(const ushort4*)(qp + ((kk << 2) + 2) * 32);
                ushort4 q3 = *(const ushort4*)(qp + ((kk << 2) + 3) * 32);
                a0 += t0 * bf2f(q0.x); a1 += t0 * bf2f(q0.y);
                a2 += t0 * bf2f(q0.z); a3 += t0 * bf2f(q0.w);
                a0 += t1 * bf2f(q1.x); a1 += t1 * bf2f(q1.y);
                a2 += t1 * bf2f(q1.z); a3 += t1 * bf2f(q1.w);
                a0 += t2 * bf2f(q2.x); a1 += t2 * bf2f(q2.y);
                a2 += t2 * bf2f(q2.z); a3 += t2 * bf2f(q2.w);
                a0 += t3 * bf2f(q3.x); a1 += t3 * bf2f(q3.y);
                a2 += t3 * bf2f(q3.z); a3 += t3 * bf2f(q3.w);
            }
            if (MODE) {
                *(float4*)(outbuf + (size_t)sIdx[el] * 32 + (l8 << 2)) =
                    make_float4(a0, a1, a2, a3);
            } else {
                float* ap = outbuf + (size_t)sIdx[el] * 32 + (l8 << 2);
                atomicAdd(ap + 0, a0); atomicAdd(ap + 1, a1);
                atomicAdd(ap + 2, a2); atomicAdd(ap + 3, a3);
            }
        }
        __syncthreads();
    }
}

// ---- fallback msg (tiny ws): recompute We per edge (t in original order)
__global__ __launch_bounds__(256) void k_msgC(
    const float* __restrict__ t, const int* __restrict__ src, const int* __restrict__ dst,
    const float* __restrict__ h, const float* __restrict__ W2ext, float* __restrict__ agg) {
    __shared__ float sT[32][33], sH[32][33];
    __shared__ int sSrc[32], sDst[32];
    int tid = threadIdx.x;
    int e0 = blockIdx.x * 32;
    if (tid < 32) sSrc[tid] = src[e0 + tid];
    else if (tid < 64) sDst[tid - 32] = dst[e0 + tid - 32];
    __syncthreads();
    for (int idx = tid; idx < 1024; idx += 256) {
        int el = idx >> 5, k = idx & 31;
        sT[el][k] = t[(e0 + el) * 32 + k];
        sH[el][k] = h[(size_t)sSrc[el] * 32 + k];
    }
    __syncthreads();
    int el = tid >> 3, l8 = tid & 7;
    int c0 = l8 * 4;
    float m0 = 0.f, m1 = 0.f, m2 = 0.f, m3 = 0.f;
    for (int i = 0; i < 32; ++i) {
        const float* wrow = W2ext + i * QC;
        float4 wb = *(const float4*)(wrow + 1024 + c0);
        float w0 = wb.x, w1 = wb.y, w2 = wb.z, w3 = wb.w;
        #pragma unroll 8
        for (int k = 0; k < 32; ++k) {
            float tk = sT[el][k];
            float4 w = *(const float4*)(wrow + k * 32 + c0);
            w0 += tk * w.x; w1 += tk * w.y; w2 += tk * w.z; w3 += tk * w.w;
        }
        float hi = sH[el][i];
        m0 += hi * w0; m1 += hi * w1; m2 += hi * w2; m3 += hi * w3;
    }
    float* ap = agg + (size_t)sDst[el] * 32 + c0;
    atomicAdd(ap + 0, m0); atomicAdd(ap + 1, m1);
    atomicAdd(ap + 2, m2); atomicAdd(ap + 3, m3);
}

// ---- GRU step reading agg[] (MODE 0 / fallback)
__global__ __launch_bounds__(256) void k_gru(
    const float* __restrict__ agg, const float* __restrict__ convB,
    const float* __restrict__ Wi, const float* __restrict__ Wh,
    const float* __restrict__ bi, const float* __restrict__ bh,
    float* __restrict__ h) {
    __shared__ float sWi[3072], sWh[3072], sBi[96], sBh[96], sCb[32];
    __shared__ float sX[8][33], sH[8][33];
    int tid = threadIdx.x;
    for (int i = tid; i < 3072; i += 256) { sWi[i] = Wi[i]; sWh[i] = Wh[i]; }
    if (tid < 96) { sBi[tid] = bi[tid]; sBh[tid] = bh[tid]; }
    if (tid < 32) sCb[tid] = convB[tid];
    int ln = tid >> 5, o = tid & 31;
    for (int g = 0; g < 4; ++g) {
        int node = blockIdx.x * 32 + g * 8 + ln;
        float hv = h[node * 32 + o];
        float av = agg[node * 32 + o];
        __syncthreads();
        sX[ln][o] = fmaxf(av + sCb[o], 0.f);
        sH[ln][o] = hv;
        __syncthreads();
        float air = sBi[o], aiz = sBi[o + 32], ain = sBi[o + 64];
        float ahr = sBh[o], ahz = sBh[o + 32], ahn = sBh[o + 64];
        #pragma unroll 8
        for (int i = 0; i < 32; ++i) {
            float x = sX[ln][i], hh = sH[ln][i];
            air += x * sWi[i * 96 + o];      ahr += hh * sWh[i * 96 + o];
            aiz += x * sWi[i * 96 + o + 32]; ahz += hh * sWh[i * 96 + o + 32];
            ain += x * sWi[i * 96 + o + 64]; ahn += hh * sWh[i * 96 + o + 64];
        }
        float r = sigm(air + ahr);
        float zz = sigm(aiz + ahz);
        float ng = tanhf(ain + r * ahn);
        h[node * 32 + o] = (1.f - zz) * ng + zz * hv;
    }
}

// ---- MODE 1: per 32-node dst tile: segment-sum -> X in LDS, GRU via split-bf16 MFMA.
// [X|H](32x64) @ [[Wi],[Wh]](64x96); wave w: M-half m=w>>1, col-half c=w&1;
// gates r,z stacked-K; n via separate inn/hn accumulators. 18 MFMAs/wave.
__global__ __launch_bounds__(256) void k_gruAgg4(
    const float* __restrict__ msgbuf, const int* __restrict__ nodeOffs,
    const float* __restrict__ convB,
    const unsigned short* __restrict__ Whi, const unsigned short* __restrict__ Wlo,
    const float* __restrict__ bi, const float* __restrict__ bh,
    float* __restrict__ h) {
    __shared__ float sAgg[32 * 33];
    int tid = threadIdx.x;
    int d = blockIdx.x;
    int base = d * 32;

    // 1) segment-sum + relu(conv_b) -> sAgg (x)
    {
        int n8 = tid >> 3, l8 = tid & 7;
        int node = base + n8;
        int nb = nodeOffs[node], ne2 = nodeOffs[node + 1];
        float a0 = 0.f, a1 = 0.f, a2 = 0.f, a3 = 0.f;
        for (int p = nb; p < ne2; ++p) {
            float4 v = *(const float4*)(msgbuf + (size_t)p * 32 + (l8 << 2));
            a0 += v.x; a1 += v.y; a2 += v.z; a3 += v.w;
        }
        int c0 = l8 << 2;
        float4 cb = *(const float4*)(convB + c0);
        float* sp = sAgg + n8 * 33 + c0;
        sp[0] = fmaxf(a0 + cb.x, 0.f);
        sp[1] = fmaxf(a1 + cb.y, 0.f);
        sp[2] = fmaxf(a2 + cb.z, 0.f);
        sp[3] = fmaxf(a3 + cb.w, 0.f);
    }
    __syncthreads();

    // 2) MFMA gates
    int wave = tid >> 6, lane = tid & 63;
    int m = wave >> 1, c = wave & 1;
    int arow = lane & 15, kg = (lane >> 4) << 2;

    bf16x8 xhi, xlo, hhi, hlo;
    {
        const float* xp = sAgg + (m * 16 + arow) * 33 + kg;
        float4 v0 = *(const float4*)xp;
        float4 v1 = *(const float4*)(xp + 16);
        float xv[8] = {v0.x, v0.y, v0.z, v0.w, v1.x, v1.y, v1.z, v1.w};
        #pragma unroll
        for (int j = 0; j < 8; ++j) {
            unsigned short hi16 = f2bf(xv[j]);
            xhi[j] = (short)hi16;
            xlo[j] = (short)f2bf(xv[j] - bf2f(hi16));
        }
        const float* hp = h + (size_t)(base + m * 16 + arow) * 32 + kg;
        float4 w0 = *(const float4*)hp;
        float4 w1 = *(const float4*)(hp + 16);
        float hv8[8] = {w0.x, w0.y, w0.z, w0.w, w1.x, w1.y, w1.z, w1.w};
        #pragma unroll
        for (int j = 0; j < 8; ++j) {
            unsigned short hi16 = f2bf(hv8[j]);
            hhi[j] = (short)hi16;
            hlo[j] = (short)f2bf(hv8[j] - bf2f(hi16));
        }
    }

    int ccol = lane & 15, crow0 = (lane >> 4) << 2;
    int o = c * 16 + ccol;
    auto Bf = [&](int nt, int kt, const unsigned short* W) {
        return *(const bf16x8*)(W + (size_t)(((nt * 2 + kt) * 64 + lane) << 3));
    };
    f32x4 accR = {0.f, 0.f, 0.f, 0.f}, accZ = {0.f, 0.f, 0.f, 0.f};
    f32x4 accIN = {0.f, 0.f, 0.f, 0.f}, accHN = {0.f, 0.f, 0.f, 0.f};
    {
        int nt = c;        // r gate
        bf16x8 b0h = Bf(nt, 0, Whi), b0l = Bf(nt, 0, Wlo);
        bf16x8 b1h = Bf(nt, 1, Whi), b1l = Bf(nt, 1, Wlo);
        accR = __builtin_amdgcn_mfma_f32_16x16x32_bf16(xhi, b0h, accR, 0, 0, 0);
        accR = __builtin_amdgcn_mfma_f32_16x16x32_bf16(xlo, b0h, accR, 0, 0, 0);
        accR = __builtin_amdgcn_mfma_f32_16x16x32_bf16(xhi, b0l, accR, 0, 0, 0);
        accR = __builtin_amdgcn_mfma_f32_16x16x32_bf16(hhi, b1h, accR, 0, 0, 0);
        accR = __builtin_amdgcn_mfma_f32_16x16x32_bf16(hlo, b1h, accR, 0, 0, 0);
        accR = __builtin_amdgcn_mfma_f32_16x16x32_bf16(hhi, b1l, accR, 0, 0, 0);
    }
    {
        int nt = 2 + c;    // z gate
        bf16x8 b0h = Bf(nt, 0, Whi), b0l = Bf(nt, 0, Wlo);
        bf16x8 b1h = Bf(nt, 1, Whi), b1l = Bf(nt, 1, Wlo);
        accZ = __builtin_amdgcn_mfma_f32_16x16x32_bf16(xhi, b0h, accZ, 0, 0, 0);
        accZ = __builtin_amdgcn_mfma_f32_16x16x32_bf16(xlo, b0h, accZ, 0, 0, 0);
        accZ = __builtin_amdgcn_mfma_f32_16x16x32_bf16(xhi, b0l, accZ, 0, 0, 0);
        accZ = __builtin_amdgcn_mfma_f32_16x16x32_bf16(hhi, b1h, accZ, 0, 0, 0);
        accZ = __builtin_amdgcn_mfma_f32_16x16x32_bf16(hlo, b1h, accZ, 0, 0, 0);
        accZ = __builtin_amdgcn_mfma_f32_16x16x32_bf16(hhi, b1l, accZ, 0, 0, 0);
    }
    {
        int nt = 4 + c;    // n gate: inn (X@Wi) and hn (H@Wh) separate
        bf16x8 b0h = Bf(nt, 0, Whi), b0l = Bf(nt, 0, Wlo);
        bf16x8 b1h = Bf(nt, 1, Whi), b1l = Bf(nt, 1, Wlo);
        accIN = __builtin_amdgcn_mfma_f32_16x16x32_bf16(xhi, b0h, accIN, 0, 0, 0);
        accIN = __builtin_amdgcn_mfma_f32_16x16x32_bf16(xlo, b0h, accIN, 0, 0, 0);
        accIN = __builtin_amdgcn_mfma_f32_16x16x32_bf16(xhi, b0l, accIN, 0, 0, 0);
        accHN = __builtin_amdgcn_mfma_f32_16x16x32_bf16(hhi, b1h, accHN, 0, 0, 0);
        accHN = __builtin_amdgcn_mfma_f32_16x16x32_bf16(hlo, b1h, accHN, 0, 0, 0);
        accHN = __builtin_amdgcn_mfma_f32_16x16x32_bf16(hhi, b1l, accHN, 0, 0, 0);
    }

    float bir = bi[o], biz = bi[32 + o], bin = bi[64 + o];
    float bhr = bh[o], bhz = bh[32 + o], bhn = bh[64 + o];
    float hv[4];
    #pragma unroll
    for (int j = 0; j < 4; ++j)
        hv[j] = h[(size_t)(base + m * 16 + crow0 + j) * 32 + o];
    __syncthreads();    // all h reads complete before any h writes (cross-wave cols)
    #pragma unroll
    for (int j = 0; j < 4; ++j) {
        float r  = sigm(accR[j] + bir + bhr);
        float zz = sigm(accZ[j] + biz + bhz);
        float ng = tanhf(accIN[j] + bin + r * (accHN[j] + bhn));
        h[(size_t)(base + m * 16 + crow0 + j) * 32 + o] = (1.f - zz) * ng + zz * hv[j];
    }
}

// ---- decoder
__global__ __launch_bounds__(256) void k_dec(
    const float* __restrict__ h,
    const float* __restrict__ W1, const float* __restrict__ b1, const float* __restrict__ a1,
    const float* __restrict__ W2, const float* __restrict__ b2, const float* __restrict__ a2,
    const float* __restrict__ W3, const float* __restrict__ b3, const float* __restrict__ a3,
    const float* __restrict__ W4, const float* __restrict__ b4,
    float* __restrict__ out) {
    __shared__ float sW1[1024], sW2[1024], sW3[1024], sW4[96];
    __shared__ float sB1[32], sB2[32], sB3[32], sB4[3];
    __shared__ float sYa[8][33], sYb[8][33];
    int tid = threadIdx.x;
    for (int i = tid; i < 1024; i += 256) { sW1[i] = W1[i]; sW2[i] = W2[i]; sW3[i] = W3[i]; }
    if (tid < 96) sW4[tid] = W4[tid];
    if (tid < 32) { sB1[tid] = b1[tid]; sB2[tid] = b2[tid]; sB3[tid] = b3[tid]; }
    if (tid < 3) sB4[tid] = b4[tid];
    float A1 = a1[0], A2 = a2[0], A3 = a3[0];
    int ln = tid >> 5, o = tid & 31;
    int node = blockIdx.x * 8 + ln;
    sYa[ln][o] = h[node * 32 + o];
    __syncthreads();
    float acc = sB1[o];
    #pragma unroll
    for (int i = 0; i < 32; ++i) acc += sYa[ln][i] * sW1[i * 32 + o];
    acc = acc >= 0.f ? acc : A1 * acc;
    sYb[ln][o] = acc;
    __syncthreads();
    acc = sB2[o];
    #pragma unroll
    for (int i = 0; i < 32; ++i) acc += sYb[ln][i] * sW2[i * 32 + o];
    acc = acc >= 0.f ? acc : A2 * acc;
    __syncthreads();
    sYa[ln][o] = acc;
    __syncthreads();
    acc = sB3[o];
    #pragma unroll
    for (int i = 0; i < 32; ++i) acc += sYa[ln][i] * sW3[i * 32 + o];
    acc = acc >= 0.f ? acc : A3 * acc;
    __syncthreads();
    sYb[ln][o] = acc;
    __syncthreads();
    if (o < 3) {
        float r = sB4[o];
        #pragma unroll
        for (int i = 0; i < 32; ++i) r += sYb[ln][i] * sW4[i * 3 + o];
        out[node * 3 + o] = r;
    }
}

extern "C" void kernel_launch(void* const* d_in, const int* in_sizes, int n_in,
                              void* d_out, int out_size, void* d_ws, size_t ws_size,
                              hipStream_t stream) {
    const int*   nfeats = (const int*)d_in[0];
    const float* efeats = (const float*)d_in[1];
    const int*   src    = (const int*)d_in[2];
    const int*   dst    = (const int*)d_in[3];
    const float* emb    = (const float*)d_in[4];
    const float* encW   = (const float*)d_in[5];
    const float* encB   = (const float*)d_in[6];
    const float* eencW  = (const float*)d_in[7];
    const float* eencB  = (const float*)d_in[8];
    const float* projW  = (const float*)d_in[9];
    const float* projB  = (const float*)d_in[10];
    const float* enW1   = (const float*)d_in[11];
    const float* enB1   = (const float*)d_in[12];
    const float* enW2   = (const float*)d_in[13];
    const float* enB2   = (const float*)d_in[14];
    const float* convB  = (const float*)d_in[15];
    const float* gruWi  = (const float*)d_in[16];
    const float* gruWh  = (const float*)d_in[17];
    const float* gruBi  = (const float*)d_in[18];
    const float* gruBh  = (const float*)d_in[19];
    const float* dW1 = (const float*)d_in[20]; const float* db1 = (const float*)d_in[21]; const float* da1 = (const float*)d_in[22];
    const float* dW2 = (const float*)d_in[23]; const float* db2 = (const float*)d_in[24]; const float* da2 = (const float*)d_in[25];
    const float* dW3 = (const float*)d_in[26]; const float* db3 = (const float*)d_in[27]; const float* da3 = (const float*)d_in[28];
    const float* dW4 = (const float*)d_in[29]; const float* db4 = (const float*)d_in[30];
    float* out = (float*)d_out;
    char* ws = (char*)d_ws;

    // bump allocator (256-B aligned)
    size_t cur = 0;
    auto alloc = [&](size_t n) { size_t p = cur; cur = (cur + n + 255) & ~(size_t)255; return p; };
    size_t o_h   = alloc((size_t)NN * 32 * 4);
    size_t o_t   = alloc((size_t)NE * 32 * 4);      // tS (or t in fallback)
    size_t o_w2e = alloc((size_t)32 * QC * 4);
    size_t afterCommon = cur;                       // fallback agg goes here
    size_t o_w2b = alloc((size_t)66 * 512 * 2);
    size_t o_epS = alloc((size_t)NE * 4);
    size_t o_ofS = alloc((size_t)(NTS + 1) * 4);
    size_t o_posS = alloc((size_t)NE * 4);
    size_t o_srcS = alloc((size_t)NE * 4);
    size_t o_idxS = alloc((size_t)NE * 4);
    size_t baseEnd = cur;                           // MODE0 agg goes here
    size_t o_epD  = alloc((size_t)NE * 4);
    size_t o_ofD  = alloc((size_t)(NT_D + 1) * 4);
    size_t o_epD2 = alloc((size_t)NE * 4);
    size_t o_noff = alloc((size_t)(NN + 1) * 4);
    size_t o_whi  = alloc((size_t)6144 * 2);
    size_t o_wlo  = alloc((size_t)6144 * 2);
    size_t o_msg  = alloc((size_t)NE * 32 * 4);     // MODE1 msgbuf
    size_t need1 = cur;
    size_t need0 = baseEnd + (size_t)NN * 32 * 4;

    int mode;                                       // 1: node-sorted, 0: atomic, -1: msgC
    if (ws_size >= need1) mode = 1;
    else if (ws_size >= need0) mode = 0;
    else mode = -1;

    float* h     = (float*)(ws + o_h);
    float* tS    = (float*)(ws + o_t);
    float* W2ext = (float*)(ws + o_w2e);
    unsigned short* W2bf = (unsigned short*)(ws + o_w2b);
    int* epermS  = (int*)(ws + o_epS);
    int* offsS   = (int*)(ws + o_ofS);
    int* posS    = (int*)(ws + o_posS);
    int* srcS    = (int*)(ws + o_srcS);
    int* idxS    = (int*)(ws + o_idxS);
    int* epermD  = (int*)(ws + o_epD);
    int* offsD   = (int*)(ws + o_ofD);
    int* epermD2 = (int*)(ws + o_epD2);
    int* nodeOffs = (int*)(ws + o_noff);
    unsigned short* gWhi = (unsigned short*)(ws + o_whi);
    unsigned short* gWlo = (unsigned short*)(ws + o_wlo);
    float* outbuf = (mode == 1) ? (float*)(ws + o_msg)
                  : (mode == 0) ? (float*)(ws + baseEnd)
                                : (float*)(ws + afterCommon);
    // scratch (prologue only) unions into outbuf region
    int* blockCounts = (int*)outbuf;                      // HB*NTS = 3.2 MB
    int* blockStart  = blockCounts + (size_t)HB * NTS;    // 3.2 MB
    int* tileTot     = blockStart + (size_t)HB * NTS;     // 25 KB

    k_node_enc<<<NN / 8, 256, 0, stream>>>(nfeats, emb, encW, encB, projW, projB, h);

    if (mode >= 0) {
        k_w2prep<<<(66 * 512 + 255) / 256, 256, 0, stream>>>(enW2, enB2, W2bf);
        // src bucketing (16-node tiles)
        k_histT<NTS, 4><<<HB, 256, 0, stream>>>(src, blockCounts);
        k_colsumT<NTS><<<(NTS + 255) / 256, 256, 0, stream>>>(blockCounts, blockStart, tileTot);
        k_scanT<NTS, 25><<<1, 256, 0, stream>>>(tileTot, offsS);
        k_scatterT<NTS, 4><<<HB, 256, 0, stream>>>(src, blockStart, offsS, epermS);
        k_invperm<<<(NE + 255) / 256, 256, 0, stream>>>(epermS, posS);
        k_gatherKey<<<(NE + 255) / 256, 256, 0, stream>>>(epermS, src, srcS);
        if (mode == 1) {
            k_wgru<<<(6144 + 255) / 256, 256, 0, stream>>>(gruWi, gruWh, gWhi, gWlo);
            // dst bucketing (32-node tiles) -> per-node sort -> idxS via posS
            k_histT<NT_D, 5><<<HB, 256, 0, stream>>>(dst, blockCounts);
            k_colsumT<NT_D><<<(NT_D + 255) / 256, 256, 0, stream>>>(blockCounts, blockStart, tileTot);
            k_scanT<NT_D, 13><<<1, 256, 0, stream>>>(tileTot, offsD);
            k_scatterT<NT_D, 5><<<HB, 256, 0, stream>>>(dst, blockStart, offsD, epermD);
            k_sortNode<<<NT_D, 256, 0, stream>>>(epermD, dst, offsD, epermD2, nodeOffs);
            k_scatterIdx<<<(NE + 255) / 256, 256, 0, stream>>>(epermD2, posS, idxS);
        } else {
            k_gatherKey<<<(NE + 255) / 256, 256, 0, stream>>>(epermS, dst, idxS);
        }
        k_edge_t2<<<NE / 64, 256, 0, stream>>>(efeats, eencW, eencB, enW1, enB1, epermS, tS);
    } else {
        k_w2ext<<<(32 * QC + 255) / 256, 256, 0, stream>>>(enW2, enB2, W2ext);
        k_edge_t2<<<NE / 64, 256, 0, stream>>>(efeats, eencW, eencB, enW1, enB1, nullptr, tS);
    }

    for (int s = 0; s < 3; ++s) {
        if (mode == 1) {
            k_msgF16<1><<<NTS, 256, 0, stream>>>(h, W2bf, tS, srcS, idxS, offsS, outbuf);
            k_gruAgg4<<<NT_D, 256, 0, stream>>>(outbuf, nodeOffs, convB,
                                                gWhi, gWlo, gruBi, gruBh, h);
        } else if (mode == 0) {
            hipMemsetAsync(outbuf, 0, (size_t)NN * 32 * 4, stream);
            k_msgF16<0><<<NTS, 256, 0, stream>>>(h, W2bf, tS, srcS, idxS, offsS, outbuf);
            k_gru<<<NN / 32, 256, 0, stream>>>(outbuf, convB, gruWi, gruWh, gruBi, gruBh, h);
        } else {
            hipMemsetAsync(outbuf, 0, (size_t)NN * 32 * 4, stream);
            k_msgC<<<NE / 32, 256, 0, stream>>>(tS, src, dst, h, W2ext, outbuf);
            k_gru<<<NN / 32, 256, 0, stream>>>(outbuf, convB, gruWi, gruWh, gruBi, gruBh, h);
        }
    }
    k_dec<<<NN / 8, 256, 0, stream>>>(h, dW1, db1, da1, dW2, db2, da2, dW3, db3, da3, dW4, db4, out);
}

// Round 12
// 455.819 us; speedup vs baseline: 4.6162x; 1.1036x over previous
//
#include <hip/hip_runtime.h>
#include <hip/hip_bf16.h>

// MPNN on MI355X — fused 16-node-tile msg kernel + MFMA GRU, fully pre-sorted streams.
// msg[e,o] = sum_k t[e,k]*Q[src,k,o] + q0[src,o],  Q[n] = h[n] @ W2ext
// k_msgF16: per 16-node src tile, MFMA Q (16x1056 bf16) into LDS (QSTRH=1068 ->
// all 16 rows on distinct bank phases), then a BARRIER-FREE edge stream (srcS/idxS
// read via same-address broadcast). Edge encoder algebraically folded:
// t = relu(ef @ (eencW@enW1) + (eencB@enW1+enB1)) — one 16x32 matmul, weights in
// registers. k_gruAgg4: split-bf16 MFMA GRU. No global atomics (MODE1).

#define NN 100000
#define NE 320000
#define QC 1056
#define NTS 6250      // NN/16 src tiles
#define NT_D 3125     // NN/32 dst tiles
#define HB 128        // bucketing blocks
#define EPB (NE / HB) // 2500
#define QSTRH 1068    // sQ row stride (shorts); 534 dwords % 32 = 22 -> distinct row banks

typedef short bf16x8 __attribute__((ext_vector_type(8)));
typedef float f32x4  __attribute__((ext_vector_type(4)));

__device__ __forceinline__ float bf2f(unsigned short u) {
    return __uint_as_float(((unsigned int)u) << 16);
}
__device__ __forceinline__ unsigned short f2bf(float f) {
    unsigned int x = __float_as_uint(f);
    unsigned int r = (x + 0x7fffu + ((x >> 16) & 1u)) >> 16;
    return (unsigned short)r;
}
__device__ __forceinline__ float sigm(float x) {
    return 1.f / (1.f + __expf(-x));
}

// ---- build W2ext [32][1056] (fp32, msgC fallback only)
__global__ __launch_bounds__(256) void k_w2ext(const float* __restrict__ W2,
                                               const float* __restrict__ b2,
                                               float* __restrict__ W2ext) {
    int idx = blockIdx.x * 256 + threadIdx.x;
    if (idx >= 32 * QC) return;
    int i = idx / QC, c = idx % QC;
    float v;
    if (c < 1024) { int k = c >> 5, o = c & 31; v = W2[k * 1024 + i * 32 + o]; }
    else          { v = b2[i * 32 + (c - 1024)]; }
    W2ext[idx] = v;
}

// ---- pack W2ext into bf16 B-fragment layout
__global__ __launch_bounds__(256) void k_w2prep(const float* __restrict__ W2,
                                                const float* __restrict__ b2,
                                                unsigned short* __restrict__ W2bf) {
    int idx = blockIdx.x * 256 + threadIdx.x;
    if (idx >= 66 * 512) return;
    int ct = idx >> 9, l = (idx >> 3) & 63, j = idx & 7;
    int kk = ((j >> 2) << 4) + ((l >> 4) << 2) + (j & 3);
    int c = ct * 16 + (l & 15);
    float v;
    if (c < 1024) { int kb = c >> 5, o = c & 31; v = W2[kb * 1024 + kk * 32 + o]; }
    else          { v = b2[kk * 32 + (c - 1024)]; }
    W2bf[idx] = f2bf(v);
}

// ---- pack combined GRU weights into B-frag bf16 hi/lo
__global__ __launch_bounds__(256) void k_wgru(const float* __restrict__ Wi,
                                              const float* __restrict__ Wh,
                                              unsigned short* __restrict__ Whi,
                                              unsigned short* __restrict__ Wlo) {
    int idx = blockIdx.x * 256 + threadIdx.x;
    if (idx >= 6144) return;
    int j = idx & 7, l = (idx >> 3) & 63, kt = (idx >> 9) & 1, nt = idx >> 10;
    int k = ((j >> 2) << 4) + ((l >> 4) << 2) + (j & 3);
    int col = nt * 16 + (l & 15);
    float v = kt ? Wh[k * 96 + col] : Wi[k * 96 + col];
    unsigned short hi = f2bf(v);
    Whi[idx] = hi;
    Wlo[idx] = f2bf(v - bf2f(hi));
}

// ---- fold edge encoder: Wcomb[i][o] = sum_j eencW[i][j]*enW1[j][o];
//      bcomb[o] = enB1[o] + sum_j eencB[j]*enW1[j][o].  One block of 544 threads.
__global__ __launch_bounds__(544) void k_wcomb(const float* __restrict__ eencW,
                                               const float* __restrict__ eencB,
                                               const float* __restrict__ enW1,
                                               const float* __restrict__ enB1,
                                               float* __restrict__ Wcomb,
                                               float* __restrict__ bcomb) {
    int tid = threadIdx.x;
    if (tid < 512) {
        int i = tid >> 5, o = tid & 31;
        float acc = 0.f;
        #pragma unroll 8
        for (int j = 0; j < 32; ++j) acc += eencW[i * 32 + j] * enW1[j * 32 + o];
        Wcomb[i * 32 + o] = acc;
    } else {
        int o = tid - 512;
        float acc = enB1[o];
        #pragma unroll 8
        for (int j = 0; j < 32; ++j) acc += eencB[j] * enW1[j * 32 + o];
        bcomb[o] = acc;
    }
}

// ---- node encoder + projection
__global__ __launch_bounds__(256) void k_node_enc(
    const int* __restrict__ nfeats, const float* __restrict__ emb,
    const float* __restrict__ encW, const float* __restrict__ encB,
    const float* __restrict__ projW, const float* __restrict__ projB,
    float* __restrict__ h) {
    __shared__ float sEncW[1024], sProjW[1024], sEncB[32], sProjB[32];
    __shared__ float sEmb[8][33], sNh[8][33];
    int tid = threadIdx.x;
    for (int i = tid; i < 1024; i += 256) { sEncW[i] = encW[i]; sProjW[i] = projW[i]; }
    if (tid < 32) { sEncB[tid] = encB[tid]; sProjB[tid] = projB[tid]; }
    int ln = tid >> 5, o = tid & 31;
    int node = blockIdx.x * 8 + ln;
    int nt = nfeats[node];
    sEmb[ln][o] = fmaxf(emb[nt * 32 + o], 0.f);
    __syncthreads();
    float acc = sEncB[o];
    #pragma unroll
    for (int i = 0; i < 32; ++i) acc += sEmb[ln][i] * sEncW[i * 32 + o];
    sNh[ln][o] = fmaxf(acc, 0.f);
    __syncthreads();
    float acc2 = sProjB[o];
    #pragma unroll
    for (int i = 0; i < 32; ++i) acc2 += sNh[ln][i] * sProjW[i * 32 + o];
    h[node * 32 + o] = fmaxf(acc2, 0.f);
}

// ---- edge encoder (folded): 128 edges/block, weights in registers, no barriers
__global__ __launch_bounds__(256) void k_edge_t3(
    const float* __restrict__ efeats, const float* __restrict__ Wcomb,
    const float* __restrict__ bcomb, const int* __restrict__ eperm,
    float* __restrict__ tS) {
    int tid = threadIdx.x;
    int el = tid >> 3, l8 = tid & 7;
    int gbase = (tid & 63) & 56;
    int c0 = l8 << 2;
    // per-thread Wcomb slice: W[i][c0..c0+3], i=0..15
    float4 w[16];
    #pragma unroll
    for (int i = 0; i < 16; ++i) w[i] = *(const float4*)(Wcomb + i * 32 + c0);
    float4 bb = *(const float4*)(bcomb + c0);
    #pragma unroll
    for (int it = 0; it < 4; ++it) {
        int p = blockIdx.x * 128 + it * 32 + el;
        int e = eperm ? eperm[p] : p;
        float2 efv = *(const float2*)(efeats + (size_t)e * 16 + (l8 << 1));
        float a0 = bb.x, a1 = bb.y, a2 = bb.z, a3 = bb.w;
        #pragma unroll
        for (int i = 0; i < 8; ++i) {
            float f0 = __shfl(efv.x, gbase + i, 64);
            float f1 = __shfl(efv.y, gbase + i, 64);
            float4 w0 = w[2 * i], w1 = w[2 * i + 1];
            a0 += f0 * w0.x + f1 * w1.x;
            a1 += f0 * w0.y + f1 * w1.y;
            a2 += f0 * w0.z + f1 * w1.z;
            a3 += f0 * w0.w + f1 * w1.w;
        }
        *(float4*)(tS + (size_t)p * 32 + c0) =
            make_float4(fmaxf(a0, 0.f), fmaxf(a1, 0.f), fmaxf(a2, 0.f), fmaxf(a3, 0.f));
    }
}

// ---- generic counting-sort bucketing
template<int NT, int SHIFT>
__global__ __launch_bounds__(256) void k_histT(const int* __restrict__ keys,
                                               int* __restrict__ blockCounts) {
    __shared__ int sHist[NT];
    int tid = threadIdx.x, b = blockIdx.x;
    for (int c = tid; c < NT; c += 256) sHist[c] = 0;
    __syncthreads();
    int beg = b * EPB, end = min(beg + EPB, NE);
    for (int e = beg + tid; e < end; e += 256)
        atomicAdd(&sHist[keys[e] >> SHIFT], 1);
    __syncthreads();
    for (int c = tid; c < NT; c += 256) blockCounts[b * NT + c] = sHist[c];
}

template<int NT>
__global__ __launch_bounds__(256) void k_colsumT(const int* __restrict__ blockCounts,
                                                 int* __restrict__ blockStart,
                                                 int* __restrict__ tileTot) {
    int c = blockIdx.x * 256 + threadIdx.x;
    if (c >= NT) return;
    int running = 0;
    #pragma unroll 8
    for (int b = 0; b < HB; ++b) {
        blockStart[b * NT + c] = running;
        running += blockCounts[b * NT + c];
    }
    tileTot[c] = running;
}

template<int NT, int SEG>
__global__ __launch_bounds__(256) void k_scanT(const int* __restrict__ tileTot,
                                               int* __restrict__ offs) {
    __shared__ int sTot[NT];
    __shared__ int sPart[257];
    int tid = threadIdx.x;
    for (int c = tid; c < NT; c += 256) sTot[c] = tileTot[c];
    __syncthreads();
    int base = tid * SEG;
    int loc = 0;
    for (int j = 0; j < SEG; ++j) {
        int c = base + j;
        if (c < NT) { int v = sTot[c]; sTot[c] = loc; loc += v; }
    }
    sPart[tid] = loc;
    __syncthreads();
    if (tid == 0) {
        int s = 0;
        for (int i = 0; i < 256; ++i) { int v = sPart[i]; sPart[i] = s; s += v; }
        sPart[256] = s;
    }
    __syncthreads();
    int add = sPart[tid];
    for (int j = 0; j < SEG; ++j) {
        int c = base + j;
        if (c < NT) sTot[c] += add;
    }
    __syncthreads();
    for (int c = tid; c < NT; c += 256) offs[c] = sTot[c];
    if (tid == 0) offs[NT] = sPart[256];
}

template<int NT, int SHIFT>
__global__ __launch_bounds__(256) void k_scatterT(const int* __restrict__ keys,
                                                  const int* __restrict__ blockStart,
                                                  const int* __restrict__ offs,
                                                  int* __restrict__ eperm) {
    __shared__ int sCur[NT];
    int tid = threadIdx.x, b = blockIdx.x;
    for (int c = tid; c < NT; c += 256)
        sCur[c] = offs[c] + blockStart[b * NT + c];
    __syncthreads();
    int beg = b * EPB, end = min(beg + EPB, NE);
    for (int e = beg + tid; e < end; e += 256) {
        int pos = atomicAdd(&sCur[keys[e] >> SHIFT], 1);
        eperm[pos] = e;
    }
}

// ---- second-level sort: within each dst tile, sort by node (32 LDS bins)
__global__ __launch_bounds__(256) void k_sortNode(
    const int* __restrict__ epermD, const int* __restrict__ dst,
    const int* __restrict__ offsD, int* __restrict__ epermD2,
    int* __restrict__ nodeOffs) {
    __shared__ int sCnt[32], sStart[32];
    int tid = threadIdx.x, d = blockIdx.x;
    int beg = offsD[d], end = offsD[d + 1];
    if (tid < 32) sCnt[tid] = 0;
    __syncthreads();
    for (int p = beg + tid; p < end; p += 256)
        atomicAdd(&sCnt[dst[epermD[p]] & 31], 1);
    __syncthreads();
    if (tid == 0) {
        int s = beg;
        for (int r = 0; r < 32; ++r) { sStart[r] = s; s += sCnt[r]; }
    }
    __syncthreads();
    if (tid < 32) {
        nodeOffs[d * 32 + tid] = sStart[tid];
        sCnt[tid] = sStart[tid];       // reuse as cursor
    }
    if (d == NT_D - 1 && tid == 0) nodeOffs[NN] = end;
    __syncthreads();
    for (int p = beg + tid; p < end; p += 256) {
        int e = epermD[p];
        int pos = atomicAdd(&sCnt[dst[e] & 31], 1);
        epermD2[pos] = e;
    }
}

// ---- inverse permutation: pos[eperm[p]] = p
__global__ __launch_bounds__(256) void k_invperm(const int* __restrict__ eperm,
                                                 int* __restrict__ pos) {
    int p = blockIdx.x * 256 + threadIdx.x;
    if (p < NE) pos[eperm[p]] = p;
}

// ---- gather key into src-sorted positions: out[p] = key[epermS[p]]
__global__ __launch_bounds__(256) void k_gatherKey(const int* __restrict__ epermS,
                                                   const int* __restrict__ key,
                                                   int* __restrict__ out) {
    int p = blockIdx.x * 256 + threadIdx.x;
    if (p < NE) out[p] = key[epermS[p]];
}

// ---- idxS[posS[epermD2[q]]] = q
__global__ __launch_bounds__(256) void k_scatterIdx(const int* __restrict__ epermD2,
                                                    const int* __restrict__ posS,
                                                    int* __restrict__ idxS) {
    int q = blockIdx.x * 256 + threadIdx.x;
    if (q < NE) idxS[posS[epermD2[q]]] = q;
}

// ---- fused per-16-node-src-tile: MFMA Q -> bf16 LDS, barrier-free edge stream.
// MODE 0: atomicAdd into agg[idxS=dst]; MODE 1: store to msgbuf[idxS=slot].
template<int MODE>
__global__ __launch_bounds__(256) void k_msgF16(
    const float* __restrict__ h, const unsigned short* __restrict__ W2bf,
    const float* __restrict__ tS, const int* __restrict__ srcS,
    const int* __restrict__ idxS, const int* __restrict__ offs,
    float* __restrict__ outbuf) {
    __shared__ unsigned short sQ[16 * QSTRH];   // 34176 B
    int tid = threadIdx.x;
    int tile = blockIdx.x;
    int beg = offs[tile], end = offs[tile + 1];
    if (beg >= end) return;
    int nodeBase = tile * 16;
    int wave = tid >> 6, lane = tid & 63;

    int arow = lane & 15;
    const float* hp = h + (size_t)(nodeBase + arow) * 32 + ((lane >> 4) << 2);
    float4 x0 = *(const float4*)hp;
    float4 x1 = *(const float4*)(hp + 16);
    bf16x8 a;
    a[0] = (short)f2bf(x0.x); a[1] = (short)f2bf(x0.y);
    a[2] = (short)f2bf(x0.z); a[3] = (short)f2bf(x0.w);
    a[4] = (short)f2bf(x1.x); a[5] = (short)f2bf(x1.y);
    a[6] = (short)f2bf(x1.z); a[7] = (short)f2bf(x1.w);

    f32x4 z = {0.f, 0.f, 0.f, 0.f};
    int crow0 = (lane >> 4) << 2;
    int ccol = lane & 15;
    for (int ct = wave; ct < 66; ct += 4) {
        bf16x8 b = *(const bf16x8*)(W2bf + (size_t)((ct << 6) + lane) * 8);
        f32x4 acc = __builtin_amdgcn_mfma_f32_16x16x32_bf16(a, b, z, 0, 0, 0);
        unsigned short* qp = sQ + crow0 * QSTRH + (ct << 4) + ccol;
        qp[0 * QSTRH] = f2bf(acc[0]); qp[1 * QSTRH] = f2bf(acc[1]);
        qp[2 * QSTRH] = f2bf(acc[2]); qp[3 * QSTRH] = f2bf(acc[3]);
    }
    __syncthreads();   // the only barrier

    int el = tid >> 3, l8 = tid & 7;
    int gbase = lane & 56;
    for (int p = beg + el; p < end; p += 32) {
        int row = srcS[p] - nodeBase;      // 8 lanes same addr -> broadcast
        int widx = idxS[p];
        float4 tv = *(const float4*)(tS + (size_t)p * 32 + (l8 << 2));
        const unsigned short* qp = sQ + row * QSTRH + (l8 << 2);
        ushort4 qb = *(const ushort4*)(qp + 1024);
        float a0 = bf2f(qb.x), a1 = bf2f(qb.y), a2 = bf2f(qb.z), a3 = bf2f(qb.w);
        #pragma unroll
        for (int kk = 0; kk < 8; ++kk) {
            float t0 = __shfl(tv.x, gbase + kk, 64);
            float t1 = __shfl(tv.y, gbase + kk, 64);
            float t2 = __shfl(tv.z, gbase + kk, 64);
            float t3 = __shfl(tv.w, gbase + kk, 64);
            ushort4 q0 = *(const ushort4*)(qp + ((kk << 2) + 0) * 32);
            ushort4 q1 = *(const ushort4*)(qp + ((kk << 2) + 1) * 32);
            ushort4 q2 = *(const ushort4*)(qp + ((kk << 2) + 2) * 32);
            ushort4 q3 = *(const ushort4*)(qp + ((kk << 2) + 3) * 32);
            a0 += t0 * bf2f(q0.x); a1 += t0 * bf2f(q0.y);
            a2 += t0 * bf2f(q0.z); a3 += t0 * bf2f(q0.w);
            a0 += t1 * bf2f(q1.x); a1 += t1 * bf2f(q1.y);
            a2 += t1 * bf2f(q1.z); a3 += t1 * bf2f(q1.w);
            a0 += t2 * bf2f(q2.x); a1 += t2 * bf2f(q2.y);
            a2 += t2 * bf2f(q2.z); a3 += t2 * bf2f(q2.w);
            a0 += t3 * bf2f(q3.x); a1 += t3 * bf2f(q3.y);
            a2 += t3 * bf2f(q3.z); a3 += t3 * bf2f(q3.w);
        }
        if (MODE) {
            *(float4*)(outbuf + (size_t)widx * 32 + (l8 << 2)) =
                make_float4(a0, a1, a2, a3);
        } else {
            float* ap = outbuf + (size_t)widx * 32 + (l8 << 2);
            atomicAdd(ap + 0, a0); atomicAdd(ap + 1, a1);
            atomicAdd(ap + 2, a2); atomicAdd(ap + 3, a3);
        }
    }
}

// ---- fallback msg (tiny ws): recompute We per edge (t in original order)
__global__ __launch_bounds__(256) void k_msgC(
    const float* __restrict__ t, const int* __restrict__ src, const int* __restrict__ dst,
    const float* __restrict__ h, const float* __restrict__ W2ext, float* __restrict__ agg) {
    __shared__ float sT[32][33], sH[32][33];
    __shared__ int sSrc[32], sDst[32];
    int tid = threadIdx.x;
    int e0 = blockIdx.x * 32;
    if (tid < 32) sSrc[tid] = src[e0 + tid];
    else if (tid < 64) sDst[tid - 32] = dst[e0 + tid - 32];
    __syncthreads();
    for (int idx = tid; idx < 1024; idx += 256) {
        int el = idx >> 5, k = idx & 31;
        sT[el][k] = t[(e0 + el) * 32 + k];
        sH[el][k] = h[(size_t)sSrc[el] * 32 + k];
    }
    __syncthreads();
    int el = tid >> 3, l8 = tid & 7;
    int c0 = l8 * 4;
    float m0 = 0.f, m1 = 0.f, m2 = 0.f, m3 = 0.f;
    for (int i = 0; i < 32; ++i) {
        const float* wrow = W2ext + i * QC;
        float4 wb = *(const float4*)(wrow + 1024 + c0);
        float w0 = wb.x, w1 = wb.y, w2 = wb.z, w3 = wb.w;
        #pragma unroll 8
        for (int k = 0; k < 32; ++k) {
            float tk = sT[el][k];
            float4 w = *(const float4*)(wrow + k * 32 + c0);
            w0 += tk * w.x; w1 += tk * w.y; w2 += tk * w.z; w3 += tk * w.w;
        }
        float hi = sH[el][i];
        m0 += hi * w0; m1 += hi * w1; m2 += hi * w2; m3 += hi * w3;
    }
    float* ap = agg + (size_t)sDst[el] * 32 + c0;
    atomicAdd(ap + 0, m0); atomicAdd(ap + 1, m1);
    atomicAdd(ap + 2, m2); atomicAdd(ap + 3, m3);
}

// ---- GRU step reading agg[] (MODE 0 / fallback)
__global__ __launch_bounds__(256) void k_gru(
    const float* __restrict__ agg, const float* __restrict__ convB,
    const float* __restrict__ Wi, const float* __restrict__ Wh,
    const float* __restrict__ bi, const float* __restrict__ bh,
    float* __restrict__ h) {
    __shared__ float sWi[3072], sWh[3072], sBi[96], sBh[96], sCb[32];
    __shared__ float sX[8][33], sH[8][33];
    int tid = threadIdx.x;
    for (int i = tid; i < 3072; i += 256) { sWi[i] = Wi[i]; sWh[i] = Wh[i]; }
    if (tid < 96) { sBi[tid] = bi[tid]; sBh[tid] = bh[tid]; }
    if (tid < 32) sCb[tid] = convB[tid];
    int ln = tid >> 5, o = tid & 31;
    for (int g = 0; g < 4; ++g) {
        int node = blockIdx.x * 32 + g * 8 + ln;
        float hv = h[node * 32 + o];
        float av = agg[node * 32 + o];
        __syncthreads();
        sX[ln][o] = fmaxf(av + sCb[o], 0.f);
        sH[ln][o] = hv;
        __syncthreads();
        float air = sBi[o], aiz = sBi[o + 32], ain = sBi[o + 64];
        float ahr = sBh[o], ahz = sBh[o + 32], ahn = sBh[o + 64];
        #pragma unroll 8
        for (int i = 0; i < 32; ++i) {
            float x = sX[ln][i], hh = sH[ln][i];
            air += x * sWi[i * 96 + o];      ahr += hh * sWh[i * 96 + o];
            aiz += x * sWi[i * 96 + o + 32]; ahz += hh * sWh[i * 96 + o + 32];
            ain += x * sWi[i * 96 + o + 64]; ahn += hh * sWh[i * 96 + o + 64];
        }
        float r = sigm(air + ahr);
        float zz = sigm(aiz + ahz);
        float ng = tanhf(ain + r * ahn);
        h[node * 32 + o] = (1.f - zz) * ng + zz * hv;
    }
}

// ---- MODE 1: per 32-node dst tile: segment-sum -> X in LDS, GRU via split-bf16 MFMA.
__global__ __launch_bounds__(256) void k_gruAgg4(
    const float* __restrict__ msgbuf, const int* __restrict__ nodeOffs,
    const float* __restrict__ convB,
    const unsigned short* __restrict__ Whi, const unsigned short* __restrict__ Wlo,
    const float* __restrict__ bi, const float* __restrict__ bh,
    float* __restrict__ h) {
    __shared__ float sAgg[32 * 33];
    int tid = threadIdx.x;
    int d = blockIdx.x;
    int base = d * 32;

    {
        int n8 = tid >> 3, l8 = tid & 7;
        int node = base + n8;
        int nb = nodeOffs[node], ne2 = nodeOffs[node + 1];
        float a0 = 0.f, a1 = 0.f, a2 = 0.f, a3 = 0.f;
        for (int p = nb; p < ne2; ++p) {
            float4 v = *(const float4*)(msgbuf + (size_t)p * 32 + (l8 << 2));
            a0 += v.x; a1 += v.y; a2 += v.z; a3 += v.w;
        }
        int c0 = l8 << 2;
        float4 cb = *(const float4*)(convB + c0);
        float* sp = sAgg + n8 * 33 + c0;
        sp[0] = fmaxf(a0 + cb.x, 0.f);
        sp[1] = fmaxf(a1 + cb.y, 0.f);
        sp[2] = fmaxf(a2 + cb.z, 0.f);
        sp[3] = fmaxf(a3 + cb.w, 0.f);
    }
    __syncthreads();

    int wave = tid >> 6, lane = tid & 63;
    int m = wave >> 1, c = wave & 1;
    int arow = lane & 15, kg = (lane >> 4) << 2;

    bf16x8 xhi, xlo, hhi, hlo;
    {
        const float* xp = sAgg + (m * 16 + arow) * 33 + kg;
        float4 v0 = *(const float4*)xp;
        float4 v1 = *(const float4*)(xp + 16);
        float xv[8] = {v0.x, v0.y, v0.z, v0.w, v1.x, v1.y, v1.z, v1.w};
        #pragma unroll
        for (int j = 0; j < 8; ++j) {
            unsigned short hi16 = f2bf(xv[j]);
            xhi[j] = (short)hi16;
            xlo[j] = (short)f2bf(xv[j] - bf2f(hi16));
        }
        const float* hp = h + (size_t)(base + m * 16 + arow) * 32 + kg;
        float4 w0 = *(const float4*)hp;
        float4 w1 = *(const float4*)(hp + 16);
        float hv8[8] = {w0.x, w0.y, w0.z, w0.w, w1.x, w1.y, w1.z, w1.w};
        #pragma unroll
        for (int j = 0; j < 8; ++j) {
            unsigned short hi16 = f2bf(hv8[j]);
            hhi[j] = (short)hi16;
            hlo[j] = (short)f2bf(hv8[j] - bf2f(hi16));
        }
    }

    int ccol = lane & 15, crow0 = (lane >> 4) << 2;
    int o = c * 16 + ccol;
    auto Bf = [&](int nt, int kt, const unsigned short* W) {
        return *(const bf16x8*)(W + (size_t)(((nt * 2 + kt) * 64 + lane) << 3));
    };
    f32x4 accR = {0.f, 0.f, 0.f, 0.f}, accZ = {0.f, 0.f, 0.f, 0.f};
    f32x4 accIN = {0.f, 0.f, 0.f, 0.f}, accHN = {0.f, 0.f, 0.f, 0.f};
    {
        int nt = c;
        bf16x8 b0h = Bf(nt, 0, Whi), b0l = Bf(nt, 0, Wlo);
        bf16x8 b1h = Bf(nt, 1, Whi), b1l = Bf(nt, 1, Wlo);
        accR = __builtin_amdgcn_mfma_f32_16x16x32_bf16(xhi, b0h, accR, 0, 0, 0);
        accR = __builtin_amdgcn_mfma_f32_16x16x32_bf16(xlo, b0h, accR, 0, 0, 0);
        accR = __builtin_amdgcn_mfma_f32_16x16x32_bf16(xhi, b0l, accR, 0, 0, 0);
        accR = __builtin_amdgcn_mfma_f32_16x16x32_bf16(hhi, b1h, accR, 0, 0, 0);
        accR = __builtin_amdgcn_mfma_f32_16x16x32_bf16(hlo, b1h, accR, 0, 0, 0);
        accR = __builtin_amdgcn_mfma_f32_16x16x32_bf16(hhi, b1l, accR, 0, 0, 0);
    }
    {
        int nt = 2 + c;
        bf16x8 b0h = Bf(nt, 0, Whi), b0l = Bf(nt, 0, Wlo);
        bf16x8 b1h = Bf(nt, 1, Whi), b1l = Bf(nt, 1, Wlo);
        accZ = __builtin_amdgcn_mfma_f32_16x16x32_bf16(xhi, b0h, accZ, 0, 0, 0);
        accZ = __builtin_amdgcn_mfma_f32_16x16x32_bf16(xlo, b0h, accZ, 0, 0, 0);
        accZ = __builtin_amdgcn_mfma_f32_16x16x32_bf16(xhi, b0l, accZ, 0, 0, 0);
        accZ = __builtin_amdgcn_mfma_f32_16x16x32_bf16(hhi, b1h, accZ, 0, 0, 0);
        accZ = __builtin_amdgcn_mfma_f32_16x16x32_bf16(hlo, b1h, accZ, 0, 0, 0);
        accZ = __builtin_amdgcn_mfma_f32_16x16x32_bf16(hhi, b1l, accZ, 0, 0, 0);
    }
    {
        int nt = 4 + c;
        bf16x8 b0h = Bf(nt, 0, Whi), b0l = Bf(nt, 0, Wlo);
        bf16x8 b1h = Bf(nt, 1, Whi), b1l = Bf(nt, 1, Wlo);
        accIN = __builtin_amdgcn_mfma_f32_16x16x32_bf16(xhi, b0h, accIN, 0, 0, 0);
        accIN = __builtin_amdgcn_mfma_f32_16x16x32_bf16(xlo, b0h, accIN, 0, 0, 0);
        accIN = __builtin_amdgcn_mfma_f32_16x16x32_bf16(xhi, b0l, accIN, 0, 0, 0);
        accHN = __builtin_amdgcn_mfma_f32_16x16x32_bf16(hhi, b1h, accHN, 0, 0, 0);
        accHN = __builtin_amdgcn_mfma_f32_16x16x32_bf16(hlo, b1h, accHN, 0, 0, 0);
        accHN = __builtin_amdgcn_mfma_f32_16x16x32_bf16(hhi, b1l, accHN, 0, 0, 0);
    }

    float bir = bi[o], biz = bi[32 + o], bin = bi[64 + o];
    float bhr = bh[o], bhz = bh[32 + o], bhn = bh[64 + o];
    float hv[4];
    #pragma unroll
    for (int j = 0; j < 4; ++j)
        hv[j] = h[(size_t)(base + m * 16 + crow0 + j) * 32 + o];
    __syncthreads();
    #pragma unroll
    for (int j = 0; j < 4; ++j) {
        float r  = sigm(accR[j] + bir + bhr);
        float zz = sigm(accZ[j] + biz + bhz);
        float ng = tanhf(accIN[j] + bin + r * (accHN[j] + bhn));
        h[(size_t)(base + m * 16 + crow0 + j) * 32 + o] = (1.f - zz) * ng + zz * hv[j];
    }
}

// ---- decoder
__global__ __launch_bounds__(256) void k_dec(
    const float* __restrict__ h,
    const float* __restrict__ W1, const float* __restrict__ b1, const float* __restrict__ a1,
    const float* __restrict__ W2, const float* __restrict__ b2, const float* __restrict__ a2,
    const float* __restrict__ W3, const float* __restrict__ b3, const float* __restrict__ a3,
    const float* __restrict__ W4, const float* __restrict__ b4,
    float* __restrict__ out) {
    __shared__ float sW1[1024], sW2[1024], sW3[1024], sW4[96];
    __shared__ float sB1[32], sB2[32], sB3[32], sB4[3];
    __shared__ float sYa[8][33], sYb[8][33];
    int tid = threadIdx.x;
    for (int i = tid; i < 1024; i += 256) { sW1[i] = W1[i]; sW2[i] = W2[i]; sW3[i] = W3[i]; }
    if (tid < 96) sW4[tid] = W4[tid];
    if (tid < 32) { sB1[tid] = b1[tid]; sB2[tid] = b2[tid]; sB3[tid] = b3[tid]; }
    if (tid < 3) sB4[tid] = b4[tid];
    float A1 = a1[0], A2 = a2[0], A3 = a3[0];
    int ln = tid >> 5, o = tid & 31;
    int node = blockIdx.x * 8 + ln;
    sYa[ln][o] = h[node * 32 + o];
    __syncthreads();
    float acc = sB1[o];
    #pragma unroll
    for (int i = 0; i < 32; ++i) acc += sYa[ln][i] * sW1[i * 32 + o];
    acc = acc >= 0.f ? acc : A1 * acc;
    sYb[ln][o] = acc;
    __syncthreads();
    acc = sB2[o];
    #pragma unroll
    for (int i = 0; i < 32; ++i) acc += sYb[ln][i] * sW2[i * 32 + o];
    acc = acc >= 0.f ? acc : A2 * acc;
    __syncthreads();
    sYa[ln][o] = acc;
    __syncthreads();
    acc = sB3[o];
    #pragma unroll
    for (int i = 0; i < 32; ++i) acc += sYa[ln][i] * sW3[i * 32 + o];
    acc = acc >= 0.f ? acc : A3 * acc;
    __syncthreads();
    sYb[ln][o] = acc;
    __syncthreads();
    if (o < 3) {
        float r = sB4[o];
        #pragma unroll
        for (int i = 0; i < 32; ++i) r += sYb[ln][i] * sW4[i * 3 + o];
        out[node * 3 + o] = r;
    }
}

extern "C" void kernel_launch(void* const* d_in, const int* in_sizes, int n_in,
                              void* d_out, int out_size, void* d_ws, size_t ws_size,
                              hipStream_t stream) {
    const int*   nfeats = (const int*)d_in[0];
    const float* efeats = (const float*)d_in[1];
    const int*   src    = (const int*)d_in[2];
    const int*   dst    = (const int*)d_in[3];
    const float* emb    = (const float*)d_in[4];
    const float* encW   = (const float*)d_in[5];
    const float* encB   = (const float*)d_in[6];
    const float* eencW  = (const float*)d_in[7];
    const float* eencB  = (const float*)d_in[8];
    const float* projW  = (const float*)d_in[9];
    const float* projB  = (const float*)d_in[10];
    const float* enW1   = (const float*)d_in[11];
    const float* enB1   = (const float*)d_in[12];
    const float* enW2   = (const float*)d_in[13];
    const float* enB2   = (const float*)d_in[14];
    const float* convB  = (const float*)d_in[15];
    const float* gruWi  = (const float*)d_in[16];
    const float* gruWh  = (const float*)d_in[17];
    const float* gruBi  = (const float*)d_in[18];
    const float* gruBh  = (const float*)d_in[19];
    const float* dW1 = (const float*)d_in[20]; const float* db1 = (const float*)d_in[21]; const float* da1 = (const float*)d_in[22];
    const float* dW2 = (const float*)d_in[23]; const float* db2 = (const float*)d_in[24]; const float* da2 = (const float*)d_in[25];
    const float* dW3 = (const float*)d_in[26]; const float* db3 = (const float*)d_in[27]; const float* da3 = (const float*)d_in[28];
    const float* dW4 = (const float*)d_in[29]; const float* db4 = (const float*)d_in[30];
    float* out = (float*)d_out;
    char* ws = (char*)d_ws;

    // bump allocator (256-B aligned)
    size_t cur = 0;
    auto alloc = [&](size_t n) { size_t p = cur; cur = (cur + n + 255) & ~(size_t)255; return p; };
    size_t o_h   = alloc((size_t)NN * 32 * 4);
    size_t o_t   = alloc((size_t)NE * 32 * 4);      // tS (or t in fallback)
    size_t o_w2e = alloc((size_t)32 * QC * 4);
    size_t afterCommon = cur;                       // fallback agg goes here
    size_t o_w2b = alloc((size_t)66 * 512 * 2);
    size_t o_epS = alloc((size_t)NE * 4);
    size_t o_ofS = alloc((size_t)(NTS + 1) * 4);
    size_t o_posS = alloc((size_t)NE * 4);
    size_t o_srcS = alloc((size_t)NE * 4);
    size_t o_idxS = alloc((size_t)NE * 4);
    size_t o_wcomb = alloc((size_t)(512 + 32) * 4);
    size_t baseEnd = cur;                           // MODE0 agg goes here
    size_t o_epD  = alloc((size_t)NE * 4);
    size_t o_ofD  = alloc((size_t)(NT_D + 1) * 4);
    size_t o_epD2 = alloc((size_t)NE * 4);
    size_t o_noff = alloc((size_t)(NN + 1) * 4);
    size_t o_whi  = alloc((size_t)6144 * 2);
    size_t o_wlo  = alloc((size_t)6144 * 2);
    size_t o_msg  = alloc((size_t)NE * 32 * 4);     // MODE1 msgbuf
    size_t need1 = cur;
    size_t need0 = baseEnd + (size_t)NN * 32 * 4;

    int mode;                                       // 1: node-sorted, 0: atomic, -1: msgC
    if (ws_size >= need1) mode = 1;
    else if (ws_size >= need0) mode = 0;
    else mode = -1;

    float* h     = (float*)(ws + o_h);
    float* tS    = (float*)(ws + o_t);
    float* W2ext = (float*)(ws + o_w2e);
    unsigned short* W2bf = (unsigned short*)(ws + o_w2b);
    int* epermS  = (int*)(ws + o_epS);
    int* offsS   = (int*)(ws + o_ofS);
    int* posS    = (int*)(ws + o_posS);
    int* srcS    = (int*)(ws + o_srcS);
    int* idxS    = (int*)(ws + o_idxS);
    float* Wcomb = (float*)(ws + o_wcomb);
    float* bcomb = Wcomb + 512;
    int* epermD  = (int*)(ws + o_epD);
    int* offsD   = (int*)(ws + o_ofD);
    int* epermD2 = (int*)(ws + o_epD2);
    int* nodeOffs = (int*)(ws + o_noff);
    unsigned short* gWhi = (unsigned short*)(ws + o_whi);
    unsigned short* gWlo = (unsigned short*)(ws + o_wlo);
    float* outbuf = (mode == 1) ? (float*)(ws + o_msg)
                  : (mode == 0) ? (float*)(ws + baseEnd)
                                : (float*)(ws + afterCommon);
    // scratch (prologue only) unions into outbuf region
    int* blockCounts = (int*)outbuf;                      // HB*NTS = 3.2 MB
    int* blockStart  = blockCounts + (size_t)HB * NTS;    // 3.2 MB
    int* tileTot     = blockStart + (size_t)HB * NTS;     // 25 KB

    k_node_enc<<<NN / 8, 256, 0, stream>>>(nfeats, emb, encW, encB, projW, projB, h);
    k_wcomb<<<1, 544, 0, stream>>>(eencW, eencB, enW1, enB1, Wcomb, bcomb);

    if (mode >= 0) {
        k_w2prep<<<(66 * 512 + 255) / 256, 256, 0, stream>>>(enW2, enB2, W2bf);
        // src bucketing (16-node tiles)
        k_histT<NTS, 4><<<HB, 256, 0, stream>>>(src, blockCounts);
        k_colsumT<NTS><<<(NTS + 255) / 256, 256, 0, stream>>>(blockCounts, blockStart, tileTot);
        k_scanT<NTS, 25><<<1, 256, 0, stream>>>(tileTot, offsS);
        k_scatterT<NTS, 4><<<HB, 256, 0, stream>>>(src, blockStart, offsS, epermS);
        k_invperm<<<(NE + 255) / 256, 256, 0, stream>>>(epermS, posS);
        k_gatherKey<<<(NE + 255) / 256, 256, 0, stream>>>(epermS, src, srcS);
        if (mode == 1) {
            k_wgru<<<(6144 + 255) / 256, 256, 0, stream>>>(gruWi, gruWh, gWhi, gWlo);
            k_histT<NT_D, 5><<<HB, 256, 0, stream>>>(dst, blockCounts);
            k_colsumT<NT_D><<<(NT_D + 255) / 256, 256, 0, stream>>>(blockCounts, blockStart, tileTot);
            k_scanT<NT_D, 13><<<1, 256, 0, stream>>>(tileTot, offsD);
            k_scatterT<NT_D, 5><<<HB, 256, 0, stream>>>(dst, blockStart, offsD, epermD);
            k_sortNode<<<NT_D, 256, 0, stream>>>(epermD, dst, offsD, epermD2, nodeOffs);
            k_scatterIdx<<<(NE + 255) / 256, 256, 0, stream>>>(epermD2, posS, idxS);
        } else {
            k_gatherKey<<<(NE + 255) / 256, 256, 0, stream>>>(epermS, dst, idxS);
        }
        k_edge_t3<<<NE / 128, 256, 0, stream>>>(efeats, Wcomb, bcomb, epermS, tS);
    } else {
        k_w2ext<<<(32 * QC + 255) / 256, 256, 0, stream>>>(enW2, enB2, W2ext);
        k_edge_t3<<<NE / 128, 256, 0, stream>>>(efeats, Wcomb, bcomb, nullptr, tS);
    }

    for (int s = 0; s < 3; ++s) {
        if (mode == 1) {
            k_msgF16<1><<<NTS, 256, 0, stream>>>(h, W2bf, tS, srcS, idxS, offsS, outbuf);
            k_gruAgg4<<<NT_D, 256, 0, stream>>>(outbuf, nodeOffs, convB,
                                                gWhi, gWlo, gruBi, gruBh, h);
        } else if (mode == 0) {
            hipMemsetAsync(outbuf, 0, (size_t)NN * 32 * 4, stream);
            k_msgF16<0><<<NTS, 256, 0, stream>>>(h, W2bf, tS, srcS, idxS, offsS, outbuf);
            k_gru<<<NN / 32, 256, 0, stream>>>(outbuf, convB, gruWi, gruWh, gruBi, gruBh, h);
        } else {
            hipMemsetAsync(outbuf, 0, (size_t)NN * 32 * 4, stream);
            k_msgC<<<NE / 32, 256, 0, stream>>>(tS, src, dst, h, W2ext, outbuf);
            k_gru<<<NN / 32, 256, 0, stream>>>(outbuf, convB, gruWi, gruWh, gruBi, gruBh, h);
        }
    }
    k_dec<<<NN / 8, 256, 0, stream>>>(h, dW1, db1, da1, dW2, db2, da2, dW3, db3, da3, dW4, db4, out);
}